// Round 1
// baseline (1462.272 us; speedup 1.0000x reference)
//
#include <hip/hip_runtime.h>
#include <math.h>

constexpr int S  = 2048;
constexpr int D  = 1024;
constexpr int NH = 16;
constexpr int HD = 64;
constexpr int NE = 8;
constexpr int I  = 1024;
constexpr float EPS   = 1e-6f;
constexpr float THETA = 10000.0f;

// ---------------------------------------------------------------- RMSNorm
__global__ __launch_bounds__(256) void rmsnorm_kernel(const float* __restrict__ x,
    const float* __restrict__ w, float* __restrict__ out) {
  const int t = blockIdx.x;
  const float* xr = x + (size_t)t * D;
  float v[4];
  float ss = 0.f;
#pragma unroll
  for (int i = 0; i < 4; ++i) { v[i] = xr[threadIdx.x + i * 256]; ss += v[i] * v[i]; }
#pragma unroll
  for (int m = 32; m >= 1; m >>= 1) ss += __shfl_xor(ss, m, 64);
  __shared__ float red[4];
  if ((threadIdx.x & 63) == 0) red[threadIdx.x >> 6] = ss;
  __syncthreads();
  const float tot = red[0] + red[1] + red[2] + red[3];
  const float rs = rsqrtf(tot * (1.f / (float)D) + EPS);
#pragma unroll
  for (int i = 0; i < 4; ++i) {
    const int d = threadIdx.x + i * 256;
    out[(size_t)t * D + d] = v[i] * rs * w[d];
  }
}

// ---------------------------------------------------------------- plain GEMM (C = A@B [+ Res])
template <bool ADD>
__global__ __launch_bounds__(256) void gemm_kernel(const float* __restrict__ A,
    const float* __restrict__ B, const float* __restrict__ Res, float* __restrict__ C,
    int M, int N, int K) {
  __shared__ __align__(16) float As[16][64];
  __shared__ __align__(16) float Bs[16][64];
  const int tid = threadIdx.x;
  const int m0 = blockIdx.y * 64, n0 = blockIdx.x * 64;
  const int ar = tid >> 2, ak = (tid & 3) << 2;
  const int bk = tid >> 4, bn = (tid & 15) << 2;
  const int tr = (tid >> 4) << 2, tc = (tid & 15) << 2;
  float acc[4][4] = {};
  for (int k0 = 0; k0 < K; k0 += 16) {
    const float4 av = *(const float4*)(A + (size_t)(m0 + ar) * K + k0 + ak);
    const float4 bv = *(const float4*)(B + (size_t)(k0 + bk) * N + n0 + bn);
    __syncthreads();
    As[ak + 0][ar] = av.x; As[ak + 1][ar] = av.y; As[ak + 2][ar] = av.z; As[ak + 3][ar] = av.w;
    *(float4*)(&Bs[bk][bn]) = bv;
    __syncthreads();
#pragma unroll
    for (int k = 0; k < 16; ++k) {
      const float4 a = *(const float4*)(&As[k][tr]);
      const float4 b = *(const float4*)(&Bs[k][tc]);
      const float aa[4] = {a.x, a.y, a.z, a.w};
      const float bb[4] = {b.x, b.y, b.z, b.w};
#pragma unroll
      for (int i = 0; i < 4; ++i)
#pragma unroll
        for (int j = 0; j < 4; ++j) acc[i][j] += aa[i] * bb[j];
    }
  }
#pragma unroll
  for (int i = 0; i < 4; ++i) {
    const size_t row = m0 + tr + i;
#pragma unroll
    for (int j = 0; j < 4; ++j) {
      const size_t col = n0 + tc + j;
      float v = acc[i][j];
      if (ADD) v += Res[row * N + col];
      C[row * N + col] = v;
    }
  }
}

// ---------------------------------------------------------------- RoPE (in-place on q,k of qkv)
__global__ __launch_bounds__(256) void rope_kernel(float* __restrict__ qkv,
    const int* __restrict__ positions) {
  const int idx = blockIdx.x * 256 + threadIdx.x;  // S*NH*2*32 = 2,097,152 threads
  const int j = idx & 31;
  const int h = (idx >> 5) & 15;
  const int which = (idx >> 9) & 1;  // 0=q, 1=k
  const int t = idx >> 10;
  const size_t base = (size_t)t * 3072 + (size_t)which * 1024 + h * 64;
  const float inv = powf(THETA, -(float)j * (1.f / 32.f));
  const float fr = (float)positions[t] * inv;
  float sn, cs;
  sincosf(fr, &sn, &cs);
  const float x1 = qkv[base + j], x2 = qkv[base + j + 32];
  qkv[base + j]      = x1 * cs - x2 * sn;
  qkv[base + j + 32] = x1 * sn + x2 * cs;
}

// ---------------------------------------------------------------- flash attention (f32)
__global__ __launch_bounds__(256) void attn_kernel(const float* __restrict__ qkv,
    float* __restrict__ o) {
  const int head = blockIdx.y;
  const int q0 = blockIdx.x * 16;
  const int tid = threadIdx.x;
  const int qi = tid >> 4;  // 0..15 query within tile
  const int g  = tid & 15;  // 0..15 lane group
  __shared__ float qs[16][64];
  __shared__ float ks[64][65];
  __shared__ float vs[64][65];
  __shared__ float ps[16][68];

  for (int i = tid; i < 16 * 64; i += 256) {
    const int r = i >> 6, d = i & 63;
    qs[r][d] = qkv[(size_t)(q0 + r) * 3072 + head * 64 + d];
  }
  float m_run = -INFINITY, l_run = 0.f;
  float acc[4] = {0.f, 0.f, 0.f, 0.f};
  const int qrow = q0 + qi;
  const int ktiles = q0 / 64 + 1;
  for (int kt = 0; kt < ktiles; ++kt) {
    const int k0 = kt * 64;
    __syncthreads();
    for (int i = tid; i < 64 * 64; i += 256) {
      const int r = i >> 6, d = i & 63;
      ks[r][d] = qkv[(size_t)(k0 + r) * 3072 + 1024 + head * 64 + d];
      vs[r][d] = qkv[(size_t)(k0 + r) * 3072 + 2048 + head * 64 + d];
    }
    __syncthreads();
    float s[4] = {0.f, 0.f, 0.f, 0.f};
    for (int d = 0; d < 64; ++d) {
      const float qv = qs[qi][d];
      s[0] += qv * ks[g * 4 + 0][d];
      s[1] += qv * ks[g * 4 + 1][d];
      s[2] += qv * ks[g * 4 + 2][d];
      s[3] += qv * ks[g * 4 + 3][d];
    }
#pragma unroll
    for (int jj = 0; jj < 4; ++jj)
      s[jj] = (qrow >= k0 + g * 4 + jj) ? s[jj] * 0.125f : -INFINITY;
    float mx = fmaxf(fmaxf(s[0], s[1]), fmaxf(s[2], s[3]));
#pragma unroll
    for (int msk = 8; msk >= 1; msk >>= 1) mx = fmaxf(mx, __shfl_xor(mx, msk, 64));
    const float m_new = fmaxf(m_run, mx);
    const float fac = expf(m_run - m_new);
    float psum = 0.f;
#pragma unroll
    for (int jj = 0; jj < 4; ++jj) { s[jj] = expf(s[jj] - m_new); psum += s[jj]; }
#pragma unroll
    for (int msk = 8; msk >= 1; msk >>= 1) psum += __shfl_xor(psum, msk, 64);
    l_run = l_run * fac + psum;
    m_run = m_new;
#pragma unroll
    for (int jj = 0; jj < 4; ++jj) { acc[jj] *= fac; ps[qi][g * 4 + jj] = s[jj]; }
    __syncthreads();
    for (int jv = 0; jv < 64; ++jv) {
      const float p = ps[qi][jv];
#pragma unroll
      for (int jj = 0; jj < 4; ++jj) acc[jj] += p * vs[jv][g * 4 + jj];
    }
  }
  const float invl = 1.f / l_run;
#pragma unroll
  for (int jj = 0; jj < 4; ++jj)
    o[(size_t)qrow * 1024 + head * 64 + g * 4 + jj] = acc[jj] * invl;
}

// ---------------------------------------------------------------- gate + top-2
__global__ __launch_bounds__(256) void gate_topk_kernel(const float* __restrict__ Y,
    const float* __restrict__ GW, int* __restrict__ top_idx, float* __restrict__ top_w) {
  const int t = blockIdx.x;
  const int e = threadIdx.x & 7;
  const int c = threadIdx.x >> 3;  // 0..31
  float p = 0.f;
  for (int d = c; d < D; d += 32) p += Y[(size_t)t * D + d] * GW[d * NE + e];
  __shared__ float part[32][8];
  part[c][e] = p;
  __syncthreads();
  __shared__ float lg[8];
  if (threadIdx.x < 8) {
    float sAcc = 0.f;
    for (int i = 0; i < 32; ++i) sAcc += part[i][threadIdx.x];
    lg[threadIdx.x] = sAcc;
  }
  __syncthreads();
  if (threadIdx.x == 0) {
    int i0 = 0; float v0 = lg[0];
    for (int i = 1; i < 8; ++i) if (lg[i] > v0) { v0 = lg[i]; i0 = i; }
    int i1 = -1; float v1 = -INFINITY;
    for (int i = 0; i < 8; ++i) if (i != i0 && lg[i] > v1) { v1 = lg[i]; i1 = i; }
    // normalized top-2 softmax weights (denominator cancels)
    const float e1 = expf(v1 - v0);
    const float inv = 1.f / (1.f + e1);
    top_idx[t * 2 + 0] = i0; top_idx[t * 2 + 1] = i1;
    top_w[t * 2 + 0] = inv;  top_w[t * 2 + 1] = e1 * inv;
  }
}

// ---------------------------------------------------------------- scatter tokens to experts
__global__ void scatter_kernel(const int* __restrict__ top_idx, const float* __restrict__ top_w,
    int* __restrict__ counts, int* __restrict__ tok_map, int* __restrict__ slot_map,
    float* __restrict__ w_map) {
  const int t = blockIdx.x * 256 + threadIdx.x;
  if (t >= S) return;
  for (int s = 0; s < 2; ++s) {
    const int e = top_idx[t * 2 + s];
    const int p = atomicAdd(&counts[e], 1);
    tok_map[e * S + p] = t;
    slot_map[e * S + p] = s;
    w_map[e * S + p] = top_w[t * 2 + s];
  }
}

// ---------------------------------------------------------------- MoE gate/up GEMM + SiLU*u
__global__ __launch_bounds__(256) void moe_gu_kernel(const float* __restrict__ Y,
    const float* __restrict__ Wg, const float* __restrict__ Wu,
    const int* __restrict__ counts, const int* __restrict__ tok_map,
    float* __restrict__ Hbuf) {
  const int e = blockIdx.z;
  const int cnt = counts[e];
  const int m0 = blockIdx.y * 64;
  if (m0 >= cnt) return;
  const int n0 = blockIdx.x * 64;
  const float* Bg = Wg + (size_t)e * D * I;
  const float* Bu = Wu + (size_t)e * D * I;
  const int* tmap = tok_map + e * S;
  __shared__ __align__(16) float As[16][64];
  __shared__ __align__(16) float Bgs[16][64];
  __shared__ __align__(16) float Bus[16][64];
  const int tid = threadIdx.x;
  const int ar = tid >> 2, ak = (tid & 3) << 2;
  const int bk = tid >> 4, bn = (tid & 15) << 2;
  const int tr = (tid >> 4) << 2, tc = (tid & 15) << 2;
  const int arow = m0 + ar;
  const bool aval = arow < cnt;
  const float* Arow = Y + (aval ? (size_t)tmap[arow] * D : 0);
  float accg[4][4] = {}, accu[4][4] = {};
  for (int k0 = 0; k0 < D; k0 += 16) {
    const float4 av = aval ? *(const float4*)(Arow + k0 + ak) : make_float4(0.f, 0.f, 0.f, 0.f);
    const float4 bgv = *(const float4*)(Bg + (size_t)(k0 + bk) * I + n0 + bn);
    const float4 buv = *(const float4*)(Bu + (size_t)(k0 + bk) * I + n0 + bn);
    __syncthreads();
    As[ak + 0][ar] = av.x; As[ak + 1][ar] = av.y; As[ak + 2][ar] = av.z; As[ak + 3][ar] = av.w;
    *(float4*)(&Bgs[bk][bn]) = bgv;
    *(float4*)(&Bus[bk][bn]) = buv;
    __syncthreads();
#pragma unroll
    for (int k = 0; k < 16; ++k) {
      const float4 a = *(const float4*)(&As[k][tr]);
      const float4 bg = *(const float4*)(&Bgs[k][tc]);
      const float4 bu = *(const float4*)(&Bus[k][tc]);
      const float aa[4] = {a.x, a.y, a.z, a.w};
      const float gg[4] = {bg.x, bg.y, bg.z, bg.w};
      const float uu[4] = {bu.x, bu.y, bu.z, bu.w};
#pragma unroll
      for (int i = 0; i < 4; ++i)
#pragma unroll
        for (int j = 0; j < 4; ++j) { accg[i][j] += aa[i] * gg[j]; accu[i][j] += aa[i] * uu[j]; }
    }
  }
#pragma unroll
  for (int i = 0; i < 4; ++i) {
    const int row = m0 + tr + i;
    if (row < cnt) {
#pragma unroll
      for (int j = 0; j < 4; ++j) {
        const float gg = accg[i][j], uu = accu[i][j];
        const float sg = gg / (1.f + expf(-gg));
        Hbuf[(size_t)e * S * I + (size_t)row * I + n0 + tc + j] = sg * uu;
      }
    }
  }
}

// ---------------------------------------------------------------- MoE down GEMM -> slot buffers
__global__ __launch_bounds__(256) void moe_down_kernel(const float* __restrict__ Hbuf,
    const float* __restrict__ Wd, const int* __restrict__ counts,
    const int* __restrict__ tok_map, const int* __restrict__ slot_map,
    const float* __restrict__ w_map, float* __restrict__ slot_out) {
  const int e = blockIdx.z;
  const int cnt = counts[e];
  const int m0 = blockIdx.y * 64;
  if (m0 >= cnt) return;
  const int n0 = blockIdx.x * 64;
  const float* Amat = Hbuf + (size_t)e * S * I;
  const float* Bmat = Wd + (size_t)e * I * D;
  __shared__ __align__(16) float As[16][64];
  __shared__ __align__(16) float Bs[16][64];
  const int tid = threadIdx.x;
  const int ar = tid >> 2, ak = (tid & 3) << 2;
  const int bk = tid >> 4, bn = (tid & 15) << 2;
  const int tr = (tid >> 4) << 2, tc = (tid & 15) << 2;
  const int arow = m0 + ar;
  const bool aval = arow < cnt;
  float acc[4][4] = {};
  for (int k0 = 0; k0 < I; k0 += 16) {
    const float4 av = aval ? *(const float4*)(Amat + (size_t)arow * I + k0 + ak)
                           : make_float4(0.f, 0.f, 0.f, 0.f);
    const float4 bv = *(const float4*)(Bmat + (size_t)(k0 + bk) * D + n0 + bn);
    __syncthreads();
    As[ak + 0][ar] = av.x; As[ak + 1][ar] = av.y; As[ak + 2][ar] = av.z; As[ak + 3][ar] = av.w;
    *(float4*)(&Bs[bk][bn]) = bv;
    __syncthreads();
#pragma unroll
    for (int k = 0; k < 16; ++k) {
      const float4 a = *(const float4*)(&As[k][tr]);
      const float4 b = *(const float4*)(&Bs[k][tc]);
      const float aa[4] = {a.x, a.y, a.z, a.w};
      const float bb[4] = {b.x, b.y, b.z, b.w};
#pragma unroll
      for (int i = 0; i < 4; ++i)
#pragma unroll
        for (int j = 0; j < 4; ++j) acc[i][j] += aa[i] * bb[j];
    }
  }
#pragma unroll
  for (int i = 0; i < 4; ++i) {
    const int row = m0 + tr + i;
    if (row < cnt) {
      const int t = tok_map[e * S + row];
      const int sl = slot_map[e * S + row];
      const float w = w_map[e * S + row];
#pragma unroll
      for (int j = 0; j < 4; ++j)
        slot_out[(size_t)sl * S * D + (size_t)t * D + n0 + tc + j] = w * acc[i][j];
    }
  }
}

// ---------------------------------------------------------------- final residual add
__global__ void final_add_kernel(float* __restrict__ out, const float* __restrict__ s0,
                                 const float* __restrict__ s1) {
  const int i = blockIdx.x * 256 + threadIdx.x;
  out[i] = out[i] + s0[i] + s1[i];
}

// ---------------------------------------------------------------- launch
extern "C" void kernel_launch(void* const* d_in, const int* in_sizes, int n_in,
                              void* d_out, int out_size, void* d_ws, size_t ws_size,
                              hipStream_t stream) {
  const int*   positions = (const int*)d_in[0];
  const float* hidden    = (const float*)d_in[1];
  // d_in[2] (residual) is unused by the reference
  const float* ln1_w  = (const float*)d_in[3];
  const float* ln2_w  = (const float*)d_in[4];
  const float* wqkv   = (const float*)d_in[5];
  const float* wo     = (const float*)d_in[6];
  const float* gate_w = (const float*)d_in[7];
  const float* wg     = (const float*)d_in[8];
  const float* wu     = (const float*)d_in[9];
  const float* wd     = (const float*)d_in[10];
  float* out = (float*)d_out;

  char* ws = (char*)d_ws;
  // phase-aliased layout (peak ~88.5 MB)
  float* y     = (float*)(ws + 0);               // 8 MB   [MoE phase]
  float* qkv   = (float*)(ws + (8u  << 20));     // 24 MB  [attn phase]
  float* xn    = (float*)(ws + (32u << 20));     // 8 MB   [attn phase]
  float* o     = (float*)(ws + (40u << 20));     // 8 MB   [attn phase]
  float* hbuf  = (float*)(ws + (8u  << 20));     // 64 MB  [MoE phase, aliases qkv/xn/o]
  float* slot0 = (float*)(ws + (72u << 20));     // 16 MB (slot0 + slot1)
  char*  extra = ws + (88u << 20);
  int*   top_idx  = (int*)extra;                         // 16 KB
  float* top_w    = (float*)(extra + 16384);             // 16 KB
  int*   counts   = (int*)(extra + 32768);               // 32 B (padded)
  int*   tok_map  = (int*)(extra + 33792);               // 64 KB
  int*   slot_map = (int*)(extra + 33792 + 65536);       // 64 KB
  float* w_map    = (float*)(extra + 33792 + 131072);    // 64 KB

  // 1) x_norm = rmsnorm(hidden, ln1_w)
  rmsnorm_kernel<<<S, 256, 0, stream>>>(hidden, ln1_w, xn);
  // 2) qkv = x_norm @ wqkv
  gemm_kernel<false><<<dim3(48, 32), 256, 0, stream>>>(xn, wqkv, nullptr, qkv, S, 3 * D, D);
  // 3) RoPE on q,k
  rope_kernel<<<8192, 256, 0, stream>>>(qkv, positions);
  // 4) causal attention -> o [S][H][HD]
  attn_kernel<<<dim3(S / 16, NH), 256, 0, stream>>>(qkv, o);
  // 5) res2 = hidden + o @ wo   (written to d_out)
  gemm_kernel<true><<<dim3(16, 32), 256, 0, stream>>>(o, wo, hidden, out, S, D, D);
  // 6) y = rmsnorm(res2, ln2_w)
  rmsnorm_kernel<<<S, 256, 0, stream>>>(out, ln2_w, y);
  // 7) gating: top-2 experts per token
  gate_topk_kernel<<<S, 256, 0, stream>>>(y, gate_w, top_idx, top_w);
  // 8) scatter token->expert lists
  hipMemsetAsync(counts, 0, NE * sizeof(int), stream);
  scatter_kernel<<<(S + 255) / 256, 256, 0, stream>>>(top_idx, top_w, counts, tok_map,
                                                      slot_map, w_map);
  // 9) h = silu(Y@wg) * (Y@wu) per expert (gathered rows)
  moe_gu_kernel<<<dim3(I / 64, S / 64, NE), 256, 0, stream>>>(y, wg, wu, counts, tok_map, hbuf);
  // 10) slot_out[slot][t] = w * (h @ wd)
  moe_down_kernel<<<dim3(D / 64, S / 64, NE), 256, 0, stream>>>(hbuf, wd, counts, tok_map,
                                                                slot_map, w_map, slot0);
  // 11) out = res2 + slot0 + slot1
  final_add_kernel<<<(S * D) / 256, 256, 0, stream>>>(out, slot0, slot0 + (size_t)S * D);
}

// Round 2
// 504.208 us; speedup vs baseline: 2.9001x; 2.9001x over previous
//
#include <hip/hip_runtime.h>
#include <math.h>

constexpr int S  = 2048;
constexpr int D  = 1024;
constexpr int NH = 16;
constexpr int NE = 8;
constexpr float EPS   = 1e-6f;
constexpr float THETA = 10000.0f;

typedef unsigned short u16;
typedef unsigned int   u32;
typedef unsigned long long u64;
typedef __attribute__((ext_vector_type(8))) short short8;
typedef __attribute__((ext_vector_type(4))) float f32x4;

__device__ __forceinline__ u16 f2bf(float x) {
  union { float f; u32 u; } v; v.f = x;
  u32 r = (v.u + 0x7FFFu + ((v.u >> 16) & 1u)) >> 16;
  return (u16)r;
}
__device__ __forceinline__ float bf2f(u16 h) {
  union { u32 u; float f; } v; v.u = ((u32)h) << 16;
  return v.f;
}
__device__ __forceinline__ f32x4 mfma16(short8 a, short8 b, f32x4 c) {
  return __builtin_amdgcn_mfma_f32_16x16x32_bf16(a, b, c, 0, 0, 0);
}
__device__ __forceinline__ void gl_lds16(const void* g, void* l) {
  __builtin_amdgcn_global_load_lds((const __attribute__((address_space(1))) u32*)g,
                                   (__attribute__((address_space(3))) u32*)l, 16, 0, 0);
}

// ------------------------------------------------ weight transpose+split: W[K][N] f32 -> out[N][2K] bf16 (hi|lo)
__global__ __launch_bounds__(256) void wsplit_t(const float* __restrict__ W,
    u16* __restrict__ out, int K, int N) {
  __shared__ float t_[64][65];
  const int k0 = blockIdx.y * 64, n0 = blockIdx.x * 64;
  const int tid = threadIdx.x;
  const int r = tid >> 4, c4 = (tid & 15) * 4;
#pragma unroll
  for (int i = 0; i < 4; ++i) {
    const float4 v = *(const float4*)(W + (size_t)(k0 + r + i * 16) * N + n0 + c4);
    t_[r + i * 16][c4 + 0] = v.x; t_[r + i * 16][c4 + 1] = v.y;
    t_[r + i * 16][c4 + 2] = v.z; t_[r + i * 16][c4 + 3] = v.w;
  }
  __syncthreads();
#pragma unroll
  for (int i = 0; i < 4; ++i) {
    const int n = n0 + r + i * 16;
    u16* oh = out + (size_t)n * (2 * K) + k0 + c4;
    u16* ol = oh + K;
#pragma unroll
    for (int j = 0; j < 4; ++j) {
      const float v = t_[c4 + j][r + i * 16];
      const u16 h = f2bf(v);
      oh[j] = h; ol[j] = f2bf(v - bf2f(h));
    }
  }
}

// ------------------------------------------------ plain transpose: W[e][K][N] f32 -> out[e][N][K] bf16
__global__ __launch_bounds__(256) void wplain_t(const float* __restrict__ Wb,
    u16* __restrict__ outb, int K, int N) {
  __shared__ float t_[64][65];
  const float* W = Wb + (size_t)blockIdx.z * K * N;
  u16* out = outb + (size_t)blockIdx.z * N * K;
  const int k0 = blockIdx.y * 64, n0 = blockIdx.x * 64;
  const int tid = threadIdx.x;
  const int r = tid >> 4, c4 = (tid & 15) * 4;
#pragma unroll
  for (int i = 0; i < 4; ++i) {
    const float4 v = *(const float4*)(W + (size_t)(k0 + r + i * 16) * N + n0 + c4);
    t_[r + i * 16][c4 + 0] = v.x; t_[r + i * 16][c4 + 1] = v.y;
    t_[r + i * 16][c4 + 2] = v.z; t_[r + i * 16][c4 + 3] = v.w;
  }
  __syncthreads();
#pragma unroll
  for (int i = 0; i < 4; ++i) {
    const int n = n0 + r + i * 16;
    u16* o = out + (size_t)n * K + k0 + c4;
#pragma unroll
    for (int j = 0; j < 4; ++j) o[j] = f2bf(t_[c4 + j][r + i * 16]);
  }
}

// ------------------------------------------------ rmsnorm -> split bf16 [t][2048] (hi|lo)
__global__ __launch_bounds__(256) void rmsnorm_split(const float* __restrict__ x,
    const float* __restrict__ w, u16* __restrict__ out2) {
  const int t = blockIdx.x;
  const float* xr = x + (size_t)t * D;
  float v[4]; float ss = 0.f;
#pragma unroll
  for (int i = 0; i < 4; ++i) { v[i] = xr[threadIdx.x + i * 256]; ss += v[i] * v[i]; }
#pragma unroll
  for (int m = 32; m >= 1; m >>= 1) ss += __shfl_xor(ss, m, 64);
  __shared__ float red[4];
  if ((threadIdx.x & 63) == 0) red[threadIdx.x >> 6] = ss;
  __syncthreads();
  const float rs = rsqrtf((red[0] + red[1] + red[2] + red[3]) * (1.f / (float)D) + EPS);
#pragma unroll
  for (int i = 0; i < 4; ++i) {
    const int d = threadIdx.x + i * 256;
    const float y = v[i] * rs * w[d];
    const u16 h = f2bf(y);
    out2[(size_t)t * 2048 + d] = h;
    out2[(size_t)t * 2048 + 1024 + d] = f2bf(y - bf2f(h));
  }
}

// ------------------------------------------------ rmsnorm -> f32 y + plain bf16 yb
__global__ __launch_bounds__(256) void rmsnorm_y(const float* __restrict__ x,
    const float* __restrict__ w, float* __restrict__ y, u16* __restrict__ yb) {
  const int t = blockIdx.x;
  const float* xr = x + (size_t)t * D;
  float v[4]; float ss = 0.f;
#pragma unroll
  for (int i = 0; i < 4; ++i) { v[i] = xr[threadIdx.x + i * 256]; ss += v[i] * v[i]; }
#pragma unroll
  for (int m = 32; m >= 1; m >>= 1) ss += __shfl_xor(ss, m, 64);
  __shared__ float red[4];
  if ((threadIdx.x & 63) == 0) red[threadIdx.x >> 6] = ss;
  __syncthreads();
  const float rs = rsqrtf((red[0] + red[1] + red[2] + red[3]) * (1.f / (float)D) + EPS);
#pragma unroll
  for (int i = 0; i < 4; ++i) {
    const int d = threadIdx.x + i * 256;
    const float yy = v[i] * rs * w[d];
    y[(size_t)t * D + d] = yy;
    yb[(size_t)t * D + d] = f2bf(yy);
  }
}

// ------------------------------------------------ split bf16 GEMM, m97 structure
// A2 [M][2048] (hi|lo), Bt2 [N][2048] (hi|lo). C = Ahi*Bhi + Alo*Bhi + Ahi*Blo.
// EPI 0: write split bf16 (Ch,Clo); EPI 1: write f32 C + Res
template <int EPI>
__global__ __launch_bounds__(256) void gemm_split(const u16* __restrict__ A2,
    const u16* __restrict__ Bt2, const float* __restrict__ Res,
    void* __restrict__ Cout, u16* __restrict__ Clo, int N) {
  constexpr int K = 1024;
  __shared__ u16 As[128 * 32];
  __shared__ u16 Bs[128 * 32];
  const int tid = threadIdx.x, wv = tid >> 6, lane = tid & 63;
  const int l15 = lane & 15, lg = lane >> 4;
  const int m0 = blockIdx.y * 128, n0 = blockIdx.x * 128;
  const int wr = wv >> 1, wc = wv & 1;
  const int sr = lane >> 2;            // staging row-in-16
  const int sk = (lane & 3) * 16;      // staging byte offset
  const u16* aptr[2]; const u16* bptr[2];
#pragma unroll
  for (int i = 0; i < 2; ++i) {
    aptr[i] = A2 + (size_t)(m0 + (wv * 2 + i) * 16 + sr) * 2048;
    bptr[i] = Bt2 + (size_t)(n0 + (wv * 2 + i) * 16 + sr) * 2048;
  }
  f32x4 acc[4][4] = {};
  for (int kk = 0; kk < 96; ++kk) {
    const int t = kk * 32;
    int ka, kb;
    if (t < K)          { ka = t;         kb = t; }
    else if (t < 2 * K) { ka = t;         kb = t - K; }
    else                { ka = t - 2 * K; kb = t - K; }
    __syncthreads();
#pragma unroll
    for (int i = 0; i < 2; ++i) {
      gl_lds16((const char*)(aptr[i] + ka) + sk, (char*)As + (wv * 2 + i) * 1024);
      gl_lds16((const char*)(bptr[i] + kb) + sk, (char*)Bs + (wv * 2 + i) * 1024);
    }
    __syncthreads();
    short8 a[4], b[4];
#pragma unroll
    for (int i = 0; i < 4; ++i)
      a[i] = *(const short8*)(const void*)(As + (size_t)(wr * 64 + i * 16 + l15) * 32 + lg * 8);
#pragma unroll
    for (int j = 0; j < 4; ++j)
      b[j] = *(const short8*)(const void*)(Bs + (size_t)(wc * 64 + j * 16 + l15) * 32 + lg * 8);
#pragma unroll
    for (int i = 0; i < 4; ++i)
#pragma unroll
      for (int j = 0; j < 4; ++j) acc[i][j] = mfma16(a[i], b[j], acc[i][j]);
  }
#pragma unroll
  for (int i = 0; i < 4; ++i)
#pragma unroll
    for (int j = 0; j < 4; ++j)
#pragma unroll
      for (int r = 0; r < 4; ++r) {
        const int row = m0 + wr * 64 + i * 16 + lg * 4 + r;
        const int col = n0 + wc * 64 + j * 16 + l15;
        const float v = acc[i][j][r];
        if (EPI == 0) {
          u16* Ch = (u16*)Cout;
          const u16 h = f2bf(v);
          Ch[(size_t)row * N + col] = h;
          Clo[(size_t)row * N + col] = f2bf(v - bf2f(h));
        } else {
          ((float*)Cout)[(size_t)row * N + col] = v + Res[(size_t)row * N + col];
        }
      }
}

// ------------------------------------------------ RoPE on split q,k
__global__ __launch_bounds__(256) void rope_split(u16* __restrict__ Qh, u16* __restrict__ Ql,
    const int* __restrict__ positions) {
  const int idx = blockIdx.x * 256 + threadIdx.x;
  const int j = idx & 31;
  const int h = (idx >> 5) & 15;
  const int which = (idx >> 9) & 1;
  const int t = idx >> 10;
  const size_t base = (size_t)t * 3072 + (size_t)which * 1024 + h * 64;
  const float inv = powf(THETA, -(float)j * (1.f / 32.f));
  const float fr = (float)positions[t] * inv;
  float sn, cs; sincosf(fr, &sn, &cs);
  const float x1 = bf2f(Qh[base + j]) + bf2f(Ql[base + j]);
  const float x2 = bf2f(Qh[base + j + 32]) + bf2f(Ql[base + j + 32]);
  const float y1 = x1 * cs - x2 * sn;
  const float y2 = x1 * sn + x2 * cs;
  const u16 h1 = f2bf(y1);
  Qh[base + j] = h1; Ql[base + j] = f2bf(y1 - bf2f(h1));
  const u16 h2 = f2bf(y2);
  Qh[base + j + 32] = h2; Ql[base + j + 32] = f2bf(y2 - bf2f(h2));
}

// ------------------------------------------------ MFMA flash attention, split-bf16 (3-term)
// block: 1 head x 64 q-rows, 4 waves x 16 q-rows. Out: OA2 [S][2048] split (hi|lo).
__global__ __launch_bounds__(256) void attn_mfma(const u16* __restrict__ Qh,
    const u16* __restrict__ Ql, u16* __restrict__ OA2) {
  const int head = blockIdx.y, q0 = blockIdx.x * 64;
  const int tid = threadIdx.x, w = tid >> 6, lane = tid & 63;
  const int l15 = lane & 15, lg = lane >> 4;
  __shared__ u16 Ksh[64 * 64];   // [key][d], XOR-swizzled (byte ^ ((key&7)<<4))
  __shared__ u16 Ksl[64 * 64];
  __shared__ u16 Vth[64 * 72];   // [d][key], padded rows
  __shared__ u16 Vtl[64 * 72];
  __shared__ u16 Ph[4 * 16 * 72]; // per-wave P rows [16][72]
  __shared__ u16 Pl[4 * 16 * 72];

  // Q fragments (A operand): row = l15, k = lg*8
  short8 qh[2], ql[2];
  {
    const size_t qbase = (size_t)(q0 + w * 16 + l15) * 3072 + head * 64;
    qh[0] = *(const short8*)(const void*)(Qh + qbase + lg * 8);
    qh[1] = *(const short8*)(const void*)(Qh + qbase + 32 + lg * 8);
    ql[0] = *(const short8*)(const void*)(Ql + qbase + lg * 8);
    ql[1] = *(const short8*)(const void*)(Ql + qbase + 32 + lg * 8);
  }
  f32x4 oacc[4] = {};
  float m_run[4], l_run[4];
#pragma unroll
  for (int r = 0; r < 4; ++r) { m_run[r] = -__builtin_inff(); l_run[r] = 0.f; }
  const int qbase_row = q0 + w * 16 + lg * 4;
  const int ktiles = q0 / 64 + 1;

  for (int kt = 0; kt < ktiles; ++kt) {
    const int k0 = kt * 64;
    __syncthreads();
    // stage K hi/lo via global_load_lds with pre-swizzled global source
#pragma unroll
    for (int i = 0; i < 2; ++i) {
      const int inst = w * 2 + i;
      const int key = inst * 8 + (lane >> 3);
      const int db = ((lane & 7) * 16) ^ ((key & 7) << 4);
      const char* gh = (const char*)(Qh + (size_t)(k0 + key) * 3072 + 1024 + head * 64) + db;
      const char* gl = (const char*)(Ql + (size_t)(k0 + key) * 3072 + 1024 + head * 64) + db;
      gl_lds16(gh, (char*)Ksh + inst * 1024);
      gl_lds16(gl, (char*)Ksl + inst * 1024);
    }
    // stage V transposed (reg-staged)
    {
      const int key = tid >> 2, dg = tid & 3;
      const u16* vh = Qh + (size_t)(k0 + key) * 3072 + 2048 + head * 64 + dg * 16;
      const u16* vl = Ql + (size_t)(k0 + key) * 3072 + 2048 + head * 64 + dg * 16;
      short8 a0 = *(const short8*)(const void*)vh;
      short8 a1 = *(const short8*)(const void*)(vh + 8);
      short8 b0 = *(const short8*)(const void*)vl;
      short8 b1 = *(const short8*)(const void*)(vl + 8);
#pragma unroll
      for (int jj = 0; jj < 8; ++jj) {
        Vth[(dg * 16 + jj) * 72 + key] = (u16)a0[jj];
        Vth[(dg * 16 + 8 + jj) * 72 + key] = (u16)a1[jj];
        Vtl[(dg * 16 + jj) * 72 + key] = (u16)b0[jj];
        Vtl[(dg * 16 + 8 + jj) * 72 + key] = (u16)b1[jj];
      }
    }
    __syncthreads();
    // QK^T: S = QhKh + QlKh + QhKl
    f32x4 sacc[4];
#pragma unroll
    for (int nt = 0; nt < 4; ++nt) {
      const int key = nt * 16 + l15;
      const char* kbh = (const char*)Ksh + key * 128;
      const char* kbl = (const char*)Ksl + key * 128;
      const int sw = (key & 7) << 4;
      const short8 kh0 = *(const short8*)(kbh + ((lg * 16) ^ sw));
      const short8 kh1 = *(const short8*)(kbh + ((64 + lg * 16) ^ sw));
      const short8 kl0 = *(const short8*)(kbl + ((lg * 16) ^ sw));
      const short8 kl1 = *(const short8*)(kbl + ((64 + lg * 16) ^ sw));
      f32x4 s = {};
      s = mfma16(qh[0], kh0, s); s = mfma16(qh[1], kh1, s);
      s = mfma16(ql[0], kh0, s); s = mfma16(ql[1], kh1, s);
      s = mfma16(qh[0], kl0, s); s = mfma16(qh[1], kl1, s);
      sacc[nt] = s;
    }
    // mask + scale
#pragma unroll
    for (int nt = 0; nt < 4; ++nt) {
      const int key = k0 + nt * 16 + l15;
#pragma unroll
      for (int r = 0; r < 4; ++r) {
        float sv = sacc[nt][r] * 0.125f;
        if (key > qbase_row + r) sv = -__builtin_inff();
        sacc[nt][r] = sv;
      }
    }
    // online softmax (per q-row r, reduce over 16 lanes)
    float m_new[4], fac[4];
#pragma unroll
    for (int r = 0; r < 4; ++r) {
      float mx = fmaxf(fmaxf(sacc[0][r], sacc[1][r]), fmaxf(sacc[2][r], sacc[3][r]));
#pragma unroll
      for (int msk = 8; msk >= 1; msk >>= 1) mx = fmaxf(mx, __shfl_xor(mx, msk, 64));
      m_new[r] = fmaxf(m_run[r], mx);
      fac[r] = expf(m_run[r] - m_new[r]);
      m_run[r] = m_new[r];
    }
#pragma unroll
    for (int nt = 0; nt < 4; ++nt)
#pragma unroll
      for (int r = 0; r < 4; ++r) sacc[nt][r] = expf(sacc[nt][r] - m_new[r]);
#pragma unroll
    for (int r = 0; r < 4; ++r) {
      float ls = sacc[0][r] + sacc[1][r] + sacc[2][r] + sacc[3][r];
#pragma unroll
      for (int msk = 8; msk >= 1; msk >>= 1) ls += __shfl_xor(ls, msk, 64);
      l_run[r] = l_run[r] * fac[r] + ls;
    }
#pragma unroll
    for (int nd = 0; nd < 4; ++nd)
#pragma unroll
      for (int r = 0; r < 4; ++r) oacc[nd][r] *= fac[r];
    // split P -> per-wave LDS
#pragma unroll
    for (int nt = 0; nt < 4; ++nt)
#pragma unroll
      for (int r = 0; r < 4; ++r) {
        const float p = sacc[nt][r];
        const u16 ph = f2bf(p);
        Ph[w * 1152 + (lg * 4 + r) * 72 + nt * 16 + l15] = ph;
        Pl[w * 1152 + (lg * 4 + r) * 72 + nt * 16 + l15] = f2bf(p - bf2f(ph));
      }
    // PV: O += PhVh + PlVh + PhVl
#pragma unroll
    for (int kk2 = 0; kk2 < 2; ++kk2) {
      const short8 pah = *(const short8*)((const char*)Ph + w * 2304 + l15 * 144 + kk2 * 64 + lg * 16);
      const short8 pal = *(const short8*)((const char*)Pl + w * 2304 + l15 * 144 + kk2 * 64 + lg * 16);
#pragma unroll
      for (int nd = 0; nd < 4; ++nd) {
        const short8 vbh = *(const short8*)((const char*)Vth + (nd * 16 + l15) * 144 + kk2 * 64 + lg * 16);
        const short8 vbl = *(const short8*)((const char*)Vtl + (nd * 16 + l15) * 144 + kk2 * 64 + lg * 16);
        oacc[nd] = mfma16(pah, vbh, oacc[nd]);
        oacc[nd] = mfma16(pal, vbh, oacc[nd]);
        oacc[nd] = mfma16(pah, vbl, oacc[nd]);
      }
    }
  }
  // epilogue: normalize, split-store
  float invl[4];
#pragma unroll
  for (int r = 0; r < 4; ++r) invl[r] = 1.f / l_run[r];
#pragma unroll
  for (int nd = 0; nd < 4; ++nd)
#pragma unroll
    for (int r = 0; r < 4; ++r) {
      const float o = oacc[nd][r] * invl[r];
      const int row = qbase_row + r;
      const int col = head * 64 + nd * 16 + l15;
      const u16 h = f2bf(o);
      OA2[(size_t)row * 2048 + col] = h;
      OA2[(size_t)row * 2048 + 1024 + col] = f2bf(o - bf2f(h));
    }
}

// ------------------------------------------------ gate + top-2 (f32, selection-critical)
__global__ __launch_bounds__(256) void gate_topk(const float* __restrict__ Y,
    const float* __restrict__ GW, int* __restrict__ top_idx, float* __restrict__ top_w) {
  const int t = blockIdx.x;
  const int e = threadIdx.x & 7;
  const int c = threadIdx.x >> 3;
  float p = 0.f;
  for (int d = c; d < D; d += 32) p += Y[(size_t)t * D + d] * GW[d * NE + e];
  __shared__ float part[32][8];
  part[c][e] = p;
  __syncthreads();
  __shared__ float lg[8];
  if (threadIdx.x < 8) {
    float sAcc = 0.f;
    for (int i = 0; i < 32; ++i) sAcc += part[i][threadIdx.x];
    lg[threadIdx.x] = sAcc;
  }
  __syncthreads();
  if (threadIdx.x == 0) {
    int i0 = 0; float v0 = lg[0];
    for (int i = 1; i < 8; ++i) if (lg[i] > v0) { v0 = lg[i]; i0 = i; }
    int i1 = -1; float v1 = -__builtin_inff();
    for (int i = 0; i < 8; ++i) if (i != i0 && lg[i] > v1) { v1 = lg[i]; i1 = i; }
    const float e1 = expf(v1 - v0);
    const float inv = 1.f / (1.f + e1);
    top_idx[t * 2 + 0] = i0; top_idx[t * 2 + 1] = i1;
    top_w[t * 2 + 0] = inv;  top_w[t * 2 + 1] = e1 * inv;
  }
}

__global__ void scatter_k(const int* __restrict__ top_idx, const float* __restrict__ top_w,
    int* __restrict__ counts, int* __restrict__ tok_map, int* __restrict__ slot_map,
    float* __restrict__ w_map) {
  const int t = blockIdx.x * 256 + threadIdx.x;
  if (t >= S) return;
  for (int s = 0; s < 2; ++s) {
    const int e = top_idx[t * 2 + s];
    const int p = atomicAdd(&counts[e], 1);
    tok_map[e * S + p] = t;
    slot_map[e * S + p] = s;
    w_map[e * S + p] = top_w[t * 2 + s];
  }
}

// ------------------------------------------------ MoE GEMMs, plain bf16, m97 structure
// GU: A = yb gathered, B1 = wgT[e], B2 = wuT[e] -> Hb = silu(g)*u (bf16)
// !GU: A = Hb packed, B1 = wdT[e] -> slots[sl][t] = w*acc (bf16)
template <bool GU>
__global__ __launch_bounds__(256) void gemm_moe(const u16* __restrict__ Abase,
    const u16* __restrict__ B1b, const u16* __restrict__ B2b, u16* __restrict__ Out,
    const int* __restrict__ counts, const int* __restrict__ tokmap,
    const int* __restrict__ slotmap, const float* __restrict__ wmap) {
  const int e = blockIdx.z;
  const int cnt = counts[e];
  const int m0 = blockIdx.y * 128;
  if (m0 >= cnt) return;
  const int n0 = blockIdx.x * 128;
  __shared__ u16 As[128 * 32];
  __shared__ u16 B1s[128 * 32];
  __shared__ u16 B2s[GU ? 128 * 32 : 64];
  const int tid = threadIdx.x, wv = tid >> 6, lane = tid & 63;
  const int l15 = lane & 15, lg = lane >> 4;
  const int wr = wv >> 1, wc = wv & 1;
  const int sr = lane >> 2;
  const int sk = (lane & 3) * 16;
  const u16* B1 = B1b + (size_t)e * 1024 * 1024;
  const u16* B2 = GU ? (B2b + (size_t)e * 1024 * 1024) : (const u16*)nullptr;

  // staging inst ids and A row pointers
  int ia[2];
  const u16* aptr[2]; const u16* b1p[2]; const u16* b2p[2];
#pragma unroll
  for (int i = 0; i < 2; ++i) {
    ia[i] = GU ? (wv + i * 4) : (wv * 2 + i);
    const int arow = m0 + ia[i] * 16 + sr;
    if (GU) {
      const int tok = tokmap[e * S + arow];
      aptr[i] = Abase + (size_t)tok * 1024;
    } else {
      aptr[i] = Abase + ((size_t)e * 2048 + arow) * 1024;
    }
    b1p[i] = B1 + (size_t)(n0 + ia[i] * 16 + sr) * 1024;
    if (GU) b2p[i] = B2 + (size_t)(n0 + ia[i] * 16 + sr) * 1024;
  }
  f32x4 acc1[4][4] = {};
  f32x4 acc2[GU ? 4 : 1][GU ? 4 : 1] = {};
  for (int kk = 0; kk < 32; ++kk) {
    const int k = kk * 32;
    __syncthreads();
#pragma unroll
    for (int i = 0; i < 2; ++i) {
      gl_lds16((const char*)(aptr[i] + k) + sk, (char*)As + ia[i] * 1024);
      gl_lds16((const char*)(b1p[i] + k) + sk, (char*)B1s + ia[i] * 1024);
      if (GU) gl_lds16((const char*)(b2p[i] + k) + sk, (char*)B2s + ia[i] * 1024);
    }
    __syncthreads();
    short8 a[4], b1f[4];
#pragma unroll
    for (int i = 0; i < 4; ++i)
      a[i] = *(const short8*)(const void*)(As + (size_t)(wr * 64 + i * 16 + l15) * 32 + lg * 8);
#pragma unroll
    for (int j = 0; j < 4; ++j)
      b1f[j] = *(const short8*)(const void*)(B1s + (size_t)(wc * 64 + j * 16 + l15) * 32 + lg * 8);
    if (GU) {
      short8 b2f[4];
#pragma unroll
      for (int j = 0; j < 4; ++j)
        b2f[j] = *(const short8*)(const void*)(B2s + (size_t)(wc * 64 + j * 16 + l15) * 32 + lg * 8);
#pragma unroll
      for (int i = 0; i < 4; ++i)
#pragma unroll
        for (int j = 0; j < 4; ++j) {
          acc1[i][j] = mfma16(a[i], b1f[j], acc1[i][j]);
          acc2[i][j] = mfma16(a[i], b2f[j], acc2[i][j]);
        }
    } else {
#pragma unroll
      for (int i = 0; i < 4; ++i)
#pragma unroll
        for (int j = 0; j < 4; ++j) acc1[i][j] = mfma16(a[i], b1f[j], acc1[i][j]);
    }
  }
#pragma unroll
  for (int i = 0; i < 4; ++i)
#pragma unroll
    for (int j = 0; j < 4; ++j)
#pragma unroll
      for (int r = 0; r < 4; ++r) {
        const int row = m0 + wr * 64 + i * 16 + lg * 4 + r;
        if (row >= cnt) continue;
        const int col = n0 + wc * 64 + j * 16 + l15;
        if (GU) {
          const float g = acc1[i][j][r];
          const float u = acc2[i][j][r];
          const float h = u * (g / (1.f + expf(-g)));
          Out[((size_t)e * 2048 + row) * 1024 + col] = f2bf(h);
        } else {
          const int t = tokmap[e * S + row];
          const int sl = slotmap[e * S + row];
          const float wgt = wmap[e * S + row];
          Out[(size_t)sl * 2048 * 1024 + (size_t)t * 1024 + col] = f2bf(wgt * acc1[i][j][r]);
        }
      }
}

// ------------------------------------------------ final residual add
__global__ void final_add(float* __restrict__ out, const u16* __restrict__ s0,
                          const u16* __restrict__ s1) {
  const int i = (blockIdx.x * 256 + threadIdx.x) * 4;
  float4 o = *(float4*)(out + i);
  const u64 a = *(const u64*)(s0 + i);
  const u64 b = *(const u64*)(s1 + i);
  o.x += bf2f((u16)(a)) + bf2f((u16)(b));
  o.y += bf2f((u16)(a >> 16)) + bf2f((u16)(b >> 16));
  o.z += bf2f((u16)(a >> 32)) + bf2f((u16)(b >> 32));
  o.w += bf2f((u16)(a >> 48)) + bf2f((u16)(b >> 48));
  *(float4*)(out + i) = o;
}

// ------------------------------------------------ launch
extern "C" void kernel_launch(void* const* d_in, const int* in_sizes, int n_in,
                              void* d_out, int out_size, void* d_ws, size_t ws_size,
                              hipStream_t stream) {
  const int*   positions = (const int*)d_in[0];
  const float* hidden    = (const float*)d_in[1];
  const float* ln1_w  = (const float*)d_in[3];
  const float* ln2_w  = (const float*)d_in[4];
  const float* wqkv   = (const float*)d_in[5];
  const float* wo     = (const float*)d_in[6];
  const float* gate_w = (const float*)d_in[7];
  const float* wg     = (const float*)d_in[8];
  const float* wu     = (const float*)d_in[9];
  const float* wd     = (const float*)d_in[10];
  float* out = (float*)d_out;

  char* ws = (char*)d_ws;
  const size_t MB = 1ull << 20;
  u16* wqkvT2 = (u16*)(ws);             // [3072][2048] 12MB
  u16* woT2   = (u16*)(ws + 12 * MB);   // [1024][2048] 4MB
  u16* wgT    = (u16*)(ws + 16 * MB);   // [8][1024][1024] 16MB
  u16* wuT    = (u16*)(ws + 32 * MB);   // 16MB
  u16* wdT    = (u16*)(ws + 48 * MB);   // 16MB
  u16* xn2    = (u16*)(ws + 64 * MB);   // [2048][2048] 8MB (dead after QKV)
  u16* QKVh   = (u16*)(ws + 72 * MB);   // [2048][3072] 12MB (dead after attn)
  u16* QKVl   = (u16*)(ws + 84 * MB);   // 12MB
  u16* OA2    = (u16*)(ws + 96 * MB);   // [2048][2048] 8MB (dead after Wo)
  float* yf   = (float*)(ws + 104 * MB);// 8MB (dead after gate)
  u16* yb     = (u16*)(ws + 112 * MB);  // 4MB
  char* mapb  = ws + 116 * MB;
  int*   top_idx  = (int*)mapb;
  float* top_w    = (float*)(mapb + 16384);
  int*   counts   = (int*)(mapb + 32768);
  int*   tok_map  = (int*)(mapb + 33024);
  int*   slot_map = (int*)(mapb + 33024 + 65536);
  float* w_map    = (float*)(mapb + 33024 + 131072);
  u16* slots = (u16*)(ws + 117 * MB);   // [2][2048][1024] 8MB
  u16* Hb    = (u16*)(ws + 64 * MB);    // [8][2048][1024] 32MB overlay (xn2/QKV dead)

  // weight conversion
  wsplit_t<<<dim3(48, 16), 256, 0, stream>>>(wqkv, wqkvT2, 1024, 3072);
  wsplit_t<<<dim3(16, 16), 256, 0, stream>>>(wo, woT2, 1024, 1024);
  wplain_t<<<dim3(16, 16, 8), 256, 0, stream>>>(wg, wgT, 1024, 1024);
  wplain_t<<<dim3(16, 16, 8), 256, 0, stream>>>(wu, wuT, 1024, 1024);
  wplain_t<<<dim3(16, 16, 8), 256, 0, stream>>>(wd, wdT, 1024, 1024);

  // attention path (split-bf16)
  rmsnorm_split<<<S, 256, 0, stream>>>(hidden, ln1_w, xn2);
  gemm_split<0><<<dim3(24, 16), 256, 0, stream>>>(xn2, wqkvT2, nullptr, QKVh, QKVl, 3072);
  rope_split<<<8192, 256, 0, stream>>>(QKVh, QKVl, positions);
  attn_mfma<<<dim3(32, 16), 256, 0, stream>>>(QKVh, QKVl, OA2);
  gemm_split<1><<<dim3(8, 16), 256, 0, stream>>>(OA2, woT2, hidden, out, nullptr, 1024);

  // gating (f32)
  rmsnorm_y<<<S, 256, 0, stream>>>(out, ln2_w, yf, yb);
  gate_topk<<<S, 256, 0, stream>>>(yf, gate_w, top_idx, top_w);
  hipMemsetAsync(counts, 0, NE * sizeof(int), stream);
  hipMemsetAsync(tok_map, 0, NE * S * sizeof(int), stream);
  scatter_k<<<(S + 255) / 256, 256, 0, stream>>>(top_idx, top_w, counts, tok_map,
                                                 slot_map, w_map);
  // MoE (plain bf16)
  gemm_moe<true><<<dim3(8, 16, 8), 256, 0, stream>>>(yb, wgT, wuT, Hb, counts, tok_map,
                                                     nullptr, nullptr);
  gemm_moe<false><<<dim3(8, 16, 8), 256, 0, stream>>>(Hb, wdT, nullptr, slots, counts,
                                                      tok_map, slot_map, w_map);
  final_add<<<2048, 256, 0, stream>>>(out, slots, slots + (size_t)2048 * 1024);
}

// Round 3
// 460.279 us; speedup vs baseline: 3.1769x; 1.0954x over previous
//
#include <hip/hip_runtime.h>
#include <math.h>

constexpr int S  = 2048;
constexpr int D  = 1024;
constexpr int NH = 16;
constexpr int NE = 8;
constexpr float EPS   = 1e-6f;
constexpr float THETA = 10000.0f;
constexpr float SCL2  = 0.125f * 1.4426950408889634f;  // attn scale * log2(e)

typedef unsigned short u16;
typedef unsigned int   u32;
typedef unsigned long long u64;
typedef __attribute__((ext_vector_type(8))) short short8;
typedef __attribute__((ext_vector_type(4))) float f32x4;

__device__ __forceinline__ u16 f2bf(float x) {
  union { float f; u32 u; } v; v.f = x;
  u32 r = (v.u + 0x7FFFu + ((v.u >> 16) & 1u)) >> 16;
  return (u16)r;
}
__device__ __forceinline__ float bf2f(u16 h) {
  union { u32 u; float f; } v; v.u = ((u32)h) << 16;
  return v.f;
}
__device__ __forceinline__ f32x4 mfma16(short8 a, short8 b, f32x4 c) {
  return __builtin_amdgcn_mfma_f32_16x16x32_bf16(a, b, c, 0, 0, 0);
}
__device__ __forceinline__ void gl_lds16(const void* g, void* l) {
  __builtin_amdgcn_global_load_lds((const __attribute__((address_space(1))) u32*)g,
                                   (__attribute__((address_space(3))) u32*)l, 16, 0, 0);
}

// ------------------------------------------------ rope cos/sin table [S][32] float2
__global__ __launch_bounds__(256) void rope_tab_k(const int* __restrict__ positions,
    float2* __restrict__ tab) {
  const int idx = blockIdx.x * 256 + threadIdx.x;
  const int t = idx >> 5, p = idx & 31;
  const float inv = powf(THETA, -(float)p * (1.f / 32.f));
  const float fr = (float)positions[t] * inv;
  float sn, cs; sincosf(fr, &sn, &cs);
  tab[idx] = make_float2(cs, sn);
}

// ------------------------------------------------ weight transpose+split: W[K][N] f32 -> out[N][2K] bf16 (hi|lo)
__global__ __launch_bounds__(256) void wsplit_t(const float* __restrict__ W,
    u16* __restrict__ out, int K, int N) {
  __shared__ float t_[64][65];
  const int k0 = blockIdx.y * 64, n0 = blockIdx.x * 64;
  const int tid = threadIdx.x;
  const int r = tid >> 4, c4 = (tid & 15) * 4;
#pragma unroll
  for (int i = 0; i < 4; ++i) {
    const float4 v = *(const float4*)(W + (size_t)(k0 + r + i * 16) * N + n0 + c4);
    t_[r + i * 16][c4 + 0] = v.x; t_[r + i * 16][c4 + 1] = v.y;
    t_[r + i * 16][c4 + 2] = v.z; t_[r + i * 16][c4 + 3] = v.w;
  }
  __syncthreads();
#pragma unroll
  for (int i = 0; i < 4; ++i) {
    const int n = n0 + r + i * 16;
    u16* oh = out + (size_t)n * (2 * K) + k0 + c4;
    u16* ol = oh + K;
#pragma unroll
    for (int j = 0; j < 4; ++j) {
      const float v = t_[c4 + j][r + i * 16];
      const u16 h = f2bf(v);
      oh[j] = h; ol[j] = f2bf(v - bf2f(h));
    }
  }
}

// ------------------------------------------------ plain transpose: W[e][K][N] f32 -> out[e][N][K] bf16
__global__ __launch_bounds__(256) void wplain_t(const float* __restrict__ Wb,
    u16* __restrict__ outb, int K, int N) {
  __shared__ float t_[64][65];
  const float* W = Wb + (size_t)blockIdx.z * K * N;
  u16* out = outb + (size_t)blockIdx.z * N * K;
  const int k0 = blockIdx.y * 64, n0 = blockIdx.x * 64;
  const int tid = threadIdx.x;
  const int r = tid >> 4, c4 = (tid & 15) * 4;
#pragma unroll
  for (int i = 0; i < 4; ++i) {
    const float4 v = *(const float4*)(W + (size_t)(k0 + r + i * 16) * N + n0 + c4);
    t_[r + i * 16][c4 + 0] = v.x; t_[r + i * 16][c4 + 1] = v.y;
    t_[r + i * 16][c4 + 2] = v.z; t_[r + i * 16][c4 + 3] = v.w;
  }
  __syncthreads();
#pragma unroll
  for (int i = 0; i < 4; ++i) {
    const int n = n0 + r + i * 16;
    u16* o = out + (size_t)n * K + k0 + c4;
#pragma unroll
    for (int j = 0; j < 4; ++j) o[j] = f2bf(t_[c4 + j][r + i * 16]);
  }
}

// ------------------------------------------------ rmsnorm -> split bf16 [t][2048] (hi|lo)
__global__ __launch_bounds__(256) void rmsnorm_split(const float* __restrict__ x,
    const float* __restrict__ w, u16* __restrict__ out2) {
  const int t = blockIdx.x;
  const float* xr = x + (size_t)t * D;
  float v[4]; float ss = 0.f;
#pragma unroll
  for (int i = 0; i < 4; ++i) { v[i] = xr[threadIdx.x + i * 256]; ss += v[i] * v[i]; }
#pragma unroll
  for (int m = 32; m >= 1; m >>= 1) ss += __shfl_xor(ss, m, 64);
  __shared__ float red[4];
  if ((threadIdx.x & 63) == 0) red[threadIdx.x >> 6] = ss;
  __syncthreads();
  const float rs = rsqrtf((red[0] + red[1] + red[2] + red[3]) * (1.f / (float)D) + EPS);
#pragma unroll
  for (int i = 0; i < 4; ++i) {
    const int d = threadIdx.x + i * 256;
    const float y = v[i] * rs * w[d];
    const u16 h = f2bf(y);
    out2[(size_t)t * 2048 + d] = h;
    out2[(size_t)t * 2048 + 1024 + d] = f2bf(y - bf2f(h));
  }
}

// ------------------------------------------------ QKV GEMM: split-bf16, dbuf 2-phase, RoPE epilogue
__global__ __launch_bounds__(256) void gemm_qkv(const u16* __restrict__ A2,
    const u16* __restrict__ Bt2, const float2* __restrict__ tab,
    u16* __restrict__ Ch, u16* __restrict__ Cl) {
  constexpr int N = 3072;
  __shared__ u16 As[2][128 * 32];
  __shared__ u16 Bs[2][128 * 32];
  const int tid = threadIdx.x, wv = tid >> 6, lane = tid & 63;
  const int l15 = lane & 15, lg = lane >> 4;
  const int m0 = blockIdx.y * 128, n0 = blockIdx.x * 128;
  const int wr = wv >> 1, wc = wv & 1;
  const int sr = lane >> 2, sk = (lane & 3) * 16;
  const u16* aptr[2]; const u16* bptr[2];
#pragma unroll
  for (int i = 0; i < 2; ++i) {
    aptr[i] = A2 + (size_t)(m0 + (wv * 2 + i) * 16 + sr) * 2048;
    bptr[i] = Bt2 + (size_t)(n0 + (wv * 2 + i) * 16 + sr) * 2048;
  }
  auto STAGE = [&](int buf, int kk) {
    const int t = kk * 32;
    int ka, kb;
    if (t < 1024)      { ka = t;        kb = t; }
    else if (t < 2048) { ka = t;        kb = t - 1024; }
    else               { ka = t - 2048; kb = t - 1024; }
#pragma unroll
    for (int i = 0; i < 2; ++i) {
      gl_lds16((const char*)(aptr[i] + ka) + sk, (char*)As + buf * 8192 + (wv * 2 + i) * 1024);
      gl_lds16((const char*)(bptr[i] + kb) + sk, (char*)Bs + buf * 8192 + (wv * 2 + i) * 1024);
    }
  };
  f32x4 acc[4][4] = {};
  STAGE(0, 0);
  __syncthreads();
  int cur = 0;
  for (int kk = 0; kk < 96; ++kk) {
    if (kk < 95) STAGE(cur ^ 1, kk + 1);
    const u16* Ab = (const u16*)As + cur * 4096;
    const u16* Bb = (const u16*)Bs + cur * 4096;
    short8 a[4], b[4];
#pragma unroll
    for (int i = 0; i < 4; ++i)
      a[i] = *(const short8*)(const void*)(Ab + (size_t)(wr * 64 + i * 16 + l15) * 32 + lg * 8);
#pragma unroll
    for (int j = 0; j < 4; ++j)
      b[j] = *(const short8*)(const void*)(Bb + (size_t)(wc * 64 + j * 16 + l15) * 32 + lg * 8);
    __builtin_amdgcn_s_setprio(1);
#pragma unroll
    for (int i = 0; i < 4; ++i)
#pragma unroll
      for (int j = 0; j < 4; ++j) acc[i][j] = mfma16(a[i], b[j], acc[i][j]);
    __builtin_amdgcn_s_setprio(0);
    __syncthreads();
    cur ^= 1;
  }
  // epilogue: rope on q,k tiles; split-store all
  const bool isqk = (n0 < 2048);
#pragma unroll
  for (int i = 0; i < 4; ++i)
#pragma unroll
    for (int j2 = 0; j2 < 2; ++j2)
#pragma unroll
      for (int r = 0; r < 4; ++r) {
        const int row = m0 + wr * 64 + i * 16 + lg * 4 + r;
        const int p = j2 * 16 + l15;  // head-local, < 32
        float y1 = acc[i][j2][r], y2 = acc[i][j2 + 2][r];
        if (isqk) {
          const float2 cs = tab[row * 32 + p];
          const float x1 = y1, x2 = y2;
          y1 = x1 * cs.x - x2 * cs.y;
          y2 = x1 * cs.y + x2 * cs.x;
        }
        const size_t base = (size_t)row * N + n0 + wc * 64 + p;
        const u16 h1 = f2bf(y1);
        Ch[base] = h1; Cl[base] = f2bf(y1 - bf2f(h1));
        const u16 h2 = f2bf(y2);
        Ch[base + 32] = h2; Cl[base + 32] = f2bf(y2 - bf2f(h2));
      }
}

// ------------------------------------------------ Wo GEMM: split-bf16, dbuf, K-split x2 -> f32 partials
__global__ __launch_bounds__(256) void gemm_wo(const u16* __restrict__ A2,
    const u16* __restrict__ Bt2, float* __restrict__ Pout) {
  constexpr int N = 1024;
  __shared__ u16 As[2][128 * 32];
  __shared__ u16 Bs[2][128 * 32];
  const int tid = threadIdx.x, wv = tid >> 6, lane = tid & 63;
  const int l15 = lane & 15, lg = lane >> 4;
  const int m0 = blockIdx.y * 128, n0 = blockIdx.x * 128;
  const int wr = wv >> 1, wc = wv & 1;
  const int sr = lane >> 2, sk = (lane & 3) * 16;
  const int kk0 = blockIdx.z * 48, kk1 = kk0 + 48;
  const u16* aptr[2]; const u16* bptr[2];
#pragma unroll
  for (int i = 0; i < 2; ++i) {
    aptr[i] = A2 + (size_t)(m0 + (wv * 2 + i) * 16 + sr) * 2048;
    bptr[i] = Bt2 + (size_t)(n0 + (wv * 2 + i) * 16 + sr) * 2048;
  }
  auto STAGE = [&](int buf, int kk) {
    const int t = kk * 32;
    int ka, kb;
    if (t < 1024)      { ka = t;        kb = t; }
    else if (t < 2048) { ka = t;        kb = t - 1024; }
    else               { ka = t - 2048; kb = t - 1024; }
#pragma unroll
    for (int i = 0; i < 2; ++i) {
      gl_lds16((const char*)(aptr[i] + ka) + sk, (char*)As + buf * 8192 + (wv * 2 + i) * 1024);
      gl_lds16((const char*)(bptr[i] + kb) + sk, (char*)Bs + buf * 8192 + (wv * 2 + i) * 1024);
    }
  };
  f32x4 acc[4][4] = {};
  STAGE(0, kk0);
  __syncthreads();
  int cur = 0;
  for (int kk = kk0; kk < kk1; ++kk) {
    if (kk + 1 < kk1) STAGE(cur ^ 1, kk + 1);
    const u16* Ab = (const u16*)As + cur * 4096;
    const u16* Bb = (const u16*)Bs + cur * 4096;
    short8 a[4], b[4];
#pragma unroll
    for (int i = 0; i < 4; ++i)
      a[i] = *(const short8*)(const void*)(Ab + (size_t)(wr * 64 + i * 16 + l15) * 32 + lg * 8);
#pragma unroll
    for (int j = 0; j < 4; ++j)
      b[j] = *(const short8*)(const void*)(Bb + (size_t)(wc * 64 + j * 16 + l15) * 32 + lg * 8);
    __builtin_amdgcn_s_setprio(1);
#pragma unroll
    for (int i = 0; i < 4; ++i)
#pragma unroll
      for (int j = 0; j < 4; ++j) acc[i][j] = mfma16(a[i], b[j], acc[i][j]);
    __builtin_amdgcn_s_setprio(0);
    __syncthreads();
    cur ^= 1;
  }
  float* P = Pout + (size_t)blockIdx.z * S * N;
#pragma unroll
  for (int i = 0; i < 4; ++i)
#pragma unroll
    for (int j = 0; j < 4; ++j)
#pragma unroll
      for (int r = 0; r < 4; ++r) {
        const int row = m0 + wr * 64 + i * 16 + lg * 4 + r;
        const int col = n0 + wc * 64 + j * 16 + l15;
        P[(size_t)row * N + col] = acc[i][j][r];
      }
}

// ------------------------------------------------ MFMA flash attention, split-bf16, split-K x2
__global__ __launch_bounds__(256) void attn_mfma(const u16* __restrict__ Qh,
    const u16* __restrict__ Ql, float* __restrict__ Opart, float2* __restrict__ ml) {
  const int head = blockIdx.y, qb = blockIdx.x, q0 = qb * 64;
  const int half = blockIdx.z;
  const int ktiles = qb + 1, h0 = (ktiles + 1) >> 1;
  const int t0 = half ? h0 : 0, t1 = half ? ktiles : h0;
  const int tid = threadIdx.x, w = tid >> 6, lane = tid & 63;
  const int l15 = lane & 15, lg = lane >> 4;
  __shared__ u16 Ksh[64 * 64];   // [key][d], XOR-swizzled
  __shared__ u16 Ksl[64 * 64];
  __shared__ __align__(16) u16 Vth[64 * 72];   // [d][key], 72-padded
  __shared__ __align__(16) u16 Vtl[64 * 72];
  __shared__ u16 Ph[4 * 16 * 72];
  __shared__ u16 Pl[4 * 16 * 72];

  short8 qh[2], ql[2];
  {
    const size_t qbase = (size_t)(q0 + w * 16 + l15) * 3072 + head * 64;
    qh[0] = *(const short8*)(const void*)(Qh + qbase + lg * 8);
    qh[1] = *(const short8*)(const void*)(Qh + qbase + 32 + lg * 8);
    ql[0] = *(const short8*)(const void*)(Ql + qbase + lg * 8);
    ql[1] = *(const short8*)(const void*)(Ql + qbase + 32 + lg * 8);
  }
  f32x4 oacc[4] = {};
  float m_run[4], l_run[4];
#pragma unroll
  for (int r = 0; r < 4; ++r) { m_run[r] = -__builtin_inff(); l_run[r] = 0.f; }
  const int qrow0 = q0 + w * 16 + lg * 4;

  // V-transpose thread mapping
  const int vhl = tid >> 7, vkq = tid & 15, vdg = (tid >> 4) & 7;
  const u16* vsrc_base = (vhl ? Ql : Qh) + 2048 + head * 64 + vdg * 8;
  u16* vdst = vhl ? Vtl : Vth;

  for (int kt = t0; kt < t1; ++kt) {
    const int k0 = kt * 64;
    __syncthreads();
    // stage K hi/lo via global_load_lds with pre-swizzled global source
#pragma unroll
    for (int i = 0; i < 2; ++i) {
      const int inst = w * 2 + i;
      const int key = inst * 8 + (lane >> 3);
      const int db = ((lane & 7) * 16) ^ ((key & 7) << 4);
      gl_lds16((const char*)(Qh + (size_t)(k0 + key) * 3072 + 1024 + head * 64) + db,
               (char*)Ksh + inst * 1024);
      gl_lds16((const char*)(Ql + (size_t)(k0 + key) * 3072 + 1024 + head * 64) + db,
               (char*)Ksl + inst * 1024);
    }
    // stage V transposed: 4 short8 loads + 8 ds_write_b64
    {
      const u16* vs = vsrc_base + (size_t)(k0 + vkq * 4) * 3072;
      const short8 v0 = *(const short8*)(const void*)vs;
      const short8 v1 = *(const short8*)(const void*)(vs + 3072);
      const short8 v2 = *(const short8*)(const void*)(vs + 6144);
      const short8 v3 = *(const short8*)(const void*)(vs + 9216);
#pragma unroll
      for (int jj = 0; jj < 8; ++jj) {
        const u64 pk = (u64)(u16)v0[jj] | ((u64)(u16)v1[jj] << 16) |
                       ((u64)(u16)v2[jj] << 32) | ((u64)(u16)v3[jj] << 48);
        *(u64*)(void*)(vdst + (vdg * 8 + jj) * 72 + vkq * 4) = pk;
      }
    }
    __syncthreads();
    // QK^T (log2 domain): S2 = (QhKh + QlKh + QhKl) * SCL2
    f32x4 sacc[4];
    __builtin_amdgcn_s_setprio(1);
#pragma unroll
    for (int nt = 0; nt < 4; ++nt) {
      const int key = nt * 16 + l15;
      const char* kbh = (const char*)Ksh + key * 128;
      const char* kbl = (const char*)Ksl + key * 128;
      const int sw = (key & 7) << 4;
      const short8 kh0 = *(const short8*)(const void*)(kbh + ((lg * 16) ^ sw));
      const short8 kh1 = *(const short8*)(const void*)(kbh + ((64 + lg * 16) ^ sw));
      const short8 kl0 = *(const short8*)(const void*)(kbl + ((lg * 16) ^ sw));
      const short8 kl1 = *(const short8*)(const void*)(kbl + ((64 + lg * 16) ^ sw));
      f32x4 s = {};
      s = mfma16(qh[0], kh0, s); s = mfma16(qh[1], kh1, s);
      s = mfma16(ql[0], kh0, s); s = mfma16(ql[1], kh1, s);
      s = mfma16(qh[0], kl0, s); s = mfma16(qh[1], kl1, s);
      sacc[nt] = s;
    }
    __builtin_amdgcn_s_setprio(0);
#pragma unroll
    for (int nt = 0; nt < 4; ++nt) {
      const int key = k0 + nt * 16 + l15;
#pragma unroll
      for (int r = 0; r < 4; ++r) {
        float sv = sacc[nt][r] * SCL2;
        if (key > qrow0 + r) sv = -__builtin_inff();
        sacc[nt][r] = sv;
      }
    }
    float m_new[4], fac[4];
#pragma unroll
    for (int r = 0; r < 4; ++r) {
      float mx = fmaxf(fmaxf(sacc[0][r], sacc[1][r]), fmaxf(sacc[2][r], sacc[3][r]));
#pragma unroll
      for (int msk = 8; msk >= 1; msk >>= 1) mx = fmaxf(mx, __shfl_xor(mx, msk, 64));
      m_new[r] = fmaxf(m_run[r], mx);
      fac[r] = exp2f(m_run[r] - m_new[r]);
      m_run[r] = m_new[r];
    }
#pragma unroll
    for (int nt = 0; nt < 4; ++nt)
#pragma unroll
      for (int r = 0; r < 4; ++r) sacc[nt][r] = exp2f(sacc[nt][r] - m_new[r]);
#pragma unroll
    for (int r = 0; r < 4; ++r) {
      float ls = sacc[0][r] + sacc[1][r] + sacc[2][r] + sacc[3][r];
#pragma unroll
      for (int msk = 8; msk >= 1; msk >>= 1) ls += __shfl_xor(ls, msk, 64);
      l_run[r] = l_run[r] * fac[r] + ls;
    }
#pragma unroll
    for (int nd = 0; nd < 4; ++nd)
#pragma unroll
      for (int r = 0; r < 4; ++r) oacc[nd][r] *= fac[r];
    // split P -> per-wave LDS
#pragma unroll
    for (int nt = 0; nt < 4; ++nt)
#pragma unroll
      for (int r = 0; r < 4; ++r) {
        const float p = sacc[nt][r];
        const u16 ph = f2bf(p);
        Ph[w * 1152 + (lg * 4 + r) * 72 + nt * 16 + l15] = ph;
        Pl[w * 1152 + (lg * 4 + r) * 72 + nt * 16 + l15] = f2bf(p - bf2f(ph));
      }
    // PV: O += PhVh + PlVh + PhVl
    __builtin_amdgcn_s_setprio(1);
#pragma unroll
    for (int kk2 = 0; kk2 < 2; ++kk2) {
      const short8 pah = *(const short8*)(const void*)((const char*)Ph + w * 2304 + l15 * 144 + kk2 * 64 + lg * 16);
      const short8 pal = *(const short8*)(const void*)((const char*)Pl + w * 2304 + l15 * 144 + kk2 * 64 + lg * 16);
#pragma unroll
      for (int nd = 0; nd < 4; ++nd) {
        const short8 vbh = *(const short8*)(const void*)((const char*)Vth + (nd * 16 + l15) * 144 + kk2 * 64 + lg * 16);
        const short8 vbl = *(const short8*)(const void*)((const char*)Vtl + (nd * 16 + l15) * 144 + kk2 * 64 + lg * 16);
        oacc[nd] = mfma16(pah, vbh, oacc[nd]);
        oacc[nd] = mfma16(pal, vbh, oacc[nd]);
        oacc[nd] = mfma16(pah, vbl, oacc[nd]);
      }
    }
    __builtin_amdgcn_s_setprio(0);
  }
  // store unnormalized partials
  float* Op = Opart + (size_t)half * S * 1024;
#pragma unroll
  for (int nd = 0; nd < 4; ++nd)
#pragma unroll
    for (int r = 0; r < 4; ++r)
      Op[(size_t)(qrow0 + r) * 1024 + head * 64 + nd * 16 + l15] = oacc[nd][r];
  if (l15 == 0) {
#pragma unroll
    for (int r = 0; r < 4; ++r)
      ml[((size_t)half * S + qrow0 + r) * NH + head] = make_float2(m_run[r], l_run[r]);
  }
}

// ------------------------------------------------ combine split-K attention partials -> split bf16 OA2
__global__ __launch_bounds__(256) void attn_combine(const float* __restrict__ Op,
    const float2* __restrict__ ml, u16* __restrict__ OA2) {
  const int t = blockIdx.x, tid = threadIdx.x;
  const int h = tid >> 4, dq = (tid & 15) * 4;
  const float2 a = ml[(size_t)t * NH + h];
  const float2 b = ml[((size_t)S + t) * NH + h];
  const float m = fmaxf(a.x, b.x);
  const float e0 = exp2f(a.x - m);
  const float e1 = (b.y > 0.f) ? exp2f(b.x - m) : 0.f;
  const float inv = 1.f / (e0 * a.y + e1 * b.y);
  const float4 v0 = *(const float4*)(Op + (size_t)t * 1024 + h * 64 + dq);
  const float4 v1 = *(const float4*)(Op + (size_t)S * 1024 + (size_t)t * 1024 + h * 64 + dq);
  const float ov[4] = {(e0 * v0.x + e1 * v1.x) * inv, (e0 * v0.y + e1 * v1.y) * inv,
                       (e0 * v0.z + e1 * v1.z) * inv, (e0 * v0.w + e1 * v1.w) * inv};
#pragma unroll
  for (int c = 0; c < 4; ++c) {
    const size_t idx = (size_t)t * 2048 + h * 64 + dq + c;
    const u16 hb = f2bf(ov[c]);
    OA2[idx] = hb;
    OA2[idx + 1024] = f2bf(ov[c] - bf2f(hb));
  }
}

// ------------------------------------------------ res2 = hidden + p0 + p1; write res2(out), yb(bf16 normed), rs
__global__ __launch_bounds__(256) void rmsnorm_res2(const float* __restrict__ hidden,
    const float* __restrict__ p0, const float* __restrict__ p1, const float* __restrict__ w2,
    float* __restrict__ out, u16* __restrict__ yb, float* __restrict__ rstab) {
  const int t = blockIdx.x;
  float v[4]; float ss = 0.f;
#pragma unroll
  for (int i = 0; i < 4; ++i) {
    const size_t idx = (size_t)t * D + threadIdx.x + i * 256;
    const float r = hidden[idx] + p0[idx] + p1[idx];
    v[i] = r; ss += r * r;
  }
#pragma unroll
  for (int m = 32; m >= 1; m >>= 1) ss += __shfl_xor(ss, m, 64);
  __shared__ float red[4];
  if ((threadIdx.x & 63) == 0) red[threadIdx.x >> 6] = ss;
  __syncthreads();
  const float rs = rsqrtf((red[0] + red[1] + red[2] + red[3]) * (1.f / (float)D) + EPS);
#pragma unroll
  for (int i = 0; i < 4; ++i) {
    const int d = threadIdx.x + i * 256;
    const size_t idx = (size_t)t * D + d;
    out[idx] = v[i];
    yb[idx] = f2bf(v[i] * rs * w2[d]);
  }
  if (threadIdx.x == 0) rstab[t] = rs;
}

// ------------------------------------------------ gate + top-2 (f32 from res2)
__global__ __launch_bounds__(256) void gate_topk(const float* __restrict__ res2,
    const float* __restrict__ w2, const float* __restrict__ rstab,
    const float* __restrict__ GW, int* __restrict__ top_idx, float* __restrict__ top_w) {
  const int t = blockIdx.x;
  const int e = threadIdx.x & 7;
  const int c = threadIdx.x >> 3;
  float p = 0.f;
  for (int d = c; d < D; d += 32) p += res2[(size_t)t * D + d] * w2[d] * GW[d * NE + e];
  __shared__ float part[32][8];
  part[c][e] = p;
  __syncthreads();
  __shared__ float lg[8];
  if (threadIdx.x < 8) {
    float sAcc = 0.f;
    for (int i = 0; i < 32; ++i) sAcc += part[i][threadIdx.x];
    lg[threadIdx.x] = sAcc;
  }
  __syncthreads();
  if (threadIdx.x == 0) {
    const float rs = rstab[t];
    int i0 = 0; float v0 = lg[0];
    for (int i = 1; i < 8; ++i) if (lg[i] > v0) { v0 = lg[i]; i0 = i; }
    int i1 = -1; float v1 = -__builtin_inff();
    for (int i = 0; i < 8; ++i) if (i != i0 && lg[i] > v1) { v1 = lg[i]; i1 = i; }
    const float e1 = expf((v1 - v0) * rs);
    const float inv = 1.f / (1.f + e1);
    top_idx[t * 2 + 0] = i0; top_idx[t * 2 + 1] = i1;
    top_w[t * 2 + 0] = inv;  top_w[t * 2 + 1] = e1 * inv;
  }
}

__global__ void scatter_k(const int* __restrict__ top_idx, const float* __restrict__ top_w,
    int* __restrict__ counts, int* __restrict__ tok_map, int* __restrict__ slot_map,
    float* __restrict__ w_map) {
  const int t = blockIdx.x * 256 + threadIdx.x;
  if (t >= S) return;
  for (int s = 0; s < 2; ++s) {
    const int e = top_idx[t * 2 + s];
    const int p = atomicAdd(&counts[e], 1);
    tok_map[e * S + p] = t;
    slot_map[e * S + p] = s;
    w_map[e * S + p] = top_w[t * 2 + s];
  }
}

// ------------------------------------------------ MoE gate/up GEMM (dual-B), plain bf16, dbuf
__global__ __launch_bounds__(256) void moe_gu(const u16* __restrict__ Yb,
    const u16* __restrict__ Wgb, const u16* __restrict__ Wub, u16* __restrict__ Hb,
    const int* __restrict__ counts, const int* __restrict__ tokmap) {
  const int e = blockIdx.z;
  const int cnt = counts[e];
  const int m0 = blockIdx.y * 128;
  if (m0 >= cnt) return;
  const int n0 = blockIdx.x * 128;
  __shared__ u16 As[2][128 * 32];
  __shared__ u16 B1s[2][128 * 32];
  __shared__ u16 B2s[2][128 * 32];
  const int tid = threadIdx.x, wv = tid >> 6, lane = tid & 63;
  const int l15 = lane & 15, lg = lane >> 4;
  const int wr = wv >> 1, wc = wv & 1;
  const int sr = lane >> 2, sk = (lane & 3) * 16;
  const u16* B1 = Wgb + (size_t)e * 1024 * 1024;
  const u16* B2 = Wub + (size_t)e * 1024 * 1024;
  int ia[2];
  const u16* aptr[2]; const u16* b1p[2]; const u16* b2p[2];
#pragma unroll
  for (int i = 0; i < 2; ++i) {
    ia[i] = wv + i * 4;
    const int arow = m0 + ia[i] * 16 + sr;
    aptr[i] = Yb + (size_t)tokmap[e * S + arow] * 1024;
    b1p[i] = B1 + (size_t)(n0 + ia[i] * 16 + sr) * 1024;
    b2p[i] = B2 + (size_t)(n0 + ia[i] * 16 + sr) * 1024;
  }
  auto STAGE = [&](int buf, int k) {
#pragma unroll
    for (int i = 0; i < 2; ++i) {
      gl_lds16((const char*)(aptr[i] + k) + sk, (char*)As + buf * 8192 + ia[i] * 1024);
      gl_lds16((const char*)(b1p[i] + k) + sk, (char*)B1s + buf * 8192 + ia[i] * 1024);
      gl_lds16((const char*)(b2p[i] + k) + sk, (char*)B2s + buf * 8192 + ia[i] * 1024);
    }
  };
  f32x4 acc1[4][4] = {};
  f32x4 acc2[4][4] = {};
  STAGE(0, 0);
  __syncthreads();
  int cur = 0;
  for (int kk = 0; kk < 32; ++kk) {
    if (kk < 31) STAGE(cur ^ 1, (kk + 1) * 32);
    const u16* Ab = (const u16*)As + cur * 4096;
    const u16* B1b_ = (const u16*)B1s + cur * 4096;
    const u16* B2b_ = (const u16*)B2s + cur * 4096;
    short8 a[4], b1f[4], b2f[4];
#pragma unroll
    for (int i = 0; i < 4; ++i)
      a[i] = *(const short8*)(const void*)(Ab + (size_t)(wr * 64 + i * 16 + l15) * 32 + lg * 8);
#pragma unroll
    for (int j = 0; j < 4; ++j) {
      b1f[j] = *(const short8*)(const void*)(B1b_ + (size_t)(wc * 64 + j * 16 + l15) * 32 + lg * 8);
      b2f[j] = *(const short8*)(const void*)(B2b_ + (size_t)(wc * 64 + j * 16 + l15) * 32 + lg * 8);
    }
    __builtin_amdgcn_s_setprio(1);
#pragma unroll
    for (int i = 0; i < 4; ++i)
#pragma unroll
      for (int j = 0; j < 4; ++j) {
        acc1[i][j] = mfma16(a[i], b1f[j], acc1[i][j]);
        acc2[i][j] = mfma16(a[i], b2f[j], acc2[i][j]);
      }
    __builtin_amdgcn_s_setprio(0);
    __syncthreads();
    cur ^= 1;
  }
#pragma unroll
  for (int i = 0; i < 4; ++i)
#pragma unroll
    for (int j = 0; j < 4; ++j)
#pragma unroll
      for (int r = 0; r < 4; ++r) {
        const int row = m0 + wr * 64 + i * 16 + lg * 4 + r;
        if (row < cnt) {
          const float g = acc1[i][j][r];
          const float u = acc2[i][j][r];
          const float h = u * (g / (1.f + expf(-g)));
          Hb[((size_t)e * 2048 + row) * 1024 + n0 + wc * 64 + j * 16 + l15] = f2bf(h);
        }
      }
}

// ------------------------------------------------ MoE down GEMM, plain bf16, dbuf
__global__ __launch_bounds__(256) void moe_down(const u16* __restrict__ Hb,
    const u16* __restrict__ Wdb, u16* __restrict__ slots,
    const int* __restrict__ counts, const int* __restrict__ tokmap,
    const int* __restrict__ slotmap, const float* __restrict__ wmap) {
  const int e = blockIdx.z;
  const int cnt = counts[e];
  const int m0 = blockIdx.y * 128;
  if (m0 >= cnt) return;
  const int n0 = blockIdx.x * 128;
  __shared__ u16 As[2][128 * 32];
  __shared__ u16 Bs[2][128 * 32];
  const int tid = threadIdx.x, wv = tid >> 6, lane = tid & 63;
  const int l15 = lane & 15, lg = lane >> 4;
  const int wr = wv >> 1, wc = wv & 1;
  const int sr = lane >> 2, sk = (lane & 3) * 16;
  const u16* B = Wdb + (size_t)e * 1024 * 1024;
  const u16* aptr[2]; const u16* bptr[2];
#pragma unroll
  for (int i = 0; i < 2; ++i) {
    aptr[i] = Hb + ((size_t)e * 2048 + m0 + (wv * 2 + i) * 16 + sr) * 1024;
    bptr[i] = B + (size_t)(n0 + (wv * 2 + i) * 16 + sr) * 1024;
  }
  auto STAGE = [&](int buf, int k) {
#pragma unroll
    for (int i = 0; i < 2; ++i) {
      gl_lds16((const char*)(aptr[i] + k) + sk, (char*)As + buf * 8192 + (wv * 2 + i) * 1024);
      gl_lds16((const char*)(bptr[i] + k) + sk, (char*)Bs + buf * 8192 + (wv * 2 + i) * 1024);
    }
  };
  f32x4 acc[4][4] = {};
  STAGE(0, 0);
  __syncthreads();
  int cur = 0;
  for (int kk = 0; kk < 32; ++kk) {
    if (kk < 31) STAGE(cur ^ 1, (kk + 1) * 32);
    const u16* Ab = (const u16*)As + cur * 4096;
    const u16* Bb = (const u16*)Bs + cur * 4096;
    short8 a[4], b[4];
#pragma unroll
    for (int i = 0; i < 4; ++i)
      a[i] = *(const short8*)(const void*)(Ab + (size_t)(wr * 64 + i * 16 + l15) * 32 + lg * 8);
#pragma unroll
    for (int j = 0; j < 4; ++j)
      b[j] = *(const short8*)(const void*)(Bb + (size_t)(wc * 64 + j * 16 + l15) * 32 + lg * 8);
    __builtin_amdgcn_s_setprio(1);
#pragma unroll
    for (int i = 0; i < 4; ++i)
#pragma unroll
      for (int j = 0; j < 4; ++j) acc[i][j] = mfma16(a[i], b[j], acc[i][j]);
    __builtin_amdgcn_s_setprio(0);
    __syncthreads();
    cur ^= 1;
  }
#pragma unroll
  for (int i = 0; i < 4; ++i)
#pragma unroll
    for (int j = 0; j < 4; ++j)
#pragma unroll
      for (int r = 0; r < 4; ++r) {
        const int row = m0 + wr * 64 + i * 16 + lg * 4 + r;
        if (row < cnt) {
          const int t = tokmap[e * S + row];
          const int sl = slotmap[e * S + row];
          const float wgt = wmap[e * S + row];
          slots[(size_t)sl * S * 1024 + (size_t)t * 1024 + n0 + wc * 64 + j * 16 + l15] =
              f2bf(wgt * acc[i][j][r]);
        }
      }
}

// ------------------------------------------------ final residual add
__global__ void final_add(float* __restrict__ out, const u16* __restrict__ s0,
                          const u16* __restrict__ s1) {
  const int i = (blockIdx.x * 256 + threadIdx.x) * 4;
  float4 o = *(float4*)(out + i);
  const u64 a = *(const u64*)(s0 + i);
  const u64 b = *(const u64*)(s1 + i);
  o.x += bf2f((u16)(a)) + bf2f((u16)(b));
  o.y += bf2f((u16)(a >> 16)) + bf2f((u16)(b >> 16));
  o.z += bf2f((u16)(a >> 32)) + bf2f((u16)(b >> 32));
  o.w += bf2f((u16)(a >> 48)) + bf2f((u16)(b >> 48));
  *(float4*)(out + i) = o;
}

// ------------------------------------------------ launch
extern "C" void kernel_launch(void* const* d_in, const int* in_sizes, int n_in,
                              void* d_out, int out_size, void* d_ws, size_t ws_size,
                              hipStream_t stream) {
  const int*   positions = (const int*)d_in[0];
  const float* hidden    = (const float*)d_in[1];
  const float* ln1_w  = (const float*)d_in[3];
  const float* ln2_w  = (const float*)d_in[4];
  const float* wqkv   = (const float*)d_in[5];
  const float* wo     = (const float*)d_in[6];
  const float* gate_w = (const float*)d_in[7];
  const float* wg     = (const float*)d_in[8];
  const float* wu     = (const float*)d_in[9];
  const float* wd     = (const float*)d_in[10];
  float* out = (float*)d_out;

  char* ws = (char*)d_ws;
  const size_t MB = 1ull << 20;
  u16* wqkvT2 = (u16*)(ws);                 // 12MB  [persist]
  u16* woT2   = (u16*)(ws + 12 * MB);       // 4MB   [persist]
  u16* wgT    = (u16*)(ws + 16 * MB);       // 16MB  [persist]
  u16* wuT    = (u16*)(ws + 32 * MB);       // 16MB  [persist]
  u16* wdT    = (u16*)(ws + 48 * MB);       // 16MB  [persist]
  float2* ropetab = (float2*)(ws + 64 * MB);        // 512KB [persist]
  float2* ml      = (float2*)(ws + 64 * MB + 524288); // 512KB
  char* mapb = ws + 65 * MB;
  int*   top_idx  = (int*)mapb;
  float* top_w    = (float*)(mapb + 16384);
  int*   counts   = (int*)(mapb + 32768);
  int*   tok_map  = (int*)(mapb + 40960);
  int*   slot_map = (int*)(mapb + 40960 + 65536);
  float* w_map    = (float*)(mapb + 40960 + 131072);
  float* rstab    = (float*)(mapb + 237568);
  u16* xn2   = (u16*)(ws + 66 * MB);        // 8MB  (dead after QKV)
  u16* OA2   = xn2;                         // 8MB  (combine->Wo; dead after)
  u16* slots = xn2;                         // 8MB  (MoE phase)
  u16* QKVh  = (u16*)(ws + 74 * MB);        // 12MB (dead after attn)
  u16* yb    = (u16*)(ws + 74 * MB);        // 4MB  (MoE phase)
  u16* Hb    = (u16*)(ws + 78 * MB);        // 32MB (MoE phase)
  u16* QKVl  = (u16*)(ws + 86 * MB);        // 12MB (dead after attn)
  float* Opart = (float*)(ws + 98 * MB);    // 16MB (dead after combine)
  float* p01   = Opart;                     // 16MB (Wo partials; dead after rmsnorm_res2)

  // weight conversions + rope table
  rope_tab_k<<<256, 256, 0, stream>>>(positions, ropetab);
  wsplit_t<<<dim3(48, 16), 256, 0, stream>>>(wqkv, wqkvT2, 1024, 3072);
  wsplit_t<<<dim3(16, 16), 256, 0, stream>>>(wo, woT2, 1024, 1024);
  wplain_t<<<dim3(16, 16, 8), 256, 0, stream>>>(wg, wgT, 1024, 1024);
  wplain_t<<<dim3(16, 16, 8), 256, 0, stream>>>(wu, wuT, 1024, 1024);
  wplain_t<<<dim3(16, 16, 8), 256, 0, stream>>>(wd, wdT, 1024, 1024);

  // attention path (split-bf16)
  rmsnorm_split<<<S, 256, 0, stream>>>(hidden, ln1_w, xn2);
  gemm_qkv<<<dim3(24, 16), 256, 0, stream>>>(xn2, wqkvT2, ropetab, QKVh, QKVl);
  attn_mfma<<<dim3(32, 16, 2), 256, 0, stream>>>(QKVh, QKVl, Opart, ml);
  attn_combine<<<S, 256, 0, stream>>>(Opart, ml, OA2);
  gemm_wo<<<dim3(8, 16, 2), 256, 0, stream>>>(OA2, woT2, p01);
  rmsnorm_res2<<<S, 256, 0, stream>>>(hidden, p01, p01 + (size_t)S * D, ln2_w, out, yb, rstab);

  // gating (f32)
  gate_topk<<<S, 256, 0, stream>>>(out, ln2_w, rstab, gate_w, top_idx, top_w);
  hipMemsetAsync(counts, 0, NE * sizeof(int), stream);
  hipMemsetAsync(tok_map, 0, NE * S * sizeof(int), stream);
  scatter_k<<<(S + 255) / 256, 256, 0, stream>>>(top_idx, top_w, counts, tok_map,
                                                 slot_map, w_map);
  // MoE (plain bf16)
  moe_gu<<<dim3(8, 16, 8), 256, 0, stream>>>(yb, wgT, wuT, Hb, counts, tok_map);
  moe_down<<<dim3(8, 16, 8), 256, 0, stream>>>(Hb, wdT, slots, counts, tok_map,
                                               slot_map, w_map);
  final_add<<<2048, 256, 0, stream>>>(out, slots, slots + (size_t)S * D);
}

// Round 4
// 449.926 us; speedup vs baseline: 3.2500x; 1.0230x over previous
//
#include <hip/hip_runtime.h>
#include <math.h>

constexpr int S  = 2048;
constexpr int D  = 1024;
constexpr int NH = 16;
constexpr int NE = 8;
constexpr float EPS   = 1e-6f;
constexpr float THETA = 10000.0f;
constexpr float SCL2  = 0.125f * 1.4426950408889634f;  // attn scale * log2(e)

typedef unsigned short u16;
typedef unsigned int   u32;
typedef unsigned long long u64;
typedef __attribute__((ext_vector_type(8))) short short8;
typedef __attribute__((ext_vector_type(4))) float f32x4;

__device__ __forceinline__ u16 f2bf(float x) {
  union { float f; u32 u; } v; v.f = x;
  u32 r = (v.u + 0x7FFFu + ((v.u >> 16) & 1u)) >> 16;
  return (u16)r;
}
__device__ __forceinline__ float bf2f(u16 h) {
  union { u32 u; float f; } v; v.u = ((u32)h) << 16;
  return v.f;
}
__device__ __forceinline__ f32x4 mfma16(short8 a, short8 b, f32x4 c) {
  return __builtin_amdgcn_mfma_f32_16x16x32_bf16(a, b, c, 0, 0, 0);
}
__device__ __forceinline__ void gl_lds16(const void* g, void* l) {
  __builtin_amdgcn_global_load_lds((const __attribute__((address_space(1))) u32*)g,
                                   (__attribute__((address_space(3))) u32*)l, 16, 0, 0);
}

// ================================================= unified prep kernel
// blocks [0,768): wqkv split-T; [768,1024): wo split-T; [1024,3072): wg T;
// [3072,5120): wu T; [5120,7168): wd T; [7168,7424): rope table
__global__ __launch_bounds__(256) void prep_kernel(const float* __restrict__ wqkv,
    const float* __restrict__ wo, const float* __restrict__ wg, const float* __restrict__ wu,
    const float* __restrict__ wd, const int* __restrict__ positions,
    u16* __restrict__ wqkvT2, u16* __restrict__ woT2, u16* __restrict__ wgT,
    u16* __restrict__ wuT, u16* __restrict__ wdT, float2* __restrict__ ropetab) {
  const int b = blockIdx.x;
  const int tid = threadIdx.x;
  if (b >= 7168) {  // rope table
    const int idx = (b - 7168) * 256 + tid;
    const int t = idx >> 5, p = idx & 31;
    const float inv = powf(THETA, -(float)p * (1.f / 32.f));
    const float fr = (float)positions[t] * inv;
    float sn, cs; sincosf(fr, &sn, &cs);
    ropetab[idx] = make_float2(cs, sn);
    return;
  }
  __shared__ float t_[64][65];
  const float* W; u16* out; int K, N, n0, k0; bool split;
  if (b < 768) {
    W = wqkv; out = wqkvT2; K = 1024; N = 3072; split = true;
    n0 = (b % 48) * 64; k0 = (b / 48) * 64;
  } else if (b < 1024) {
    W = wo; out = woT2; K = 1024; N = 1024; split = true;
    const int r = b - 768; n0 = (r & 15) * 64; k0 = (r >> 4) * 64;
  } else {
    int r, e;
    if (b < 3072)      { r = b - 1024; e = r >> 8; W = wg + (size_t)e * 1048576; out = wgT + (size_t)e * 1048576; }
    else if (b < 5120) { r = b - 3072; e = r >> 8; W = wu + (size_t)e * 1048576; out = wuT + (size_t)e * 1048576; }
    else               { r = b - 5120; e = r >> 8; W = wd + (size_t)e * 1048576; out = wdT + (size_t)e * 1048576; }
    K = 1024; N = 1024; split = false;
    r &= 255; n0 = (r & 15) * 64; k0 = (r >> 4) * 64;
  }
  const int rr = tid >> 4, c4 = (tid & 15) * 4;
#pragma unroll
  for (int i = 0; i < 4; ++i) {
    const float4 v = *(const float4*)(W + (size_t)(k0 + rr + i * 16) * N + n0 + c4);
    t_[rr + i * 16][c4 + 0] = v.x; t_[rr + i * 16][c4 + 1] = v.y;
    t_[rr + i * 16][c4 + 2] = v.z; t_[rr + i * 16][c4 + 3] = v.w;
  }
  __syncthreads();
  if (split) {
#pragma unroll
    for (int i = 0; i < 4; ++i) {
      const int n = n0 + rr + i * 16;
      u16* oh = out + (size_t)n * 2048 + k0 + c4;
      u16* ol = oh + 1024;
#pragma unroll
      for (int j = 0; j < 4; ++j) {
        const float v = t_[c4 + j][rr + i * 16];
        const u16 h = f2bf(v);
        oh[j] = h; ol[j] = f2bf(v - bf2f(h));
      }
    }
  } else {
#pragma unroll
    for (int i = 0; i < 4; ++i) {
      const int n = n0 + rr + i * 16;
      u16* o = out + (size_t)n * 1024 + k0 + c4;
#pragma unroll
      for (int j = 0; j < 4; ++j) o[j] = f2bf(t_[c4 + j][rr + i * 16]);
    }
  }
}

// ================================================= rmsnorm -> split bf16 [t][2048]
__global__ __launch_bounds__(256) void rmsnorm_split(const float* __restrict__ x,
    const float* __restrict__ w, u16* __restrict__ out2) {
  const int t = blockIdx.x;
  const float* xr = x + (size_t)t * D;
  float v[4]; float ss = 0.f;
#pragma unroll
  for (int i = 0; i < 4; ++i) { v[i] = xr[threadIdx.x + i * 256]; ss += v[i] * v[i]; }
#pragma unroll
  for (int m = 32; m >= 1; m >>= 1) ss += __shfl_xor(ss, m, 64);
  __shared__ float red[4];
  if ((threadIdx.x & 63) == 0) red[threadIdx.x >> 6] = ss;
  __syncthreads();
  const float rs = rsqrtf((red[0] + red[1] + red[2] + red[3]) * (1.f / (float)D) + EPS);
#pragma unroll
  for (int i = 0; i < 4; ++i) {
    const int d = threadIdx.x + i * 256;
    const float y = v[i] * rs * w[d];
    const u16 h = f2bf(y);
    out2[(size_t)t * 2048 + d] = h;
    out2[(size_t)t * 2048 + 1024 + d] = f2bf(y - bf2f(h));
  }
}

// ================================================= QKV GEMM: 128x64 tile, split-bf16, dbuf, RoPE epi
__global__ __launch_bounds__(256) void gemm_qkv(const u16* __restrict__ A2,
    const u16* __restrict__ Bt2, const float2* __restrict__ tab,
    u16* __restrict__ Ch, u16* __restrict__ Cl) {
  constexpr int N = 3072;
  __shared__ u16 As[2][128 * 32];
  __shared__ u16 Bs[2][64 * 32];
  const int tid = threadIdx.x, wv = tid >> 6, lane = tid & 63;
  const int l15 = lane & 15, lg = lane >> 4;
  const int m0 = blockIdx.y * 128, n0 = blockIdx.x * 64;
  const int wr = wv >> 1, wc = wv & 1;
  const int sr = lane >> 2, sk = (lane & 3) * 16;
  const u16* aptr[2];
#pragma unroll
  for (int i = 0; i < 2; ++i)
    aptr[i] = A2 + (size_t)(m0 + (wv * 2 + i) * 16 + sr) * 2048;
  const u16* bptr = Bt2 + (size_t)(n0 + wv * 16 + sr) * 2048;
  auto STAGE = [&](int buf, int kk) {
    const int t = kk * 32;
    int ka, kb;
    if (t < 1024)      { ka = t;        kb = t; }
    else if (t < 2048) { ka = t;        kb = t - 1024; }
    else               { ka = t - 2048; kb = t - 1024; }
#pragma unroll
    for (int i = 0; i < 2; ++i)
      gl_lds16((const char*)(aptr[i] + ka) + sk, (char*)As + buf * 8192 + (wv * 2 + i) * 1024);
    gl_lds16((const char*)(bptr + kb) + sk, (char*)Bs + buf * 4096 + wv * 1024);
  };
  f32x4 acc[4][2] = {};
  STAGE(0, 0);
  __syncthreads();
  int cur = 0;
  for (int kk = 0; kk < 96; ++kk) {
    if (kk < 95) STAGE(cur ^ 1, kk + 1);
    const u16* Ab = (const u16*)As + cur * 4096;
    const u16* Bb = (const u16*)Bs + cur * 2048;
    short8 a[4], b[2];
#pragma unroll
    for (int i = 0; i < 4; ++i)
      a[i] = *(const short8*)(const void*)(Ab + (size_t)(wr * 64 + i * 16 + l15) * 32 + lg * 8);
#pragma unroll
    for (int j = 0; j < 2; ++j)
      b[j] = *(const short8*)(const void*)(Bb + (size_t)(wc * 16 + j * 32 + l15) * 32 + lg * 8);
    __builtin_amdgcn_s_setprio(1);
#pragma unroll
    for (int i = 0; i < 4; ++i)
#pragma unroll
      for (int j = 0; j < 2; ++j) acc[i][j] = mfma16(a[i], b[j], acc[i][j]);
    __builtin_amdgcn_s_setprio(0);
    __syncthreads();
    cur ^= 1;
  }
  const bool isqk = (n0 < 2048);
#pragma unroll
  for (int i = 0; i < 4; ++i)
#pragma unroll
    for (int r = 0; r < 4; ++r) {
      const int row = m0 + wr * 64 + i * 16 + lg * 4 + r;
      const int p = wc * 16 + l15;  // head-local in [0,32)
      float y1 = acc[i][0][r], y2 = acc[i][1][r];
      if (isqk) {
        const float2 cs = tab[row * 32 + p];
        const float x1 = y1, x2 = y2;
        y1 = x1 * cs.x - x2 * cs.y;
        y2 = x1 * cs.y + x2 * cs.x;
      }
      const size_t base = (size_t)row * N + n0 + p;
      const u16 h1 = f2bf(y1);
      Ch[base] = h1; Cl[base] = f2bf(y1 - bf2f(h1));
      const u16 h2 = f2bf(y2);
      Ch[base + 32] = h2; Cl[base + 32] = f2bf(y2 - bf2f(h2));
    }
}

// ================================================= Wo GEMM: 128x64 tile, split-bf16, dbuf, K-split x2
__global__ __launch_bounds__(256) void gemm_wo(const u16* __restrict__ A2,
    const u16* __restrict__ Bt2, float* __restrict__ Pout) {
  constexpr int N = 1024;
  __shared__ u16 As[2][128 * 32];
  __shared__ u16 Bs[2][64 * 32];
  const int tid = threadIdx.x, wv = tid >> 6, lane = tid & 63;
  const int l15 = lane & 15, lg = lane >> 4;
  const int m0 = blockIdx.y * 128, n0 = blockIdx.x * 64;
  const int wr = wv >> 1, wc = wv & 1;
  const int sr = lane >> 2, sk = (lane & 3) * 16;
  const int kk0 = blockIdx.z * 48, kk1 = kk0 + 48;
  const u16* aptr[2];
#pragma unroll
  for (int i = 0; i < 2; ++i)
    aptr[i] = A2 + (size_t)(m0 + (wv * 2 + i) * 16 + sr) * 2048;
  const u16* bptr = Bt2 + (size_t)(n0 + wv * 16 + sr) * 2048;
  auto STAGE = [&](int buf, int kk) {
    const int t = kk * 32;
    int ka, kb;
    if (t < 1024)      { ka = t;        kb = t; }
    else if (t < 2048) { ka = t;        kb = t - 1024; }
    else               { ka = t - 2048; kb = t - 1024; }
#pragma unroll
    for (int i = 0; i < 2; ++i)
      gl_lds16((const char*)(aptr[i] + ka) + sk, (char*)As + buf * 8192 + (wv * 2 + i) * 1024);
    gl_lds16((const char*)(bptr + kb) + sk, (char*)Bs + buf * 4096 + wv * 1024);
  };
  f32x4 acc[4][2] = {};
  STAGE(0, kk0);
  __syncthreads();
  int cur = 0;
  for (int kk = kk0; kk < kk1; ++kk) {
    if (kk + 1 < kk1) STAGE(cur ^ 1, kk + 1);
    const u16* Ab = (const u16*)As + cur * 4096;
    const u16* Bb = (const u16*)Bs + cur * 2048;
    short8 a[4], b[2];
#pragma unroll
    for (int i = 0; i < 4; ++i)
      a[i] = *(const short8*)(const void*)(Ab + (size_t)(wr * 64 + i * 16 + l15) * 32 + lg * 8);
#pragma unroll
    for (int j = 0; j < 2; ++j)
      b[j] = *(const short8*)(const void*)(Bb + (size_t)(wc * 16 + j * 32 + l15) * 32 + lg * 8);
    __builtin_amdgcn_s_setprio(1);
#pragma unroll
    for (int i = 0; i < 4; ++i)
#pragma unroll
      for (int j = 0; j < 2; ++j) acc[i][j] = mfma16(a[i], b[j], acc[i][j]);
    __builtin_amdgcn_s_setprio(0);
    __syncthreads();
    cur ^= 1;
  }
  float* P = Pout + (size_t)blockIdx.z * S * N;
#pragma unroll
  for (int i = 0; i < 4; ++i)
#pragma unroll
    for (int j = 0; j < 2; ++j)
#pragma unroll
      for (int r = 0; r < 4; ++r) {
        const int row = m0 + wr * 64 + i * 16 + lg * 4 + r;
        const int col = n0 + wc * 16 + j * 32 + l15;
        P[(size_t)row * N + col] = acc[i][j][r];
      }
}

// ================================================= MFMA flash attention: K-dbuf, async V, packed P
__global__ __launch_bounds__(256) void attn_mfma(const u16* __restrict__ Qh,
    const u16* __restrict__ Ql, float* __restrict__ Opart, float2* __restrict__ ml) {
  // flat grid 1024, XCD-swizzled: b = (head&7) + 8*qbi + 256*half + 512*(head>>3)
  const int b = blockIdx.x;
  const int head = (b & 7) + 8 * (b >> 9);
  const int qb = 31 - ((b >> 3) & 31);      // longest first
  const int half = (b >> 8) & 1;
  const int q0 = qb * 64;
  const int ktiles = qb + 1, hsp = (ktiles + 1) >> 1;
  const int t0 = half ? hsp : 0, t1 = half ? ktiles : hsp;
  const int tid = threadIdx.x, w = tid >> 6, lane = tid & 63;
  const int l15 = lane & 15, lg = lane >> 4;
  __shared__ u16 Kh[2][64 * 64];            // XOR-swizzled rows
  __shared__ u16 Kl[2][64 * 64];
  __shared__ __align__(16) u16 Vth[64 * 72];
  __shared__ __align__(16) u16 Vtl[64 * 72];
  __shared__ u32 Pp[4][16 * 68];            // packed hi|lo, stride 68

  short8 qh[2], qlo[2];
  {
    const size_t qbase = (size_t)(q0 + w * 16 + l15) * 3072 + head * 64;
    qh[0]  = *(const short8*)(const void*)(Qh + qbase + lg * 8);
    qh[1]  = *(const short8*)(const void*)(Qh + qbase + 32 + lg * 8);
    qlo[0] = *(const short8*)(const void*)(Ql + qbase + lg * 8);
    qlo[1] = *(const short8*)(const void*)(Ql + qbase + 32 + lg * 8);
  }
  f32x4 oacc[4] = {};
  float m_run[4], l_run[4];
#pragma unroll
  for (int r = 0; r < 4; ++r) { m_run[r] = -__builtin_inff(); l_run[r] = 0.f; }
  const int qrow0 = q0 + w * 16 + lg * 4;

  const int vhl = tid >> 7, rem = tid & 127;
  const int vkq = rem & 15, vdg = rem >> 4;
  const u16* vbase = (vhl ? Ql : Qh) + 2048 + head * 64 + vdg * 8;
  u16* vdst = vhl ? Vtl : Vth;
  short8 vr[4];

  auto STAGEK = [&](int kt, int buf) {
#pragma unroll
    for (int i = 0; i < 2; ++i) {
      const int inst = w * 2 + i;
      const int key = inst * 8 + (lane >> 3);
      const int db = ((lane & 7) * 16) ^ ((key & 7) << 4);
      gl_lds16((const char*)(Qh + (size_t)(kt * 64 + key) * 3072 + 1024 + head * 64) + db,
               (char*)Kh + buf * 8192 + inst * 1024);
      gl_lds16((const char*)(Ql + (size_t)(kt * 64 + key) * 3072 + 1024 + head * 64) + db,
               (char*)Kl + buf * 8192 + inst * 1024);
    }
  };
  auto VLOAD = [&](int kt) {
    const u16* vs = vbase + (size_t)(kt * 64 + vkq * 4) * 3072;
    vr[0] = *(const short8*)(const void*)vs;
    vr[1] = *(const short8*)(const void*)(vs + 3072);
    vr[2] = *(const short8*)(const void*)(vs + 6144);
    vr[3] = *(const short8*)(const void*)(vs + 9216);
  };
  auto VWRITE = [&]() {
#pragma unroll
    for (int jj = 0; jj < 8; ++jj) {
      const u64 pk = (u64)(u16)vr[0][jj] | ((u64)(u16)vr[1][jj] << 16) |
                     ((u64)(u16)vr[2][jj] << 32) | ((u64)(u16)vr[3][jj] << 48);
      *(u64*)(void*)(vdst + (vdg * 8 + jj) * 72 + vkq * 4) = pk;
    }
  };

  if (t0 < t1) {
    STAGEK(t0, 0);
    VLOAD(t0);
    VWRITE();
    __syncthreads();
  }
  for (int t = t0; t < t1; ++t) {
    const int cur = (t - t0) & 1;
    const int k0 = t * 64;
    const bool more = (t + 1 < t1);
    if (more) { STAGEK(t + 1, cur ^ 1); VLOAD(t + 1); }
    // ---- QK^T: 3-term split
    f32x4 sacc[4];
    __builtin_amdgcn_s_setprio(1);
#pragma unroll
    for (int nt = 0; nt < 4; ++nt) {
      const int key = nt * 16 + l15;
      const char* kbh = (const char*)Kh + cur * 8192 + key * 128;
      const char* kbl = (const char*)Kl + cur * 8192 + key * 128;
      const int sw = (key & 7) << 4;
      const short8 kh0 = *(const short8*)(const void*)(kbh + ((lg * 16) ^ sw));
      const short8 kh1 = *(const short8*)(const void*)(kbh + ((64 + lg * 16) ^ sw));
      const short8 kl0 = *(const short8*)(const void*)(kbl + ((lg * 16) ^ sw));
      const short8 kl1 = *(const short8*)(const void*)(kbl + ((64 + lg * 16) ^ sw));
      f32x4 s = {};
      s = mfma16(qh[0], kh0, s); s = mfma16(qh[1], kh1, s);
      s = mfma16(qlo[0], kh0, s); s = mfma16(qlo[1], kh1, s);
      s = mfma16(qh[0], kl0, s); s = mfma16(qh[1], kl1, s);
      sacc[nt] = s;
    }
    __builtin_amdgcn_s_setprio(0);
    // ---- mask + scale (log2 domain)
#pragma unroll
    for (int nt = 0; nt < 4; ++nt) {
      const int key = k0 + nt * 16 + l15;
#pragma unroll
      for (int r = 0; r < 4; ++r) {
        float sv = sacc[nt][r] * SCL2;
        if (key > qrow0 + r) sv = -__builtin_inff();
        sacc[nt][r] = sv;
      }
    }
    // ---- online softmax with defer-max
    float mx4[4];
#pragma unroll
    for (int r = 0; r < 4; ++r) {
      float mx = fmaxf(fmaxf(sacc[0][r], sacc[1][r]), fmaxf(sacc[2][r], sacc[3][r]));
#pragma unroll
      for (int msk = 8; msk >= 1; msk >>= 1) mx = fmaxf(mx, __shfl_xor(mx, msk, 64));
      mx4[r] = mx;
    }
    const bool grow = (mx4[0] > m_run[0] + 8.f) || (mx4[1] > m_run[1] + 8.f) ||
                      (mx4[2] > m_run[2] + 8.f) || (mx4[3] > m_run[3] + 8.f);
    if (__any(grow)) {
#pragma unroll
      for (int r = 0; r < 4; ++r) {
        const float m_new = fmaxf(m_run[r], mx4[r]);
        const float fac = exp2f(m_run[r] - m_new);
        m_run[r] = m_new;
        l_run[r] *= fac;
#pragma unroll
        for (int nd = 0; nd < 4; ++nd) oacc[nd][r] *= fac;
      }
    }
#pragma unroll
    for (int nt = 0; nt < 4; ++nt)
#pragma unroll
      for (int r = 0; r < 4; ++r) sacc[nt][r] = exp2f(sacc[nt][r] - m_run[r]);
#pragma unroll
    for (int r = 0; r < 4; ++r) {
      float ls = sacc[0][r] + sacc[1][r] + sacc[2][r] + sacc[3][r];
#pragma unroll
      for (int msk = 8; msk >= 1; msk >>= 1) ls += __shfl_xor(ls, msk, 64);
      l_run[r] += ls;
    }
    // ---- packed split P -> per-wave LDS (16 x ds_write_b32)
#pragma unroll
    for (int nt = 0; nt < 4; ++nt)
#pragma unroll
      for (int r = 0; r < 4; ++r) {
        const float p = sacc[nt][r];
        const u16 ph = f2bf(p);
        const u16 pl = f2bf(p - bf2f(ph));
        Pp[w][(lg * 4 + r) * 68 + nt * 16 + l15] = (u32)ph | ((u32)pl << 16);
      }
    // ---- PV: O += PhVh + PlVh + PhVl
    __builtin_amdgcn_s_setprio(1);
#pragma unroll
    for (int kk2 = 0; kk2 < 2; ++kk2) {
      const u32* prow = &Pp[w][l15 * 68 + kk2 * 32 + lg * 8];
      const uint4 pq0 = *(const uint4*)prow;
      const uint4 pq1 = *(const uint4*)(prow + 4);
      union U8 { u32 wd[4]; short8 v; } ph_, pl_;
      ph_.wd[0] = (pq0.x & 0xFFFFu) | (pq0.y << 16);
      ph_.wd[1] = (pq0.z & 0xFFFFu) | (pq0.w << 16);
      ph_.wd[2] = (pq1.x & 0xFFFFu) | (pq1.y << 16);
      ph_.wd[3] = (pq1.z & 0xFFFFu) | (pq1.w << 16);
      pl_.wd[0] = (pq0.x >> 16) | (pq0.y & 0xFFFF0000u);
      pl_.wd[1] = (pq0.z >> 16) | (pq0.w & 0xFFFF0000u);
      pl_.wd[2] = (pq1.x >> 16) | (pq1.y & 0xFFFF0000u);
      pl_.wd[3] = (pq1.z >> 16) | (pq1.w & 0xFFFF0000u);
#pragma unroll
      for (int nd = 0; nd < 4; ++nd) {
        const short8 vbh = *(const short8*)(const void*)((const char*)Vth + (nd * 16 + l15) * 144 + kk2 * 64 + lg * 16);
        const short8 vbl = *(const short8*)(const void*)((const char*)Vtl + (nd * 16 + l15) * 144 + kk2 * 64 + lg * 16);
        oacc[nd] = mfma16(ph_.v, vbh, oacc[nd]);
        oacc[nd] = mfma16(pl_.v, vbh, oacc[nd]);
        oacc[nd] = mfma16(ph_.v, vbl, oacc[nd]);
      }
    }
    __builtin_amdgcn_s_setprio(0);
    __syncthreads();            // PV reads done; drains K(t+1) stage + V loads
    if (more) VWRITE();
    __syncthreads();            // V(t+1) published
  }
  float* Op = Opart + (size_t)half * S * 1024;
#pragma unroll
  for (int nd = 0; nd < 4; ++nd)
#pragma unroll
    for (int r = 0; r < 4; ++r)
      Op[(size_t)(qrow0 + r) * 1024 + head * 64 + nd * 16 + l15] = oacc[nd][r];
  if (l15 == 0) {
#pragma unroll
    for (int r = 0; r < 4; ++r)
      ml[((size_t)half * S + qrow0 + r) * NH + head] = make_float2(m_run[r], l_run[r]);
  }
}

// ================================================= combine split-K attention partials
__global__ __launch_bounds__(256) void attn_combine(const float* __restrict__ Op,
    const float2* __restrict__ ml, u16* __restrict__ OA2) {
  const int t = blockIdx.x, tid = threadIdx.x;
  const int h = tid >> 4, dq = (tid & 15) * 4;
  const float2 a = ml[(size_t)t * NH + h];
  const float2 b = ml[((size_t)S + t) * NH + h];
  const float m = fmaxf(a.x, b.x);
  const float e0 = exp2f(a.x - m);
  const float e1 = (b.y > 0.f) ? exp2f(b.x - m) : 0.f;
  const float inv = 1.f / (e0 * a.y + e1 * b.y);
  const float4 v0 = *(const float4*)(Op + (size_t)t * 1024 + h * 64 + dq);
  const float4 v1 = *(const float4*)(Op + (size_t)S * 1024 + (size_t)t * 1024 + h * 64 + dq);
  const float ov[4] = {(e0 * v0.x + e1 * v1.x) * inv, (e0 * v0.y + e1 * v1.y) * inv,
                       (e0 * v0.z + e1 * v1.z) * inv, (e0 * v0.w + e1 * v1.w) * inv};
#pragma unroll
  for (int c = 0; c < 4; ++c) {
    const size_t idx = (size_t)t * 2048 + h * 64 + dq + c;
    const u16 hb = f2bf(ov[c]);
    OA2[idx] = hb;
    OA2[idx + 1024] = f2bf(ov[c] - bf2f(hb));
  }
}

// ================================================= res2 + rmsnorm2 fused
__global__ __launch_bounds__(256) void rmsnorm_res2(const float* __restrict__ hidden,
    const float* __restrict__ p0, const float* __restrict__ p1, const float* __restrict__ w2,
    float* __restrict__ out, u16* __restrict__ yb, float* __restrict__ rstab) {
  const int t = blockIdx.x;
  float v[4]; float ss = 0.f;
#pragma unroll
  for (int i = 0; i < 4; ++i) {
    const size_t idx = (size_t)t * D + threadIdx.x + i * 256;
    const float r = hidden[idx] + p0[idx] + p1[idx];
    v[i] = r; ss += r * r;
  }
#pragma unroll
  for (int m = 32; m >= 1; m >>= 1) ss += __shfl_xor(ss, m, 64);
  __shared__ float red[4];
  if ((threadIdx.x & 63) == 0) red[threadIdx.x >> 6] = ss;
  __syncthreads();
  const float rs = rsqrtf((red[0] + red[1] + red[2] + red[3]) * (1.f / (float)D) + EPS);
#pragma unroll
  for (int i = 0; i < 4; ++i) {
    const int d = threadIdx.x + i * 256;
    const size_t idx = (size_t)t * D + d;
    out[idx] = v[i];
    yb[idx] = f2bf(v[i] * rs * w2[d]);
  }
  if (threadIdx.x == 0) rstab[t] = rs;
}

// ================================================= gate + top-2 + scatter (fused)
__global__ __launch_bounds__(256) void gate_scatter(const float* __restrict__ res2,
    const float* __restrict__ w2, const float* __restrict__ rstab,
    const float* __restrict__ GW, int* __restrict__ counts, int* __restrict__ tok_map,
    float* __restrict__ w_map) {
  const int t = blockIdx.x;
  const int e = threadIdx.x & 7;
  const int c = threadIdx.x >> 3;
  float p = 0.f;
  for (int d = c; d < D; d += 32) p += res2[(size_t)t * D + d] * w2[d] * GW[d * NE + e];
  __shared__ float part[32][8];
  part[c][e] = p;
  __syncthreads();
  __shared__ float lg[8];
  if (threadIdx.x < 8) {
    float sAcc = 0.f;
    for (int i = 0; i < 32; ++i) sAcc += part[i][threadIdx.x];
    lg[threadIdx.x] = sAcc;
  }
  __syncthreads();
  if (threadIdx.x == 0) {
    const float rs = rstab[t];
    int i0 = 0; float v0 = lg[0];
    for (int i = 1; i < 8; ++i) if (lg[i] > v0) { v0 = lg[i]; i0 = i; }
    int i1 = -1; float v1 = -__builtin_inff();
    for (int i = 0; i < 8; ++i) if (i != i0 && lg[i] > v1) { v1 = lg[i]; i1 = i; }
    const float e1 = expf((v1 - v0) * rs);
    const float inv = 1.f / (1.f + e1);
    const int p0 = atomicAdd(&counts[i0], 1);
    tok_map[i0 * S + p0] = t; w_map[i0 * S + p0] = inv;
    const int p1 = atomicAdd(&counts[i1], 1);
    tok_map[i1 * S + p1] = t; w_map[i1 * S + p1] = e1 * inv;
  }
}

// ================================================= MoE gate/up GEMM (dual-B), bf16, dbuf
__global__ __launch_bounds__(256) void moe_gu(const u16* __restrict__ Yb,
    const u16* __restrict__ Wgb, const u16* __restrict__ Wub, u16* __restrict__ Hb,
    const int* __restrict__ counts, const int* __restrict__ tokmap) {
  const int e = blockIdx.z;
  const int cnt = counts[e];
  const int m0 = blockIdx.y * 128;
  if (m0 >= cnt) return;
  const int n0 = blockIdx.x * 128;
  __shared__ u16 As[2][128 * 32];
  __shared__ u16 B1s[2][128 * 32];
  __shared__ u16 B2s[2][128 * 32];
  const int tid = threadIdx.x, wv = tid >> 6, lane = tid & 63;
  const int l15 = lane & 15, lg = lane >> 4;
  const int wr = wv >> 1, wc = wv & 1;
  const int sr = lane >> 2, sk = (lane & 3) * 16;
  const u16* B1 = Wgb + (size_t)e * 1024 * 1024;
  const u16* B2 = Wub + (size_t)e * 1024 * 1024;
  int ia[2];
  const u16* aptr[2]; const u16* b1p[2]; const u16* b2p[2];
#pragma unroll
  for (int i = 0; i < 2; ++i) {
    ia[i] = wv + i * 4;
    const int arow = m0 + ia[i] * 16 + sr;
    aptr[i] = Yb + (size_t)tokmap[e * S + arow] * 1024;
    b1p[i] = B1 + (size_t)(n0 + ia[i] * 16 + sr) * 1024;
    b2p[i] = B2 + (size_t)(n0 + ia[i] * 16 + sr) * 1024;
  }
  auto STAGE = [&](int buf, int k) {
#pragma unroll
    for (int i = 0; i < 2; ++i) {
      gl_lds16((const char*)(aptr[i] + k) + sk, (char*)As + buf * 8192 + ia[i] * 1024);
      gl_lds16((const char*)(b1p[i] + k) + sk, (char*)B1s + buf * 8192 + ia[i] * 1024);
      gl_lds16((const char*)(b2p[i] + k) + sk, (char*)B2s + buf * 8192 + ia[i] * 1024);
    }
  };
  f32x4 acc1[4][4] = {};
  f32x4 acc2[4][4] = {};
  STAGE(0, 0);
  __syncthreads();
  int cur = 0;
  for (int kk = 0; kk < 32; ++kk) {
    if (kk < 31) STAGE(cur ^ 1, (kk + 1) * 32);
    const u16* Ab = (const u16*)As + cur * 4096;
    const u16* B1b_ = (const u16*)B1s + cur * 4096;
    const u16* B2b_ = (const u16*)B2s + cur * 4096;
    short8 a[4], b1f[4], b2f[4];
#pragma unroll
    for (int i = 0; i < 4; ++i)
      a[i] = *(const short8*)(const void*)(Ab + (size_t)(wr * 64 + i * 16 + l15) * 32 + lg * 8);
#pragma unroll
    for (int j = 0; j < 4; ++j) {
      b1f[j] = *(const short8*)(const void*)(B1b_ + (size_t)(wc * 64 + j * 16 + l15) * 32 + lg * 8);
      b2f[j] = *(const short8*)(const void*)(B2b_ + (size_t)(wc * 64 + j * 16 + l15) * 32 + lg * 8);
    }
    __builtin_amdgcn_s_setprio(1);
#pragma unroll
    for (int i = 0; i < 4; ++i)
#pragma unroll
      for (int j = 0; j < 4; ++j) {
        acc1[i][j] = mfma16(a[i], b1f[j], acc1[i][j]);
        acc2[i][j] = mfma16(a[i], b2f[j], acc2[i][j]);
      }
    __builtin_amdgcn_s_setprio(0);
    __syncthreads();
    cur ^= 1;
  }
#pragma unroll
  for (int i = 0; i < 4; ++i)
#pragma unroll
    for (int j = 0; j < 4; ++j)
#pragma unroll
      for (int r = 0; r < 4; ++r) {
        const int row = m0 + wr * 64 + i * 16 + lg * 4 + r;
        if (row < cnt) {
          const float g = acc1[i][j][r];
          const float u = acc2[i][j][r];
          const float h = u * (g / (1.f + expf(-g)));
          Hb[((size_t)e * 2048 + row) * 1024 + n0 + wc * 64 + j * 16 + l15] = f2bf(h);
        }
      }
}

// ================================================= MoE down GEMM -> atomic f32 into out
__global__ __launch_bounds__(256) void moe_down(const u16* __restrict__ Hb,
    const u16* __restrict__ Wdb, float* __restrict__ out,
    const int* __restrict__ counts, const int* __restrict__ tokmap,
    const float* __restrict__ wmap) {
  const int e = blockIdx.z;
  const int cnt = counts[e];
  const int m0 = blockIdx.y * 128;
  if (m0 >= cnt) return;
  const int n0 = blockIdx.x * 128;
  __shared__ u16 As[2][128 * 32];
  __shared__ u16 Bs[2][128 * 32];
  const int tid = threadIdx.x, wv = tid >> 6, lane = tid & 63;
  const int l15 = lane & 15, lg = lane >> 4;
  const int wr = wv >> 1, wc = wv & 1;
  const int sr = lane >> 2, sk = (lane & 3) * 16;
  const u16* B = Wdb + (size_t)e * 1024 * 1024;
  const u16* aptr[2]; const u16* bptr[2];
#pragma unroll
  for (int i = 0; i < 2; ++i) {
    aptr[i] = Hb + ((size_t)e * 2048 + m0 + (wv * 2 + i) * 16 + sr) * 1024;
    bptr[i] = B + (size_t)(n0 + (wv * 2 + i) * 16 + sr) * 1024;
  }
  auto STAGE = [&](int buf, int k) {
#pragma unroll
    for (int i = 0; i < 2; ++i) {
      gl_lds16((const char*)(aptr[i] + k) + sk, (char*)As + buf * 8192 + (wv * 2 + i) * 1024);
      gl_lds16((const char*)(bptr[i] + k) + sk, (char*)Bs + buf * 8192 + (wv * 2 + i) * 1024);
    }
  };
  f32x4 acc[4][4] = {};
  STAGE(0, 0);
  __syncthreads();
  int cur = 0;
  for (int kk = 0; kk < 32; ++kk) {
    if (kk < 31) STAGE(cur ^ 1, (kk + 1) * 32);
    const u16* Ab = (const u16*)As + cur * 4096;
    const u16* Bb = (const u16*)Bs + cur * 4096;
    short8 a[4], b[4];
#pragma unroll
    for (int i = 0; i < 4; ++i)
      a[i] = *(const short8*)(const void*)(Ab + (size_t)(wr * 64 + i * 16 + l15) * 32 + lg * 8);
#pragma unroll
    for (int j = 0; j < 4; ++j)
      b[j] = *(const short8*)(const void*)(Bb + (size_t)(wc * 64 + j * 16 + l15) * 32 + lg * 8);
    __builtin_amdgcn_s_setprio(1);
#pragma unroll
    for (int i = 0; i < 4; ++i)
#pragma unroll
      for (int j = 0; j < 4; ++j) acc[i][j] = mfma16(a[i], b[j], acc[i][j]);
    __builtin_amdgcn_s_setprio(0);
    __syncthreads();
    cur ^= 1;
  }
#pragma unroll
  for (int i = 0; i < 4; ++i)
#pragma unroll
    for (int j = 0; j < 4; ++j)
#pragma unroll
      for (int r = 0; r < 4; ++r) {
        const int row = m0 + wr * 64 + i * 16 + lg * 4 + r;
        if (row < cnt) {
          const int t = tokmap[e * S + row];
          const float wgt = wmap[e * S + row];
          atomicAdd(&out[(size_t)t * 1024 + n0 + wc * 64 + j * 16 + l15], wgt * acc[i][j][r]);
        }
      }
}

// ================================================= launch
extern "C" void kernel_launch(void* const* d_in, const int* in_sizes, int n_in,
                              void* d_out, int out_size, void* d_ws, size_t ws_size,
                              hipStream_t stream) {
  const int*   positions = (const int*)d_in[0];
  const float* hidden    = (const float*)d_in[1];
  const float* ln1_w  = (const float*)d_in[3];
  const float* ln2_w  = (const float*)d_in[4];
  const float* wqkv   = (const float*)d_in[5];
  const float* wo     = (const float*)d_in[6];
  const float* gate_w = (const float*)d_in[7];
  const float* wg     = (const float*)d_in[8];
  const float* wu     = (const float*)d_in[9];
  const float* wd     = (const float*)d_in[10];
  float* out = (float*)d_out;

  char* ws = (char*)d_ws;
  const size_t MB = 1ull << 20;
  u16* wqkvT2 = (u16*)(ws);                 // 12MB  [persist]
  u16* woT2   = (u16*)(ws + 12 * MB);       // 4MB   [persist]
  u16* wgT    = (u16*)(ws + 16 * MB);       // 16MB  [persist]
  u16* wuT    = (u16*)(ws + 32 * MB);       // 16MB  [persist]
  u16* wdT    = (u16*)(ws + 48 * MB);       // 16MB  [persist]
  float2* ropetab = (float2*)(ws + 64 * MB);          // 512KB
  float2* ml      = (float2*)(ws + 64 * MB + 524288); // 512KB
  char* mapb = ws + 65 * MB;
  int*   counts   = (int*)mapb;
  int*   tok_map  = (int*)(mapb + 8192);
  float* w_map    = (float*)(mapb + 8192 + 65536);
  float* rstab    = (float*)(mapb + 8192 + 131072);
  u16* xn2   = (u16*)(ws + 66 * MB);        // 8MB  (dead after QKV)
  u16* OA2   = xn2;                         // 8MB  (combine->Wo)
  u16* yb    = xn2;                         // 4MB  (MoE phase; OA2 dead)
  u16* QKVh  = (u16*)(ws + 74 * MB);        // 12MB (dead after attn)
  u16* Hb    = (u16*)(ws + 74 * MB);        // 32MB (MoE phase)
  u16* QKVl  = (u16*)(ws + 86 * MB);        // 12MB (dead after attn)
  float* Opart = (float*)(ws + 106 * MB);   // 16MB (attn partials; then Wo partials)
  float* p01   = Opart;

  // --- prep: weight transforms + rope table (one launch)
  prep_kernel<<<7424, 256, 0, stream>>>(wqkv, wo, wg, wu, wd, positions,
                                        wqkvT2, woT2, wgT, wuT, wdT, ropetab);
  // --- attention path (split-bf16)
  rmsnorm_split<<<S, 256, 0, stream>>>(hidden, ln1_w, xn2);
  gemm_qkv<<<dim3(48, 16), 256, 0, stream>>>(xn2, wqkvT2, ropetab, QKVh, QKVl);
  attn_mfma<<<1024, 256, 0, stream>>>(QKVh, QKVl, Opart, ml);
  attn_combine<<<S, 256, 0, stream>>>(Opart, ml, OA2);
  gemm_wo<<<dim3(16, 16, 2), 256, 0, stream>>>(OA2, woT2, p01);
  rmsnorm_res2<<<S, 256, 0, stream>>>(hidden, p01, p01 + (size_t)S * D, ln2_w, out, yb, rstab);
  // --- gating + MoE
  hipMemsetAsync(counts, 0, NE * sizeof(int), stream);
  hipMemsetAsync(tok_map, 0, NE * S * sizeof(int), stream);
  gate_scatter<<<S, 256, 0, stream>>>(out, ln2_w, rstab, gate_w, counts, tok_map, w_map);
  moe_gu<<<dim3(8, 16, 8), 256, 0, stream>>>(yb, wgT, wuT, Hb, counts, tok_map);
  moe_down<<<dim3(8, 16, 8), 256, 0, stream>>>(Hb, wdT, out, counts, tok_map, w_map);
}

// Round 5
// 418.250 us; speedup vs baseline: 3.4962x; 1.0757x over previous
//
#include <hip/hip_runtime.h>
#include <math.h>

constexpr int S  = 2048;
constexpr int D  = 1024;
constexpr int NH = 16;
constexpr int NE = 8;
constexpr float EPS   = 1e-6f;
constexpr float THETA = 10000.0f;
constexpr float SCL2  = 0.125f * 1.4426950408889634f;  // attn scale * log2(e)
constexpr float LOG2E = 1.4426950408889634f;

typedef unsigned short u16;
typedef unsigned int   u32;
typedef unsigned long long u64;
typedef __attribute__((ext_vector_type(8))) short short8;
typedef __attribute__((ext_vector_type(4))) float f32x4;

__device__ __forceinline__ u16 f2bf(float x) {
  union { float f; u32 u; } v; v.f = x;
  u32 r = (v.u + 0x7FFFu + ((v.u >> 16) & 1u)) >> 16;
  return (u16)r;
}
__device__ __forceinline__ float bf2f(u16 h) {
  union { u32 u; float f; } v; v.u = ((u32)h) << 16;
  return v.f;
}
__device__ __forceinline__ f32x4 mfma16(short8 a, short8 b, f32x4 c) {
  return __builtin_amdgcn_mfma_f32_16x16x32_bf16(a, b, c, 0, 0, 0);
}
__device__ __forceinline__ void gl_lds16(const void* g, void* l) {
  __builtin_amdgcn_global_load_lds((const __attribute__((address_space(1))) u32*)g,
                                   (__attribute__((address_space(3))) u32*)l, 16, 0, 0);
}

// ================================================= unified prep kernel
__global__ __launch_bounds__(256) void prep_kernel(const float* __restrict__ wqkv,
    const float* __restrict__ wo, const float* __restrict__ wg, const float* __restrict__ wu,
    const float* __restrict__ wd, const int* __restrict__ positions,
    u16* __restrict__ wqkvT2, u16* __restrict__ woT2, u16* __restrict__ wgT,
    u16* __restrict__ wuT, u16* __restrict__ wdT, float2* __restrict__ ropetab) {
  const int b = blockIdx.x;
  const int tid = threadIdx.x;
  if (b >= 7168) {  // rope table
    const int idx = (b - 7168) * 256 + tid;
    const int t = idx >> 5, p = idx & 31;
    const float inv = powf(THETA, -(float)p * (1.f / 32.f));
    const float fr = (float)positions[t] * inv;
    float sn, cs; sincosf(fr, &sn, &cs);
    ropetab[idx] = make_float2(cs, sn);
    return;
  }
  __shared__ float t_[64][65];
  const float* W; u16* out; int K, N, n0, k0; bool split;
  if (b < 768) {
    W = wqkv; out = wqkvT2; K = 1024; N = 3072; split = true;
    n0 = (b % 48) * 64; k0 = (b / 48) * 64;
  } else if (b < 1024) {
    W = wo; out = woT2; K = 1024; N = 1024; split = true;
    const int r = b - 768; n0 = (r & 15) * 64; k0 = (r >> 4) * 64;
  } else {
    int r, e;
    if (b < 3072)      { r = b - 1024; e = r >> 8; W = wg + (size_t)e * 1048576; out = wgT + (size_t)e * 1048576; }
    else if (b < 5120) { r = b - 3072; e = r >> 8; W = wu + (size_t)e * 1048576; out = wuT + (size_t)e * 1048576; }
    else               { r = b - 5120; e = r >> 8; W = wd + (size_t)e * 1048576; out = wdT + (size_t)e * 1048576; }
    K = 1024; N = 1024; split = false;
    r &= 255; n0 = (r & 15) * 64; k0 = (r >> 4) * 64;
  }
  const int rr = tid >> 4, c4 = (tid & 15) * 4;
#pragma unroll
  for (int i = 0; i < 4; ++i) {
    const float4 v = *(const float4*)(W + (size_t)(k0 + rr + i * 16) * N + n0 + c4);
    t_[rr + i * 16][c4 + 0] = v.x; t_[rr + i * 16][c4 + 1] = v.y;
    t_[rr + i * 16][c4 + 2] = v.z; t_[rr + i * 16][c4 + 3] = v.w;
  }
  __syncthreads();
  if (split) {
#pragma unroll
    for (int i = 0; i < 4; ++i) {
      const int n = n0 + rr + i * 16;
      u16* oh = out + (size_t)n * 2048 + k0 + c4;
      u16* ol = oh + 1024;
#pragma unroll
      for (int j = 0; j < 4; ++j) {
        const float v = t_[c4 + j][rr + i * 16];
        const u16 h = f2bf(v);
        oh[j] = h; ol[j] = f2bf(v - bf2f(h));
      }
    }
  } else {
#pragma unroll
    for (int i = 0; i < 4; ++i) {
      const int n = n0 + rr + i * 16;
      u16* o = out + (size_t)n * 1024 + k0 + c4;
#pragma unroll
      for (int j = 0; j < 4; ++j) o[j] = f2bf(t_[c4 + j][rr + i * 16]);
    }
  }
}

// ================================================= rmsnorm -> split bf16 [t][2048]
__global__ __launch_bounds__(256) void rmsnorm_split(const float* __restrict__ x,
    const float* __restrict__ w, u16* __restrict__ out2) {
  const int t = blockIdx.x;
  const float* xr = x + (size_t)t * D;
  float v[4]; float ss = 0.f;
#pragma unroll
  for (int i = 0; i < 4; ++i) { v[i] = xr[threadIdx.x + i * 256]; ss += v[i] * v[i]; }
#pragma unroll
  for (int m = 32; m >= 1; m >>= 1) ss += __shfl_xor(ss, m, 64);
  __shared__ float red[4];
  if ((threadIdx.x & 63) == 0) red[threadIdx.x >> 6] = ss;
  __syncthreads();
  const float rs = rsqrtf((red[0] + red[1] + red[2] + red[3]) * (1.f / (float)D) + EPS);
#pragma unroll
  for (int i = 0; i < 4; ++i) {
    const int d = threadIdx.x + i * 256;
    const float y = v[i] * rs * w[d];
    const u16 h = f2bf(y);
    out2[(size_t)t * 2048 + d] = h;
    out2[(size_t)t * 2048 + 1024 + d] = f2bf(y - bf2f(h));
  }
}

// ================================================= QKV GEMM: 128x128, split-bf16, dbuf, XCD-swz, RoPE epi
// grid flat 384: xcd=b&7 -> n-panels [xcd*3, xcd*3+3), m fastest (B L2-resident per XCD)
__global__ __launch_bounds__(256) void gemm_qkv(const u16* __restrict__ A2,
    const u16* __restrict__ Bt2, const float2* __restrict__ tab,
    u16* __restrict__ Ch, u16* __restrict__ Cl) {
  constexpr int N = 3072;
  __shared__ u16 As[2][128 * 32];
  __shared__ u16 Bs[2][128 * 32];
  const int b = blockIdx.x;
  const int xcd = b & 7, ii = b >> 3;
  const int n0 = (xcd * 3 + (ii >> 4)) * 128;
  const int m0 = (ii & 15) * 128;
  const int tid = threadIdx.x, wv = tid >> 6, lane = tid & 63;
  const int l15 = lane & 15, lg = lane >> 4;
  const int wr = wv >> 1, wc = wv & 1;
  const int sr = lane >> 2, sk = (lane & 3) * 16;
  const u16* aptr[2]; const u16* bptr[2];
#pragma unroll
  for (int i = 0; i < 2; ++i) {
    aptr[i] = A2 + (size_t)(m0 + (wv * 2 + i) * 16 + sr) * 2048;
    bptr[i] = Bt2 + (size_t)(n0 + (wv * 2 + i) * 16 + sr) * 2048;
  }
  auto STAGE = [&](int buf, int kk) {
    const int t = kk * 32;
    int ka, kb;
    if (t < 1024)      { ka = t;        kb = t; }
    else if (t < 2048) { ka = t;        kb = t - 1024; }
    else               { ka = t - 2048; kb = t - 1024; }
#pragma unroll
    for (int i = 0; i < 2; ++i) {
      gl_lds16((const char*)(aptr[i] + ka) + sk, (char*)As + buf * 8192 + (wv * 2 + i) * 1024);
      gl_lds16((const char*)(bptr[i] + kb) + sk, (char*)Bs + buf * 8192 + (wv * 2 + i) * 1024);
    }
  };
  f32x4 acc[4][4] = {};
  STAGE(0, 0);
  __syncthreads();
  int cur = 0;
  for (int kk = 0; kk < 96; ++kk) {
    if (kk < 95) STAGE(cur ^ 1, kk + 1);
    const u16* Ab = (const u16*)As + cur * 4096;
    const u16* Bb = (const u16*)Bs + cur * 4096;
    short8 a[4], bb[4];
#pragma unroll
    for (int i = 0; i < 4; ++i)
      a[i] = *(const short8*)(const void*)(Ab + (size_t)(wr * 64 + i * 16 + l15) * 32 + lg * 8);
#pragma unroll
    for (int j = 0; j < 4; ++j)
      bb[j] = *(const short8*)(const void*)(Bb + (size_t)(wc * 64 + j * 16 + l15) * 32 + lg * 8);
    __builtin_amdgcn_s_setprio(1);
#pragma unroll
    for (int i = 0; i < 4; ++i)
#pragma unroll
      for (int j = 0; j < 4; ++j) acc[i][j] = mfma16(a[i], bb[j], acc[i][j]);
    __builtin_amdgcn_s_setprio(0);
    __syncthreads();
    cur ^= 1;
  }
  const bool isqk = (n0 < 2048);
#pragma unroll
  for (int i = 0; i < 4; ++i)
#pragma unroll
    for (int j2 = 0; j2 < 2; ++j2)
#pragma unroll
      for (int r = 0; r < 4; ++r) {
        const int row = m0 + wr * 64 + i * 16 + lg * 4 + r;
        const int p = j2 * 16 + l15;  // head-local in [0,32)
        float y1 = acc[i][j2][r], y2 = acc[i][j2 + 2][r];
        if (isqk) {
          const float2 cs = tab[row * 32 + p];
          const float x1 = y1, x2 = y2;
          y1 = x1 * cs.x - x2 * cs.y;
          y2 = x1 * cs.y + x2 * cs.x;
        }
        const size_t base = (size_t)row * N + n0 + wc * 64 + p;
        const u16 h1 = f2bf(y1);
        Ch[base] = h1; Cl[base] = f2bf(y1 - bf2f(h1));
        const u16 h2 = f2bf(y2);
        Ch[base + 32] = h2; Cl[base + 32] = f2bf(y2 - bf2f(h2));
      }
}

// ================================================= Wo GEMM: 128x128, split-bf16, dbuf, XCD-swz, Kx2
// grid flat 256: xcd=b&7 -> n-panel xcd; ii=b>>3: m=ii&15 (fast), ks=ii>>4
__global__ __launch_bounds__(256) void gemm_wo(const u16* __restrict__ A2,
    const u16* __restrict__ Bt2, float* __restrict__ Pout) {
  constexpr int N = 1024;
  __shared__ u16 As[2][128 * 32];
  __shared__ u16 Bs[2][128 * 32];
  const int b = blockIdx.x;
  const int xcd = b & 7, ii = b >> 3;
  const int n0 = xcd * 128;
  const int m0 = (ii & 15) * 128;
  const int ks = ii >> 4;
  const int kk0 = ks * 48, kk1 = kk0 + 48;
  const int tid = threadIdx.x, wv = tid >> 6, lane = tid & 63;
  const int l15 = lane & 15, lg = lane >> 4;
  const int wr = wv >> 1, wc = wv & 1;
  const int sr = lane >> 2, sk = (lane & 3) * 16;
  const u16* aptr[2]; const u16* bptr[2];
#pragma unroll
  for (int i = 0; i < 2; ++i) {
    aptr[i] = A2 + (size_t)(m0 + (wv * 2 + i) * 16 + sr) * 2048;
    bptr[i] = Bt2 + (size_t)(n0 + (wv * 2 + i) * 16 + sr) * 2048;
  }
  auto STAGE = [&](int buf, int kk) {
    const int t = kk * 32;
    int ka, kb;
    if (t < 1024)      { ka = t;        kb = t; }
    else if (t < 2048) { ka = t;        kb = t - 1024; }
    else               { ka = t - 2048; kb = t - 1024; }
#pragma unroll
    for (int i = 0; i < 2; ++i) {
      gl_lds16((const char*)(aptr[i] + ka) + sk, (char*)As + buf * 8192 + (wv * 2 + i) * 1024);
      gl_lds16((const char*)(bptr[i] + kb) + sk, (char*)Bs + buf * 8192 + (wv * 2 + i) * 1024);
    }
  };
  f32x4 acc[4][4] = {};
  STAGE(0, kk0);
  __syncthreads();
  int cur = 0;
  for (int kk = kk0; kk < kk1; ++kk) {
    if (kk + 1 < kk1) STAGE(cur ^ 1, kk + 1);
    const u16* Ab = (const u16*)As + cur * 4096;
    const u16* Bb = (const u16*)Bs + cur * 4096;
    short8 a[4], bb[4];
#pragma unroll
    for (int i = 0; i < 4; ++i)
      a[i] = *(const short8*)(const void*)(Ab + (size_t)(wr * 64 + i * 16 + l15) * 32 + lg * 8);
#pragma unroll
    for (int j = 0; j < 4; ++j)
      bb[j] = *(const short8*)(const void*)(Bb + (size_t)(wc * 64 + j * 16 + l15) * 32 + lg * 8);
    __builtin_amdgcn_s_setprio(1);
#pragma unroll
    for (int i = 0; i < 4; ++i)
#pragma unroll
      for (int j = 0; j < 4; ++j) acc[i][j] = mfma16(a[i], bb[j], acc[i][j]);
    __builtin_amdgcn_s_setprio(0);
    __syncthreads();
    cur ^= 1;
  }
  float* P = Pout + (size_t)ks * S * N;
#pragma unroll
  for (int i = 0; i < 4; ++i)
#pragma unroll
    for (int j = 0; j < 4; ++j)
#pragma unroll
      for (int r = 0; r < 4; ++r) {
        const int row = m0 + wr * 64 + i * 16 + lg * 4 + r;
        const int col = n0 + wc * 64 + j * 16 + l15;
        P[(size_t)row * N + col] = acc[i][j][r];
      }
}

// ================================================= MFMA flash attention
__global__ __launch_bounds__(256) void attn_mfma(const u16* __restrict__ Qh,
    const u16* __restrict__ Ql, float* __restrict__ Opart, float2* __restrict__ ml) {
  const int b = blockIdx.x;
  const int head = (b & 7) + 8 * (b >> 9);
  const int qb = 31 - ((b >> 3) & 31);      // longest first
  const int half = (b >> 8) & 1;
  const int q0 = qb * 64;
  const int ktiles = qb + 1, hsp = (ktiles + 1) >> 1;
  const int t0 = half ? hsp : 0, t1 = half ? ktiles : hsp;
  const int tid = threadIdx.x, w = tid >> 6, lane = tid & 63;
  const int l15 = lane & 15, lg = lane >> 4;
  __shared__ u16 Kh[2][64 * 64];
  __shared__ u16 Kl[2][64 * 64];
  __shared__ __align__(16) u16 Vth[64 * 72];
  __shared__ __align__(16) u16 Vtl[64 * 72];
  __shared__ u32 Pp[4][16 * 68];

  short8 qh[2], qlo[2];
  {
    const size_t qbase = (size_t)(q0 + w * 16 + l15) * 3072 + head * 64;
    qh[0]  = *(const short8*)(const void*)(Qh + qbase + lg * 8);
    qh[1]  = *(const short8*)(const void*)(Qh + qbase + 32 + lg * 8);
    qlo[0] = *(const short8*)(const void*)(Ql + qbase + lg * 8);
    qlo[1] = *(const short8*)(const void*)(Ql + qbase + 32 + lg * 8);
  }
  f32x4 oacc[4] = {};
  float m_run[4], l_run[4];
#pragma unroll
  for (int r = 0; r < 4; ++r) { m_run[r] = -__builtin_inff(); l_run[r] = 0.f; }
  const int qrow0 = q0 + w * 16 + lg * 4;

  const int vhl = tid >> 7, rem = tid & 127;
  const int vkq = rem & 15, vdg = rem >> 4;
  const u16* vbase = (vhl ? Ql : Qh) + 2048 + head * 64 + vdg * 8;
  u16* vdst = vhl ? Vtl : Vth;
  short8 vr[4];

  auto STAGEK = [&](int kt, int buf) {
#pragma unroll
    for (int i = 0; i < 2; ++i) {
      const int inst = w * 2 + i;
      const int key = inst * 8 + (lane >> 3);
      const int db = ((lane & 7) * 16) ^ ((key & 7) << 4);
      gl_lds16((const char*)(Qh + (size_t)(kt * 64 + key) * 3072 + 1024 + head * 64) + db,
               (char*)Kh + buf * 8192 + inst * 1024);
      gl_lds16((const char*)(Ql + (size_t)(kt * 64 + key) * 3072 + 1024 + head * 64) + db,
               (char*)Kl + buf * 8192 + inst * 1024);
    }
  };
  auto VLOAD = [&](int kt) {
    const u16* vs = vbase + (size_t)(kt * 64 + vkq * 4) * 3072;
    vr[0] = *(const short8*)(const void*)vs;
    vr[1] = *(const short8*)(const void*)(vs + 3072);
    vr[2] = *(const short8*)(const void*)(vs + 6144);
    vr[3] = *(const short8*)(const void*)(vs + 9216);
  };
  auto VWRITE = [&]() {
#pragma unroll
    for (int jj = 0; jj < 8; ++jj) {
      const u64 pk = (u64)(u16)vr[0][jj] | ((u64)(u16)vr[1][jj] << 16) |
                     ((u64)(u16)vr[2][jj] << 32) | ((u64)(u16)vr[3][jj] << 48);
      *(u64*)(void*)(vdst + (vdg * 8 + jj) * 72 + vkq * 4) = pk;
    }
  };

  if (t0 < t1) {
    STAGEK(t0, 0);
    VLOAD(t0);
    VWRITE();
    __syncthreads();
  }
  for (int t = t0; t < t1; ++t) {
    const int cur = (t - t0) & 1;
    const int k0 = t * 64;
    const bool more = (t + 1 < t1);
    if (more) { STAGEK(t + 1, cur ^ 1); VLOAD(t + 1); }
    // ---- QK^T: 3-term split
    f32x4 sacc[4];
    __builtin_amdgcn_s_setprio(1);
#pragma unroll
    for (int nt = 0; nt < 4; ++nt) {
      const int key = nt * 16 + l15;
      const char* kbh = (const char*)Kh + cur * 8192 + key * 128;
      const char* kbl = (const char*)Kl + cur * 8192 + key * 128;
      const int sw = (key & 7) << 4;
      const short8 kh0 = *(const short8*)(const void*)(kbh + ((lg * 16) ^ sw));
      const short8 kh1 = *(const short8*)(const void*)(kbh + ((64 + lg * 16) ^ sw));
      const short8 kl0 = *(const short8*)(const void*)(kbl + ((lg * 16) ^ sw));
      const short8 kl1 = *(const short8*)(const void*)(kbl + ((64 + lg * 16) ^ sw));
      f32x4 s = {};
      s = mfma16(qh[0], kh0, s); s = mfma16(qh[1], kh1, s);
      s = mfma16(qlo[0], kh0, s); s = mfma16(qlo[1], kh1, s);
      s = mfma16(qh[0], kl0, s); s = mfma16(qh[1], kl1, s);
      sacc[nt] = s;
    }
    __builtin_amdgcn_s_setprio(0);
    // ---- scale always; mask only on diagonal tile (wave-uniform)
#pragma unroll
    for (int nt = 0; nt < 4; ++nt)
#pragma unroll
      for (int r = 0; r < 4; ++r) sacc[nt][r] *= SCL2;
    if (t == qb) {
#pragma unroll
      for (int nt = 0; nt < 4; ++nt) {
        const int key = k0 + nt * 16 + l15;
#pragma unroll
        for (int r = 0; r < 4; ++r)
          if (key > qrow0 + r) sacc[nt][r] = -__builtin_inff();
      }
    }
    // ---- online softmax with defer-max
    float mx4[4];
#pragma unroll
    for (int r = 0; r < 4; ++r) {
      float mx = fmaxf(fmaxf(sacc[0][r], sacc[1][r]), fmaxf(sacc[2][r], sacc[3][r]));
#pragma unroll
      for (int msk = 8; msk >= 1; msk >>= 1) mx = fmaxf(mx, __shfl_xor(mx, msk, 64));
      mx4[r] = mx;
    }
    const bool grow = (mx4[0] > m_run[0] + 8.f) || (mx4[1] > m_run[1] + 8.f) ||
                      (mx4[2] > m_run[2] + 8.f) || (mx4[3] > m_run[3] + 8.f);
    if (__any(grow)) {
#pragma unroll
      for (int r = 0; r < 4; ++r) {
        const float m_new = fmaxf(m_run[r], mx4[r]);
        const float fac = __builtin_amdgcn_exp2f(m_run[r] - m_new);
        m_run[r] = m_new;
        l_run[r] *= fac;
#pragma unroll
        for (int nd = 0; nd < 4; ++nd) oacc[nd][r] *= fac;
      }
    }
#pragma unroll
    for (int nt = 0; nt < 4; ++nt)
#pragma unroll
      for (int r = 0; r < 4; ++r)
        sacc[nt][r] = __builtin_amdgcn_exp2f(sacc[nt][r] - m_run[r]);
#pragma unroll
    for (int r = 0; r < 4; ++r) {
      float ls = sacc[0][r] + sacc[1][r] + sacc[2][r] + sacc[3][r];
#pragma unroll
      for (int msk = 8; msk >= 1; msk >>= 1) ls += __shfl_xor(ls, msk, 64);
      l_run[r] += ls;
    }
    // ---- packed split P via truncation (exact 2-term, p>=0) -> per-wave LDS
#pragma unroll
    for (int nt = 0; nt < 4; ++nt)
#pragma unroll
      for (int r = 0; r < 4; ++r) {
        const float p = sacc[nt][r];
        const u32 xu = __float_as_uint(p);
        const u32 hi = xu & 0xFFFF0000u;
        const float pl = p - __uint_as_float(hi);
        const u32 lw = __float_as_uint(pl) >> 16;
        Pp[w][(lg * 4 + r) * 68 + nt * 16 + l15] = (xu >> 16) | (lw << 16);
      }
    // ---- PV: O += PhVh + PlVh + PhVl
    __builtin_amdgcn_s_setprio(1);
#pragma unroll
    for (int kk2 = 0; kk2 < 2; ++kk2) {
      const u32* prow = &Pp[w][l15 * 68 + kk2 * 32 + lg * 8];
      const uint4 pq0 = *(const uint4*)prow;
      const uint4 pq1 = *(const uint4*)(prow + 4);
      union U8 { u32 wd[4]; short8 v; } ph_, pl_;
      ph_.wd[0] = (pq0.x & 0xFFFFu) | (pq0.y << 16);
      ph_.wd[1] = (pq0.z & 0xFFFFu) | (pq0.w << 16);
      ph_.wd[2] = (pq1.x & 0xFFFFu) | (pq1.y << 16);
      ph_.wd[3] = (pq1.z & 0xFFFFu) | (pq1.w << 16);
      pl_.wd[0] = (pq0.x >> 16) | (pq0.y & 0xFFFF0000u);
      pl_.wd[1] = (pq0.z >> 16) | (pq0.w & 0xFFFF0000u);
      pl_.wd[2] = (pq1.x >> 16) | (pq1.y & 0xFFFF0000u);
      pl_.wd[3] = (pq1.z >> 16) | (pq1.w & 0xFFFF0000u);
#pragma unroll
      for (int nd = 0; nd < 4; ++nd) {
        const short8 vbh = *(const short8*)(const void*)((const char*)Vth + (nd * 16 + l15) * 144 + kk2 * 64 + lg * 16);
        const short8 vbl = *(const short8*)(const void*)((const char*)Vtl + (nd * 16 + l15) * 144 + kk2 * 64 + lg * 16);
        oacc[nd] = mfma16(ph_.v, vbh, oacc[nd]);
        oacc[nd] = mfma16(pl_.v, vbh, oacc[nd]);
        oacc[nd] = mfma16(ph_.v, vbl, oacc[nd]);
      }
    }
    __builtin_amdgcn_s_setprio(0);
    __syncthreads();
    if (more) VWRITE();
    __syncthreads();
  }
  float* Op = Opart + (size_t)half * S * 1024;
#pragma unroll
  for (int nd = 0; nd < 4; ++nd)
#pragma unroll
    for (int r = 0; r < 4; ++r)
      Op[(size_t)(qrow0 + r) * 1024 + head * 64 + nd * 16 + l15] = oacc[nd][r];
  if (l15 == 0) {
#pragma unroll
    for (int r = 0; r < 4; ++r)
      ml[((size_t)half * S + qrow0 + r) * NH + head] = make_float2(m_run[r], l_run[r]);
  }
}

// ================================================= combine split-K attention partials
__global__ __launch_bounds__(256) void attn_combine(const float* __restrict__ Op,
    const float2* __restrict__ ml, u16* __restrict__ OA2) {
  const int t = blockIdx.x, tid = threadIdx.x;
  const int h = tid >> 4, dq = (tid & 15) * 4;
  const float2 a = ml[(size_t)t * NH + h];
  const float2 b = ml[((size_t)S + t) * NH + h];
  const float m = fmaxf(a.x, b.x);
  const float e0 = exp2f(a.x - m);
  const float e1 = (b.y > 0.f) ? exp2f(b.x - m) : 0.f;
  const float inv = 1.f / (e0 * a.y + e1 * b.y);
  const float4 v0 = *(const float4*)(Op + (size_t)t * 1024 + h * 64 + dq);
  const float4 v1 = *(const float4*)(Op + (size_t)S * 1024 + (size_t)t * 1024 + h * 64 + dq);
  const float ov[4] = {(e0 * v0.x + e1 * v1.x) * inv, (e0 * v0.y + e1 * v1.y) * inv,
                       (e0 * v0.z + e1 * v1.z) * inv, (e0 * v0.w + e1 * v1.w) * inv};
#pragma unroll
  for (int c = 0; c < 4; ++c) {
    const size_t idx = (size_t)t * 2048 + h * 64 + dq + c;
    const u16 hb = f2bf(ov[c]);
    OA2[idx] = hb;
    OA2[idx + 1024] = f2bf(ov[c] - bf2f(hb));
  }
}

// ================================================= res2 + rmsnorm2 fused
__global__ __launch_bounds__(256) void rmsnorm_res2(const float* __restrict__ hidden,
    const float* __restrict__ p0, const float* __restrict__ p1, const float* __restrict__ w2,
    float* __restrict__ out, u16* __restrict__ yb, float* __restrict__ rstab) {
  const int t = blockIdx.x;
  float v[4]; float ss = 0.f;
#pragma unroll
  for (int i = 0; i < 4; ++i) {
    const size_t idx = (size_t)t * D + threadIdx.x + i * 256;
    const float r = hidden[idx] + p0[idx] + p1[idx];
    v[i] = r; ss += r * r;
  }
#pragma unroll
  for (int m = 32; m >= 1; m >>= 1) ss += __shfl_xor(ss, m, 64);
  __shared__ float red[4];
  if ((threadIdx.x & 63) == 0) red[threadIdx.x >> 6] = ss;
  __syncthreads();
  const float rs = rsqrtf((red[0] + red[1] + red[2] + red[3]) * (1.f / (float)D) + EPS);
#pragma unroll
  for (int i = 0; i < 4; ++i) {
    const int d = threadIdx.x + i * 256;
    const size_t idx = (size_t)t * D + d;
    out[idx] = v[i];
    yb[idx] = f2bf(v[i] * rs * w2[d]);
  }
  if (threadIdx.x == 0) rstab[t] = rs;
}

// ================================================= gate + top-2 + scatter (fused)
__global__ __launch_bounds__(256) void gate_scatter(const float* __restrict__ res2,
    const float* __restrict__ w2, const float* __restrict__ rstab,
    const float* __restrict__ GW, int* __restrict__ counts, int* __restrict__ tok_map,
    float* __restrict__ w_map) {
  const int t = blockIdx.x;
  const int e = threadIdx.x & 7;
  const int c = threadIdx.x >> 3;
  float p = 0.f;
  for (int d = c; d < D; d += 32) p += res2[(size_t)t * D + d] * w2[d] * GW[d * NE + e];
  __shared__ float part[32][8];
  part[c][e] = p;
  __syncthreads();
  __shared__ float lg[8];
  if (threadIdx.x < 8) {
    float sAcc = 0.f;
    for (int i = 0; i < 32; ++i) sAcc += part[i][threadIdx.x];
    lg[threadIdx.x] = sAcc;
  }
  __syncthreads();
  if (threadIdx.x == 0) {
    const float rs = rstab[t];
    int i0 = 0; float v0 = lg[0];
    for (int i = 1; i < 8; ++i) if (lg[i] > v0) { v0 = lg[i]; i0 = i; }
    int i1 = -1; float v1 = -__builtin_inff();
    for (int i = 0; i < 8; ++i) if (i != i0 && lg[i] > v1) { v1 = lg[i]; i1 = i; }
    const float e1 = expf((v1 - v0) * rs);
    const float inv = 1.f / (1.f + e1);
    const int p0 = atomicAdd(&counts[i0], 1);
    tok_map[i0 * S + p0] = t; w_map[i0 * S + p0] = inv;
    const int p1 = atomicAdd(&counts[i1], 1);
    tok_map[i1 * S + p1] = t; w_map[i1 * S + p1] = e1 * inv;
  }
}

// ================================================= MoE gate/up GEMM (dual-B), bf16, dbuf, XCD=expert
__global__ __launch_bounds__(256) void moe_gu(const u16* __restrict__ Yb,
    const u16* __restrict__ Wgb, const u16* __restrict__ Wub, u16* __restrict__ Hb,
    const int* __restrict__ counts, const int* __restrict__ tokmap) {
  const int b = blockIdx.x;
  const int e = b & 7, ii = b >> 3;
  const int n0 = (ii & 7) * 128;
  const int m0 = (ii >> 3) * 128;
  const int cnt = counts[e];
  if (m0 >= cnt) return;
  __shared__ u16 As[2][128 * 32];
  __shared__ u16 B1s[2][128 * 32];
  __shared__ u16 B2s[2][128 * 32];
  const int tid = threadIdx.x, wv = tid >> 6, lane = tid & 63;
  const int l15 = lane & 15, lg = lane >> 4;
  const int wr = wv >> 1, wc = wv & 1;
  const int sr = lane >> 2, sk = (lane & 3) * 16;
  const u16* B1 = Wgb + (size_t)e * 1024 * 1024;
  const u16* B2 = Wub + (size_t)e * 1024 * 1024;
  int ia[2];
  const u16* aptr[2]; const u16* b1p[2]; const u16* b2p[2];
#pragma unroll
  for (int i = 0; i < 2; ++i) {
    ia[i] = wv + i * 4;
    const int arow = m0 + ia[i] * 16 + sr;
    aptr[i] = Yb + (size_t)tokmap[e * S + arow] * 1024;
    b1p[i] = B1 + (size_t)(n0 + ia[i] * 16 + sr) * 1024;
    b2p[i] = B2 + (size_t)(n0 + ia[i] * 16 + sr) * 1024;
  }
  auto STAGE = [&](int buf, int k) {
#pragma unroll
    for (int i = 0; i < 2; ++i) {
      gl_lds16((const char*)(aptr[i] + k) + sk, (char*)As + buf * 8192 + ia[i] * 1024);
      gl_lds16((const char*)(b1p[i] + k) + sk, (char*)B1s + buf * 8192 + ia[i] * 1024);
      gl_lds16((const char*)(b2p[i] + k) + sk, (char*)B2s + buf * 8192 + ia[i] * 1024);
    }
  };
  f32x4 acc1[4][4] = {};
  f32x4 acc2[4][4] = {};
  STAGE(0, 0);
  __syncthreads();
  int cur = 0;
  for (int kk = 0; kk < 32; ++kk) {
    if (kk < 31) STAGE(cur ^ 1, (kk + 1) * 32);
    const u16* Ab = (const u16*)As + cur * 4096;
    const u16* B1b_ = (const u16*)B1s + cur * 4096;
    const u16* B2b_ = (const u16*)B2s + cur * 4096;
    short8 a[4], b1f[4], b2f[4];
#pragma unroll
    for (int i = 0; i < 4; ++i)
      a[i] = *(const short8*)(const void*)(Ab + (size_t)(wr * 64 + i * 16 + l15) * 32 + lg * 8);
#pragma unroll
    for (int j = 0; j < 4; ++j) {
      b1f[j] = *(const short8*)(const void*)(B1b_ + (size_t)(wc * 64 + j * 16 + l15) * 32 + lg * 8);
      b2f[j] = *(const short8*)(const void*)(B2b_ + (size_t)(wc * 64 + j * 16 + l15) * 32 + lg * 8);
    }
    __builtin_amdgcn_s_setprio(1);
#pragma unroll
    for (int i = 0; i < 4; ++i)
#pragma unroll
      for (int j = 0; j < 4; ++j) {
        acc1[i][j] = mfma16(a[i], b1f[j], acc1[i][j]);
        acc2[i][j] = mfma16(a[i], b2f[j], acc2[i][j]);
      }
    __builtin_amdgcn_s_setprio(0);
    __syncthreads();
    cur ^= 1;
  }
#pragma unroll
  for (int i = 0; i < 4; ++i)
#pragma unroll
    for (int j = 0; j < 4; ++j)
#pragma unroll
      for (int r = 0; r < 4; ++r) {
        const int row = m0 + wr * 64 + i * 16 + lg * 4 + r;
        if (row < cnt) {
          const float g = acc1[i][j][r];
          const float u = acc2[i][j][r];
          const float sig = __builtin_amdgcn_rcpf(1.f + __builtin_amdgcn_exp2f(-g * LOG2E));
          Hb[((size_t)e * 2048 + row) * 1024 + n0 + wc * 64 + j * 16 + l15] = f2bf(u * g * sig);
        }
      }
}

// ================================================= MoE down GEMM -> atomic f32 into out, XCD=expert
__global__ __launch_bounds__(256) void moe_down(const u16* __restrict__ Hb,
    const u16* __restrict__ Wdb, float* __restrict__ out,
    const int* __restrict__ counts, const int* __restrict__ tokmap,
    const float* __restrict__ wmap) {
  const int b = blockIdx.x;
  const int e = b & 7, ii = b >> 3;
  const int n0 = (ii & 7) * 128;
  const int m0 = (ii >> 3) * 128;
  const int cnt = counts[e];
  if (m0 >= cnt) return;
  __shared__ u16 As[2][128 * 32];
  __shared__ u16 Bs[2][128 * 32];
  const int tid = threadIdx.x, wv = tid >> 6, lane = tid & 63;
  const int l15 = lane & 15, lg = lane >> 4;
  const int wr = wv >> 1, wc = wv & 1;
  const int sr = lane >> 2, sk = (lane & 3) * 16;
  const u16* B = Wdb + (size_t)e * 1024 * 1024;
  const u16* aptr[2]; const u16* bptr[2];
#pragma unroll
  for (int i = 0; i < 2; ++i) {
    aptr[i] = Hb + ((size_t)e * 2048 + m0 + (wv * 2 + i) * 16 + sr) * 1024;
    bptr[i] = B + (size_t)(n0 + (wv * 2 + i) * 16 + sr) * 1024;
  }
  auto STAGE = [&](int buf, int k) {
#pragma unroll
    for (int i = 0; i < 2; ++i) {
      gl_lds16((const char*)(aptr[i] + k) + sk, (char*)As + buf * 8192 + (wv * 2 + i) * 1024);
      gl_lds16((const char*)(bptr[i] + k) + sk, (char*)Bs + buf * 8192 + (wv * 2 + i) * 1024);
    }
  };
  f32x4 acc[4][4] = {};
  STAGE(0, 0);
  __syncthreads();
  int cur = 0;
  for (int kk = 0; kk < 32; ++kk) {
    if (kk < 31) STAGE(cur ^ 1, (kk + 1) * 32);
    const u16* Ab = (const u16*)As + cur * 4096;
    const u16* Bb = (const u16*)Bs + cur * 4096;
    short8 a[4], bb[4];
#pragma unroll
    for (int i = 0; i < 4; ++i)
      a[i] = *(const short8*)(const void*)(Ab + (size_t)(wr * 64 + i * 16 + l15) * 32 + lg * 8);
#pragma unroll
    for (int j = 0; j < 4; ++j)
      bb[j] = *(const short8*)(const void*)(Bb + (size_t)(wc * 64 + j * 16 + l15) * 32 + lg * 8);
    __builtin_amdgcn_s_setprio(1);
#pragma unroll
    for (int i = 0; i < 4; ++i)
#pragma unroll
      for (int j = 0; j < 4; ++j) acc[i][j] = mfma16(a[i], bb[j], acc[i][j]);
    __builtin_amdgcn_s_setprio(0);
    __syncthreads();
    cur ^= 1;
  }
#pragma unroll
  for (int i = 0; i < 4; ++i)
#pragma unroll
    for (int j = 0; j < 4; ++j)
#pragma unroll
      for (int r = 0; r < 4; ++r) {
        const int row = m0 + wr * 64 + i * 16 + lg * 4 + r;
        if (row < cnt) {
          const int t = tokmap[e * S + row];
          const float wgt = wmap[e * S + row];
          atomicAdd(&out[(size_t)t * 1024 + n0 + wc * 64 + j * 16 + l15], wgt * acc[i][j][r]);
        }
      }
}

// ================================================= launch
extern "C" void kernel_launch(void* const* d_in, const int* in_sizes, int n_in,
                              void* d_out, int out_size, void* d_ws, size_t ws_size,
                              hipStream_t stream) {
  const int*   positions = (const int*)d_in[0];
  const float* hidden    = (const float*)d_in[1];
  const float* ln1_w  = (const float*)d_in[3];
  const float* ln2_w  = (const float*)d_in[4];
  const float* wqkv   = (const float*)d_in[5];
  const float* wo     = (const float*)d_in[6];
  const float* gate_w = (const float*)d_in[7];
  const float* wg     = (const float*)d_in[8];
  const float* wu     = (const float*)d_in[9];
  const float* wd     = (const float*)d_in[10];
  float* out = (float*)d_out;

  char* ws = (char*)d_ws;
  const size_t MB = 1ull << 20;
  u16* wqkvT2 = (u16*)(ws);                 // 12MB  [persist]
  u16* woT2   = (u16*)(ws + 12 * MB);       // 4MB   [persist]
  u16* wgT    = (u16*)(ws + 16 * MB);       // 16MB  [persist]
  u16* wuT    = (u16*)(ws + 32 * MB);       // 16MB  [persist]
  u16* wdT    = (u16*)(ws + 48 * MB);       // 16MB  [persist]
  float2* ropetab = (float2*)(ws + 64 * MB);          // 512KB
  float2* ml      = (float2*)(ws + 64 * MB + 524288); // 512KB
  char* mapb = ws + 65 * MB;
  int*   counts   = (int*)mapb;
  int*   tok_map  = (int*)(mapb + 8192);
  float* w_map    = (float*)(mapb + 8192 + 65536);
  float* rstab    = (float*)(mapb + 8192 + 131072);
  u16* xn2   = (u16*)(ws + 66 * MB);        // 8MB  (dead after QKV)
  u16* OA2   = xn2;                         // 8MB  (combine->Wo)
  u16* yb    = xn2;                         // 4MB  (MoE phase; OA2 dead)
  u16* QKVh  = (u16*)(ws + 74 * MB);        // 12MB (dead after attn)
  u16* Hb    = (u16*)(ws + 74 * MB);        // 32MB (MoE phase)
  u16* QKVl  = (u16*)(ws + 86 * MB);        // 12MB (dead after attn)
  float* Opart = (float*)(ws + 106 * MB);   // 16MB (attn partials; then Wo partials)
  float* p01   = Opart;

  prep_kernel<<<7424, 256, 0, stream>>>(wqkv, wo, wg, wu, wd, positions,
                                        wqkvT2, woT2, wgT, wuT, wdT, ropetab);
  rmsnorm_split<<<S, 256, 0, stream>>>(hidden, ln1_w, xn2);
  gemm_qkv<<<384, 256, 0, stream>>>(xn2, wqkvT2, ropetab, QKVh, QKVl);
  attn_mfma<<<1024, 256, 0, stream>>>(QKVh, QKVl, Opart, ml);
  attn_combine<<<S, 256, 0, stream>>>(Opart, ml, OA2);
  gemm_wo<<<256, 256, 0, stream>>>(OA2, woT2, p01);
  rmsnorm_res2<<<S, 256, 0, stream>>>(hidden, p01, p01 + (size_t)S * D, ln2_w, out, yb, rstab);
  hipMemsetAsync(counts, 0, NE * sizeof(int), stream);
  hipMemsetAsync(tok_map, 0, NE * S * sizeof(int), stream);
  gate_scatter<<<S, 256, 0, stream>>>(out, ln2_w, rstab, gate_w, counts, tok_map, w_map);
  moe_gu<<<1024, 256, 0, stream>>>(yb, wgT, wuT, Hb, counts, tok_map);
  moe_down<<<1024, 256, 0, stream>>>(Hb, wdT, out, counts, tok_map, w_map);
}

// Round 6
// 395.638 us; speedup vs baseline: 3.6960x; 1.0572x over previous
//
#include <hip/hip_runtime.h>
#include <math.h>

constexpr int S  = 2048;
constexpr int D  = 1024;
constexpr int NH = 16;
constexpr int NE = 8;
constexpr float EPS   = 1e-6f;
constexpr float THETA = 10000.0f;
constexpr float SCL2  = 0.125f * 1.4426950408889634f;  // attn scale * log2(e)
constexpr float LOG2E = 1.4426950408889634f;

typedef unsigned short u16;
typedef unsigned int   u32;
typedef unsigned long long u64;
typedef __attribute__((ext_vector_type(8))) short short8;
typedef __attribute__((ext_vector_type(4))) float f32x4;

__device__ __forceinline__ u16 f2bf(float x) {
  union { float f; u32 u; } v; v.f = x;
  u32 r = (v.u + 0x7FFFu + ((v.u >> 16) & 1u)) >> 16;
  return (u16)r;
}
__device__ __forceinline__ float bf2f(u16 h) {
  union { u32 u; float f; } v; v.u = ((u32)h) << 16;
  return v.f;
}
__device__ __forceinline__ f32x4 mfma16(short8 a, short8 b, f32x4 c) {
  return __builtin_amdgcn_mfma_f32_16x16x32_bf16(a, b, c, 0, 0, 0);
}
__device__ __forceinline__ void gl_lds16(const void* g, void* l) {
  __builtin_amdgcn_global_load_lds((const __attribute__((address_space(1))) u32*)g,
                                   (__attribute__((address_space(3))) u32*)l, 16, 0, 0);
}
__device__ __forceinline__ u64 pack4bf(float a, float b, float c, float d) {
  return (u64)f2bf(a) | ((u64)f2bf(b) << 16) | ((u64)f2bf(c) << 32) | ((u64)f2bf(d) << 48);
}

// ================================================= unified prep kernel
// [0,7168): weight transposes; [7168,7424): rope tab (+counts zero);
// [7424,9472): rmsnorm_split rows; [9472,11008): zero QKVf32 (24MB)
__global__ __launch_bounds__(256) void prep_kernel(const float* __restrict__ wqkv,
    const float* __restrict__ wo, const float* __restrict__ wg, const float* __restrict__ wu,
    const float* __restrict__ wd, const int* __restrict__ positions,
    const float* __restrict__ hidden, const float* __restrict__ ln1_w,
    u16* __restrict__ wqkvT2, u16* __restrict__ woT2, u16* __restrict__ wgT,
    u16* __restrict__ wuT, u16* __restrict__ wdT, float2* __restrict__ ropetab,
    u16* __restrict__ xn2, float* __restrict__ QKVf32, int* __restrict__ counts) {
  const int b = blockIdx.x;
  const int tid = threadIdx.x;
  if (b >= 9472) {  // zero QKVf32
    const int z = b - 9472;
    float4* f4 = (float4*)QKVf32;
    const float4 zz = make_float4(0.f, 0.f, 0.f, 0.f);
#pragma unroll
    for (int i = 0; i < 4; ++i) f4[(size_t)z * 1024 + i * 256 + tid] = zz;
    return;
  }
  if (b >= 7424) {  // rmsnorm_split
    const int t = b - 7424;
    const float* xr = hidden + (size_t)t * D;
    float v[4]; float ss = 0.f;
#pragma unroll
    for (int i = 0; i < 4; ++i) { v[i] = xr[tid + i * 256]; ss += v[i] * v[i]; }
#pragma unroll
    for (int m = 32; m >= 1; m >>= 1) ss += __shfl_xor(ss, m, 64);
    __shared__ float red[4];
    if ((tid & 63) == 0) red[tid >> 6] = ss;
    __syncthreads();
    const float rs = rsqrtf((red[0] + red[1] + red[2] + red[3]) * (1.f / (float)D) + EPS);
#pragma unroll
    for (int i = 0; i < 4; ++i) {
      const int d = tid + i * 256;
      const float y = v[i] * rs * ln1_w[d];
      const u16 h = f2bf(y);
      xn2[(size_t)t * 2048 + d] = h;
      xn2[(size_t)t * 2048 + 1024 + d] = f2bf(y - bf2f(h));
    }
    return;
  }
  if (b >= 7168) {  // rope table
    if (b == 7168 && tid < 8) counts[tid] = 0;
    const int idx = (b - 7168) * 256 + tid;
    const int t = idx >> 5, p = idx & 31;
    const float inv = powf(THETA, -(float)p * (1.f / 32.f));
    const float fr = (float)positions[t] * inv;
    float sn, cs; sincosf(fr, &sn, &cs);
    ropetab[idx] = make_float2(cs, sn);
    return;
  }
  __shared__ float t_[64][65];
  const float* W; u16* out; int N, n0, k0; bool split;
  if (b < 768) {
    W = wqkv; out = wqkvT2; N = 3072; split = true;
    n0 = (b % 48) * 64; k0 = (b / 48) * 64;
  } else if (b < 1024) {
    W = wo; out = woT2; N = 1024; split = true;
    const int r = b - 768; n0 = (r & 15) * 64; k0 = (r >> 4) * 64;
  } else {
    int r;
    if (b < 3072)      { r = b - 1024; const int e = r >> 8; W = wg + (size_t)e * 1048576; out = wgT + (size_t)e * 1048576; }
    else if (b < 5120) { r = b - 3072; const int e = r >> 8; W = wu + (size_t)e * 1048576; out = wuT + (size_t)e * 1048576; }
    else               { r = b - 5120; const int e = r >> 8; W = wd + (size_t)e * 1048576; out = wdT + (size_t)e * 1048576; }
    N = 1024; split = false;
    r &= 255; n0 = (r & 15) * 64; k0 = (r >> 4) * 64;
  }
  const int rr = tid >> 4, c4 = (tid & 15) * 4;
#pragma unroll
  for (int i = 0; i < 4; ++i) {
    const float4 v = *(const float4*)(W + (size_t)(k0 + rr + i * 16) * N + n0 + c4);
    t_[rr + i * 16][c4 + 0] = v.x; t_[rr + i * 16][c4 + 1] = v.y;
    t_[rr + i * 16][c4 + 2] = v.z; t_[rr + i * 16][c4 + 3] = v.w;
  }
  __syncthreads();
  if (split) {
#pragma unroll
    for (int i = 0; i < 4; ++i) {
      const int n = n0 + rr + i * 16;
      u16* oh = out + (size_t)n * 2048 + k0 + c4;
      const float v0 = t_[c4 + 0][rr + i * 16], v1 = t_[c4 + 1][rr + i * 16];
      const float v2 = t_[c4 + 2][rr + i * 16], v3 = t_[c4 + 3][rr + i * 16];
      *(u64*)(void*)oh = pack4bf(v0, v1, v2, v3);
      *(u64*)(void*)(oh + 1024) = pack4bf(v0 - bf2f(f2bf(v0)), v1 - bf2f(f2bf(v1)),
                                          v2 - bf2f(f2bf(v2)), v3 - bf2f(f2bf(v3)));
    }
  } else {
#pragma unroll
    for (int i = 0; i < 4; ++i) {
      const int n = n0 + rr + i * 16;
      u16* o = out + (size_t)n * 1024 + k0 + c4;
      *(u64*)(void*)o = pack4bf(t_[c4 + 0][rr + i * 16], t_[c4 + 1][rr + i * 16],
                                t_[c4 + 2][rr + i * 16], t_[c4 + 3][rr + i * 16]);
    }
  }
}

// ================================================= QKV GEMM: 128x128, split-bf16, dbuf, XCD-swz,
// split-K x2, f32 atomic epilogue. grid 768: xcd=b&7; ii=b>>3: m=ii&15, np=(ii>>4)%3, ks=(ii>>4)/3
__global__ __launch_bounds__(256) void gemm_qkv(const u16* __restrict__ A2,
    const u16* __restrict__ Bt2, float* __restrict__ Cf) {
  __shared__ u16 As[2][128 * 32];
  __shared__ u16 Bs[2][128 * 32];
  const int b = blockIdx.x;
  const int xcd = b & 7, ii = b >> 3;
  const int m0 = (ii & 15) * 128;
  const int np = (ii >> 4) % 3, ks = (ii >> 4) / 3;
  const int n0 = (xcd * 3 + np) * 128;
  const int kk0 = ks * 48, kk1 = kk0 + 48;
  const int tid = threadIdx.x, wv = tid >> 6, lane = tid & 63;
  const int l15 = lane & 15, lg = lane >> 4;
  const int wr = wv >> 1, wc = wv & 1;
  const int sr = lane >> 2, sk = (lane & 3) * 16;
  const u16* aptr[2]; const u16* bptr[2];
#pragma unroll
  for (int i = 0; i < 2; ++i) {
    aptr[i] = A2 + (size_t)(m0 + (wv * 2 + i) * 16 + sr) * 2048;
    bptr[i] = Bt2 + (size_t)(n0 + (wv * 2 + i) * 16 + sr) * 2048;
  }
  auto STAGE = [&](int buf, int kk) {
    const int t = kk * 32;
    int ka, kb;
    if (t < 1024)      { ka = t;        kb = t; }
    else if (t < 2048) { ka = t;        kb = t - 1024; }
    else               { ka = t - 2048; kb = t - 1024; }
#pragma unroll
    for (int i = 0; i < 2; ++i) {
      gl_lds16((const char*)(aptr[i] + ka) + sk, (char*)As + buf * 8192 + (wv * 2 + i) * 1024);
      gl_lds16((const char*)(bptr[i] + kb) + sk, (char*)Bs + buf * 8192 + (wv * 2 + i) * 1024);
    }
  };
  f32x4 acc[4][4] = {};
  STAGE(0, kk0);
  __syncthreads();
  int cur = 0;
  for (int kk = kk0; kk < kk1; ++kk) {
    if (kk + 1 < kk1) STAGE(cur ^ 1, kk + 1);
    const u16* Ab = (const u16*)As + cur * 4096;
    const u16* Bb = (const u16*)Bs + cur * 4096;
    short8 a[4], bb[4];
#pragma unroll
    for (int i = 0; i < 4; ++i)
      a[i] = *(const short8*)(const void*)(Ab + (size_t)(wr * 64 + i * 16 + l15) * 32 + lg * 8);
#pragma unroll
    for (int j = 0; j < 4; ++j)
      bb[j] = *(const short8*)(const void*)(Bb + (size_t)(wc * 64 + j * 16 + l15) * 32 + lg * 8);
    __builtin_amdgcn_s_setprio(1);
#pragma unroll
    for (int i = 0; i < 4; ++i)
#pragma unroll
      for (int j = 0; j < 4; ++j) acc[i][j] = mfma16(a[i], bb[j], acc[i][j]);
    __builtin_amdgcn_s_setprio(0);
    __syncthreads();
    cur ^= 1;
  }
#pragma unroll
  for (int i = 0; i < 4; ++i)
#pragma unroll
    for (int j = 0; j < 4; ++j)
#pragma unroll
      for (int r = 0; r < 4; ++r) {
        const int row = m0 + wr * 64 + i * 16 + lg * 4 + r;
        const int col = n0 + wc * 64 + j * 16 + l15;
        atomicAdd(&Cf[(size_t)row * 3072 + col], acc[i][j][r]);
      }
}

// ================================================= QKV combine: rope + hi/lo split-store
__global__ __launch_bounds__(256) void qkv_combine(const float* __restrict__ Cf,
    const float2* __restrict__ tab, u16* __restrict__ Ch, u16* __restrict__ Cl) {
  const int t = blockIdx.x, tid = threadIdx.x;
  const float* row = Cf + (size_t)t * 3072;
  const size_t ob = (size_t)t * 3072;
#pragma unroll
  for (int i = 0; i < 4; ++i) {  // q,k pairs
    const int pi = tid + i * 256;
    const int h = pi >> 5, p = pi & 31;
    const int col = h * 64 + p;
    const float x1 = row[col], x2 = row[col + 32];
    const float2 cs = tab[t * 32 + p];
    const float y1 = x1 * cs.x - x2 * cs.y;
    const float y2 = x1 * cs.y + x2 * cs.x;
    const u16 h1 = f2bf(y1);
    Ch[ob + col] = h1; Cl[ob + col] = f2bf(y1 - bf2f(h1));
    const u16 h2 = f2bf(y2);
    Ch[ob + col + 32] = h2; Cl[ob + col + 32] = f2bf(y2 - bf2f(h2));
  }
#pragma unroll
  for (int i = 0; i < 4; ++i) {  // v
    const int col = 2048 + tid + i * 256;
    const float y = row[col];
    const u16 h = f2bf(y);
    Ch[ob + col] = h; Cl[ob + col] = f2bf(y - bf2f(h));
  }
}

// ================================================= Wo GEMM: 128x128, split-bf16, dbuf, XCD-swz, Kx4
// grid 512: xcd=b&7 -> n-panel; ii=b>>3: m=ii&15, ks=ii>>4 in [0,4)
__global__ __launch_bounds__(256) void gemm_wo(const u16* __restrict__ A2,
    const u16* __restrict__ Bt2, float* __restrict__ Pout) {
  constexpr int N = 1024;
  __shared__ u16 As[2][128 * 32];
  __shared__ u16 Bs[2][128 * 32];
  const int b = blockIdx.x;
  const int xcd = b & 7, ii = b >> 3;
  const int n0 = xcd * 128;
  const int m0 = (ii & 15) * 128;
  const int ks = ii >> 4;
  const int kk0 = ks * 24, kk1 = kk0 + 24;
  const int tid = threadIdx.x, wv = tid >> 6, lane = tid & 63;
  const int l15 = lane & 15, lg = lane >> 4;
  const int wr = wv >> 1, wc = wv & 1;
  const int sr = lane >> 2, sk = (lane & 3) * 16;
  const u16* aptr[2]; const u16* bptr[2];
#pragma unroll
  for (int i = 0; i < 2; ++i) {
    aptr[i] = A2 + (size_t)(m0 + (wv * 2 + i) * 16 + sr) * 2048;
    bptr[i] = Bt2 + (size_t)(n0 + (wv * 2 + i) * 16 + sr) * 2048;
  }
  auto STAGE = [&](int buf, int kk) {
    const int t = kk * 32;
    int ka, kb;
    if (t < 1024)      { ka = t;        kb = t; }
    else if (t < 2048) { ka = t;        kb = t - 1024; }
    else               { ka = t - 2048; kb = t - 1024; }
#pragma unroll
    for (int i = 0; i < 2; ++i) {
      gl_lds16((const char*)(aptr[i] + ka) + sk, (char*)As + buf * 8192 + (wv * 2 + i) * 1024);
      gl_lds16((const char*)(bptr[i] + kb) + sk, (char*)Bs + buf * 8192 + (wv * 2 + i) * 1024);
    }
  };
  f32x4 acc[4][4] = {};
  STAGE(0, kk0);
  __syncthreads();
  int cur = 0;
  for (int kk = kk0; kk < kk1; ++kk) {
    if (kk + 1 < kk1) STAGE(cur ^ 1, kk + 1);
    const u16* Ab = (const u16*)As + cur * 4096;
    const u16* Bb = (const u16*)Bs + cur * 4096;
    short8 a[4], bb[4];
#pragma unroll
    for (int i = 0; i < 4; ++i)
      a[i] = *(const short8*)(const void*)(Ab + (size_t)(wr * 64 + i * 16 + l15) * 32 + lg * 8);
#pragma unroll
    for (int j = 0; j < 4; ++j)
      bb[j] = *(const short8*)(const void*)(Bb + (size_t)(wc * 64 + j * 16 + l15) * 32 + lg * 8);
    __builtin_amdgcn_s_setprio(1);
#pragma unroll
    for (int i = 0; i < 4; ++i)
#pragma unroll
      for (int j = 0; j < 4; ++j) acc[i][j] = mfma16(a[i], bb[j], acc[i][j]);
    __builtin_amdgcn_s_setprio(0);
    __syncthreads();
    cur ^= 1;
  }
  float* P = Pout + (size_t)ks * S * N;
#pragma unroll
  for (int i = 0; i < 4; ++i)
#pragma unroll
    for (int j = 0; j < 4; ++j)
#pragma unroll
      for (int r = 0; r < 4; ++r) {
        const int row = m0 + wr * 64 + i * 16 + lg * 4 + r;
        const int col = n0 + wc * 64 + j * 16 + l15;
        P[(size_t)row * N + col] = acc[i][j][r];
      }
}

// ================================================= MFMA flash attention (unchanged from R5)
__global__ __launch_bounds__(256) void attn_mfma(const u16* __restrict__ Qh,
    const u16* __restrict__ Ql, float* __restrict__ Opart, float2* __restrict__ ml) {
  const int b = blockIdx.x;
  const int head = (b & 7) + 8 * (b >> 9);
  const int qb = 31 - ((b >> 3) & 31);
  const int half = (b >> 8) & 1;
  const int q0 = qb * 64;
  const int ktiles = qb + 1, hsp = (ktiles + 1) >> 1;
  const int t0 = half ? hsp : 0, t1 = half ? ktiles : hsp;
  const int tid = threadIdx.x, w = tid >> 6, lane = tid & 63;
  const int l15 = lane & 15, lg = lane >> 4;
  __shared__ u16 Kh[2][64 * 64];
  __shared__ u16 Kl[2][64 * 64];
  __shared__ __align__(16) u16 Vth[64 * 72];
  __shared__ __align__(16) u16 Vtl[64 * 72];
  __shared__ u32 Pp[4][16 * 68];

  short8 qh[2], qlo[2];
  {
    const size_t qbase = (size_t)(q0 + w * 16 + l15) * 3072 + head * 64;
    qh[0]  = *(const short8*)(const void*)(Qh + qbase + lg * 8);
    qh[1]  = *(const short8*)(const void*)(Qh + qbase + 32 + lg * 8);
    qlo[0] = *(const short8*)(const void*)(Ql + qbase + lg * 8);
    qlo[1] = *(const short8*)(const void*)(Ql + qbase + 32 + lg * 8);
  }
  f32x4 oacc[4] = {};
  float m_run[4], l_run[4];
#pragma unroll
  for (int r = 0; r < 4; ++r) { m_run[r] = -__builtin_inff(); l_run[r] = 0.f; }
  const int qrow0 = q0 + w * 16 + lg * 4;

  const int vhl = tid >> 7, rem = tid & 127;
  const int vkq = rem & 15, vdg = rem >> 4;
  const u16* vbase = (vhl ? Ql : Qh) + 2048 + head * 64 + vdg * 8;
  u16* vdst = vhl ? Vtl : Vth;
  short8 vr[4];

  auto STAGEK = [&](int kt, int buf) {
#pragma unroll
    for (int i = 0; i < 2; ++i) {
      const int inst = w * 2 + i;
      const int key = inst * 8 + (lane >> 3);
      const int db = ((lane & 7) * 16) ^ ((key & 7) << 4);
      gl_lds16((const char*)(Qh + (size_t)(kt * 64 + key) * 3072 + 1024 + head * 64) + db,
               (char*)Kh + buf * 8192 + inst * 1024);
      gl_lds16((const char*)(Ql + (size_t)(kt * 64 + key) * 3072 + 1024 + head * 64) + db,
               (char*)Kl + buf * 8192 + inst * 1024);
    }
  };
  auto VLOAD = [&](int kt) {
    const u16* vs = vbase + (size_t)(kt * 64 + vkq * 4) * 3072;
    vr[0] = *(const short8*)(const void*)vs;
    vr[1] = *(const short8*)(const void*)(vs + 3072);
    vr[2] = *(const short8*)(const void*)(vs + 6144);
    vr[3] = *(const short8*)(const void*)(vs + 9216);
  };
  auto VWRITE = [&]() {
#pragma unroll
    for (int jj = 0; jj < 8; ++jj) {
      const u64 pk = (u64)(u16)vr[0][jj] | ((u64)(u16)vr[1][jj] << 16) |
                     ((u64)(u16)vr[2][jj] << 32) | ((u64)(u16)vr[3][jj] << 48);
      *(u64*)(void*)(vdst + (vdg * 8 + jj) * 72 + vkq * 4) = pk;
    }
  };

  if (t0 < t1) {
    STAGEK(t0, 0);
    VLOAD(t0);
    VWRITE();
    __syncthreads();
  }
  for (int t = t0; t < t1; ++t) {
    const int cur = (t - t0) & 1;
    const int k0 = t * 64;
    const bool more = (t + 1 < t1);
    if (more) { STAGEK(t + 1, cur ^ 1); VLOAD(t + 1); }
    f32x4 sacc[4];
    __builtin_amdgcn_s_setprio(1);
#pragma unroll
    for (int nt = 0; nt < 4; ++nt) {
      const int key = nt * 16 + l15;
      const char* kbh = (const char*)Kh + cur * 8192 + key * 128;
      const char* kbl = (const char*)Kl + cur * 8192 + key * 128;
      const int sw = (key & 7) << 4;
      const short8 kh0 = *(const short8*)(const void*)(kbh + ((lg * 16) ^ sw));
      const short8 kh1 = *(const short8*)(const void*)(kbh + ((64 + lg * 16) ^ sw));
      const short8 kl0 = *(const short8*)(const void*)(kbl + ((lg * 16) ^ sw));
      const short8 kl1 = *(const short8*)(const void*)(kbl + ((64 + lg * 16) ^ sw));
      f32x4 s = {};
      s = mfma16(qh[0], kh0, s); s = mfma16(qh[1], kh1, s);
      s = mfma16(qlo[0], kh0, s); s = mfma16(qlo[1], kh1, s);
      s = mfma16(qh[0], kl0, s); s = mfma16(qh[1], kl1, s);
      sacc[nt] = s;
    }
    __builtin_amdgcn_s_setprio(0);
#pragma unroll
    for (int nt = 0; nt < 4; ++nt)
#pragma unroll
      for (int r = 0; r < 4; ++r) sacc[nt][r] *= SCL2;
    if (t == qb) {
#pragma unroll
      for (int nt = 0; nt < 4; ++nt) {
        const int key = k0 + nt * 16 + l15;
#pragma unroll
        for (int r = 0; r < 4; ++r)
          if (key > qrow0 + r) sacc[nt][r] = -__builtin_inff();
      }
    }
    float mx4[4];
#pragma unroll
    for (int r = 0; r < 4; ++r) {
      float mx = fmaxf(fmaxf(sacc[0][r], sacc[1][r]), fmaxf(sacc[2][r], sacc[3][r]));
#pragma unroll
      for (int msk = 8; msk >= 1; msk >>= 1) mx = fmaxf(mx, __shfl_xor(mx, msk, 64));
      mx4[r] = mx;
    }
    const bool grow = (mx4[0] > m_run[0] + 8.f) || (mx4[1] > m_run[1] + 8.f) ||
                      (mx4[2] > m_run[2] + 8.f) || (mx4[3] > m_run[3] + 8.f);
    if (__any(grow)) {
#pragma unroll
      for (int r = 0; r < 4; ++r) {
        const float m_new = fmaxf(m_run[r], mx4[r]);
        const float fac = __builtin_amdgcn_exp2f(m_run[r] - m_new);
        m_run[r] = m_new;
        l_run[r] *= fac;
#pragma unroll
        for (int nd = 0; nd < 4; ++nd) oacc[nd][r] *= fac;
      }
    }
#pragma unroll
    for (int nt = 0; nt < 4; ++nt)
#pragma unroll
      for (int r = 0; r < 4; ++r)
        sacc[nt][r] = __builtin_amdgcn_exp2f(sacc[nt][r] - m_run[r]);
#pragma unroll
    for (int r = 0; r < 4; ++r) {
      float ls = sacc[0][r] + sacc[1][r] + sacc[2][r] + sacc[3][r];
#pragma unroll
      for (int msk = 8; msk >= 1; msk >>= 1) ls += __shfl_xor(ls, msk, 64);
      l_run[r] += ls;
    }
#pragma unroll
    for (int nt = 0; nt < 4; ++nt)
#pragma unroll
      for (int r = 0; r < 4; ++r) {
        const float p = sacc[nt][r];
        const u32 xu = __float_as_uint(p);
        const u32 hi = xu & 0xFFFF0000u;
        const float pl = p - __uint_as_float(hi);
        const u32 lw = __float_as_uint(pl) >> 16;
        Pp[w][(lg * 4 + r) * 68 + nt * 16 + l15] = (xu >> 16) | (lw << 16);
      }
    __builtin_amdgcn_s_setprio(1);
#pragma unroll
    for (int kk2 = 0; kk2 < 2; ++kk2) {
      const u32* prow = &Pp[w][l15 * 68 + kk2 * 32 + lg * 8];
      const uint4 pq0 = *(const uint4*)prow;
      const uint4 pq1 = *(const uint4*)(prow + 4);
      union U8 { u32 wd[4]; short8 v; } ph_, pl_;
      ph_.wd[0] = (pq0.x & 0xFFFFu) | (pq0.y << 16);
      ph_.wd[1] = (pq0.z & 0xFFFFu) | (pq0.w << 16);
      ph_.wd[2] = (pq1.x & 0xFFFFu) | (pq1.y << 16);
      ph_.wd[3] = (pq1.z & 0xFFFFu) | (pq1.w << 16);
      pl_.wd[0] = (pq0.x >> 16) | (pq0.y & 0xFFFF0000u);
      pl_.wd[1] = (pq0.z >> 16) | (pq0.w & 0xFFFF0000u);
      pl_.wd[2] = (pq1.x >> 16) | (pq1.y & 0xFFFF0000u);
      pl_.wd[3] = (pq1.z >> 16) | (pq1.w & 0xFFFF0000u);
#pragma unroll
      for (int nd = 0; nd < 4; ++nd) {
        const short8 vbh = *(const short8*)(const void*)((const char*)Vth + (nd * 16 + l15) * 144 + kk2 * 64 + lg * 16);
        const short8 vbl = *(const short8*)(const void*)((const char*)Vtl + (nd * 16 + l15) * 144 + kk2 * 64 + lg * 16);
        oacc[nd] = mfma16(ph_.v, vbh, oacc[nd]);
        oacc[nd] = mfma16(pl_.v, vbh, oacc[nd]);
        oacc[nd] = mfma16(ph_.v, vbl, oacc[nd]);
      }
    }
    __builtin_amdgcn_s_setprio(0);
    __syncthreads();
    if (more) VWRITE();
    __syncthreads();
  }
  float* Op = Opart + (size_t)half * S * 1024;
#pragma unroll
  for (int nd = 0; nd < 4; ++nd)
#pragma unroll
    for (int r = 0; r < 4; ++r)
      Op[(size_t)(qrow0 + r) * 1024 + head * 64 + nd * 16 + l15] = oacc[nd][r];
  if (l15 == 0) {
#pragma unroll
    for (int r = 0; r < 4; ++r)
      ml[((size_t)half * S + qrow0 + r) * NH + head] = make_float2(m_run[r], l_run[r]);
  }
}

// ================================================= combine split-K attention partials
__global__ __launch_bounds__(256) void attn_combine(const float* __restrict__ Op,
    const float2* __restrict__ ml, u16* __restrict__ OA2) {
  const int t = blockIdx.x, tid = threadIdx.x;
  const int h = tid >> 4, dq = (tid & 15) * 4;
  const float2 a = ml[(size_t)t * NH + h];
  const float2 b = ml[((size_t)S + t) * NH + h];
  const float m = fmaxf(a.x, b.x);
  const float e0 = exp2f(a.x - m);
  const float e1 = (b.y > 0.f) ? exp2f(b.x - m) : 0.f;
  const float inv = 1.f / (e0 * a.y + e1 * b.y);
  const float4 v0 = *(const float4*)(Op + (size_t)t * 1024 + h * 64 + dq);
  const float4 v1 = *(const float4*)(Op + (size_t)S * 1024 + (size_t)t * 1024 + h * 64 + dq);
  const float ov[4] = {(e0 * v0.x + e1 * v1.x) * inv, (e0 * v0.y + e1 * v1.y) * inv,
                       (e0 * v0.z + e1 * v1.z) * inv, (e0 * v0.w + e1 * v1.w) * inv};
#pragma unroll
  for (int c = 0; c < 4; ++c) {
    const size_t idx = (size_t)t * 2048 + h * 64 + dq + c;
    const u16 hb = f2bf(ov[c]);
    OA2[idx] = hb;
    OA2[idx + 1024] = f2bf(ov[c] - bf2f(hb));
  }
}

// ================================================= res2 (4 partials) + rmsnorm2 fused
__global__ __launch_bounds__(256) void rmsnorm_res2(const float* __restrict__ hidden,
    const float* __restrict__ p01, const float* __restrict__ w2,
    float* __restrict__ out, u16* __restrict__ yb, float* __restrict__ rstab) {
  const int t = blockIdx.x;
  float v[4]; float ss = 0.f;
#pragma unroll
  for (int i = 0; i < 4; ++i) {
    const size_t idx = (size_t)t * D + threadIdx.x + i * 256;
    const float r = hidden[idx] + p01[idx] + p01[idx + (size_t)S * D] +
                    p01[idx + 2 * (size_t)S * D] + p01[idx + 3 * (size_t)S * D];
    v[i] = r; ss += r * r;
  }
#pragma unroll
  for (int m = 32; m >= 1; m >>= 1) ss += __shfl_xor(ss, m, 64);
  __shared__ float red[4];
  if ((threadIdx.x & 63) == 0) red[threadIdx.x >> 6] = ss;
  __syncthreads();
  const float rs = rsqrtf((red[0] + red[1] + red[2] + red[3]) * (1.f / (float)D) + EPS);
#pragma unroll
  for (int i = 0; i < 4; ++i) {
    const int d = threadIdx.x + i * 256;
    const size_t idx = (size_t)t * D + d;
    out[idx] = v[i];
    yb[idx] = f2bf(v[i] * rs * w2[d]);
  }
  if (threadIdx.x == 0) rstab[t] = rs;
}

// ================================================= gate + top-2 + scatter (fused)
__global__ __launch_bounds__(256) void gate_scatter(const float* __restrict__ res2,
    const float* __restrict__ w2, const float* __restrict__ rstab,
    const float* __restrict__ GW, int* __restrict__ counts, int* __restrict__ tok_map,
    float* __restrict__ w_map) {
  const int t = blockIdx.x;
  const int e = threadIdx.x & 7;
  const int c = threadIdx.x >> 3;
  float p = 0.f;
  for (int d = c; d < D; d += 32) p += res2[(size_t)t * D + d] * w2[d] * GW[d * NE + e];
  __shared__ float part[32][8];
  part[c][e] = p;
  __syncthreads();
  __shared__ float lg[8];
  if (threadIdx.x < 8) {
    float sAcc = 0.f;
    for (int i = 0; i < 32; ++i) sAcc += part[i][threadIdx.x];
    lg[threadIdx.x] = sAcc;
  }
  __syncthreads();
  if (threadIdx.x == 0) {
    const float rs = rstab[t];
    int i0 = 0; float v0 = lg[0];
    for (int i = 1; i < 8; ++i) if (lg[i] > v0) { v0 = lg[i]; i0 = i; }
    int i1 = -1; float v1 = -__builtin_inff();
    for (int i = 0; i < 8; ++i) if (i != i0 && lg[i] > v1) { v1 = lg[i]; i1 = i; }
    const float e1 = expf((v1 - v0) * rs);
    const float inv = 1.f / (1.f + e1);
    const int p0 = atomicAdd(&counts[i0], 1);
    tok_map[i0 * S + p0] = t; w_map[i0 * S + p0] = inv;
    const int p1 = atomicAdd(&counts[i1], 1);
    tok_map[i1 * S + p1] = t; w_map[i1 * S + p1] = e1 * inv;
  }
}

// ================================================= MoE gate/up GEMM: 128x64 tile, dual-B, dbuf
// grid 2048: e=b&7; ii=b>>3: n=(ii&15)*64, m=(ii>>4)*128
__global__ __launch_bounds__(256) void moe_gu(const u16* __restrict__ Yb,
    const u16* __restrict__ Wgb, const u16* __restrict__ Wub, u16* __restrict__ Hb,
    const int* __restrict__ counts, const int* __restrict__ tokmap) {
  const int b = blockIdx.x;
  const int e = b & 7, ii = b >> 3;
  const int n0 = (ii & 15) * 64;
  const int m0 = (ii >> 4) * 128;
  const int cnt = counts[e];
  if (m0 >= cnt) return;
  __shared__ u16 SH[2][16 * 512];  // chunks: 0-7 A(128x32), 8-11 B1(64x32), 12-15 B2(64x32)
  const int tid = threadIdx.x, wv = tid >> 6, lane = tid & 63;
  const int l15 = lane & 15, lg = lane >> 4;
  const int wr = wv >> 1, wc = wv & 1;
  const int sr = lane >> 2, sk = (lane & 3) * 16;
  const u16* B1 = Wgb + (size_t)e * 1048576;
  const u16* B2 = Wub + (size_t)e * 1048576;
  const u16* cp[4];
#pragma unroll
  for (int i = 0; i < 4; ++i) {
    const int c = wv * 4 + i;
    if (c < 8) {
      const int arow = m0 + c * 16 + sr;
      const int tok = tokmap[e * S + arow] & 2047;
      cp[i] = Yb + (size_t)tok * 1024;
    } else if (c < 12) {
      cp[i] = B1 + (size_t)(n0 + (c - 8) * 16 + sr) * 1024;
    } else {
      cp[i] = B2 + (size_t)(n0 + (c - 12) * 16 + sr) * 1024;
    }
  }
  auto STAGE = [&](int buf, int k) {
#pragma unroll
    for (int i = 0; i < 4; ++i) {
      const int c = wv * 4 + i;
      gl_lds16((const char*)(cp[i] + k) + sk, (char*)SH + buf * 16384 + c * 1024);
    }
  };
  f32x4 acc1[4][2] = {};
  f32x4 acc2[4][2] = {};
  STAGE(0, 0);
  __syncthreads();
  int cur = 0;
  for (int kk = 0; kk < 32; ++kk) {
    if (kk < 31) STAGE(cur ^ 1, (kk + 1) * 32);
    const u16* Sb = (const u16*)SH + cur * 8192;
    short8 a[4], b1f[2], b2f[2];
#pragma unroll
    for (int i = 0; i < 4; ++i)
      a[i] = *(const short8*)(const void*)(Sb + (size_t)(wr * 64 + i * 16 + l15) * 32 + lg * 8);
#pragma unroll
    for (int j = 0; j < 2; ++j) {
      b1f[j] = *(const short8*)(const void*)(Sb + 4096 + (size_t)(wc * 32 + j * 16 + l15) * 32 + lg * 8);
      b2f[j] = *(const short8*)(const void*)(Sb + 6144 + (size_t)(wc * 32 + j * 16 + l15) * 32 + lg * 8);
    }
    __builtin_amdgcn_s_setprio(1);
#pragma unroll
    for (int i = 0; i < 4; ++i)
#pragma unroll
      for (int j = 0; j < 2; ++j) {
        acc1[i][j] = mfma16(a[i], b1f[j], acc1[i][j]);
        acc2[i][j] = mfma16(a[i], b2f[j], acc2[i][j]);
      }
    __builtin_amdgcn_s_setprio(0);
    __syncthreads();
    cur ^= 1;
  }
#pragma unroll
  for (int i = 0; i < 4; ++i)
#pragma unroll
    for (int j = 0; j < 2; ++j)
#pragma unroll
      for (int r = 0; r < 4; ++r) {
        const int row = m0 + wr * 64 + i * 16 + lg * 4 + r;
        if (row < cnt) {
          const float g = acc1[i][j][r];
          const float u = acc2[i][j][r];
          const float sig = __builtin_amdgcn_rcpf(1.f + __builtin_amdgcn_exp2f(-g * LOG2E));
          Hb[((size_t)e * 2048 + row) * 1024 + n0 + wc * 32 + j * 16 + l15] = f2bf(u * g * sig);
        }
      }
}

// ================================================= MoE down GEMM: split-K x2, atomic f32 into out
// grid 2048: e=b&7; ii=b>>3: m=ii&15, n=(ii>>4)&7, ks=ii>>7
__global__ __launch_bounds__(256) void moe_down(const u16* __restrict__ Hb,
    const u16* __restrict__ Wdb, float* __restrict__ out,
    const int* __restrict__ counts, const int* __restrict__ tokmap,
    const float* __restrict__ wmap) {
  const int b = blockIdx.x;
  const int e = b & 7, ii = b >> 3;
  const int m0 = (ii & 15) * 128;
  const int n0 = ((ii >> 4) & 7) * 128;
  const int ks = ii >> 7;
  const int cnt = counts[e];
  if (m0 >= cnt) return;
  __shared__ u16 As[2][128 * 32];
  __shared__ u16 Bs[2][128 * 32];
  const int tid = threadIdx.x, wv = tid >> 6, lane = tid & 63;
  const int l15 = lane & 15, lg = lane >> 4;
  const int wr = wv >> 1, wc = wv & 1;
  const int sr = lane >> 2, sk = (lane & 3) * 16;
  const u16* B = Wdb + (size_t)e * 1048576;
  const u16* aptr[2]; const u16* bptr[2];
#pragma unroll
  for (int i = 0; i < 2; ++i) {
    aptr[i] = Hb + ((size_t)e * 2048 + m0 + (wv * 2 + i) * 16 + sr) * 1024;
    bptr[i] = B + (size_t)(n0 + (wv * 2 + i) * 16 + sr) * 1024;
  }
  auto STAGE = [&](int buf, int k) {
#pragma unroll
    for (int i = 0; i < 2; ++i) {
      gl_lds16((const char*)(aptr[i] + k) + sk, (char*)As + buf * 8192 + (wv * 2 + i) * 1024);
      gl_lds16((const char*)(bptr[i] + k) + sk, (char*)Bs + buf * 8192 + (wv * 2 + i) * 1024);
    }
  };
  f32x4 acc[4][4] = {};
  const int kb0 = ks * 16, kb1 = kb0 + 16;
  STAGE(0, kb0 * 32);
  __syncthreads();
  int cur = 0;
  for (int kk = kb0; kk < kb1; ++kk) {
    if (kk + 1 < kb1) STAGE(cur ^ 1, (kk + 1) * 32);
    const u16* Ab = (const u16*)As + cur * 4096;
    const u16* Bb = (const u16*)Bs + cur * 4096;
    short8 a[4], bb[4];
#pragma unroll
    for (int i = 0; i < 4; ++i)
      a[i] = *(const short8*)(const void*)(Ab + (size_t)(wr * 64 + i * 16 + l15) * 32 + lg * 8);
#pragma unroll
    for (int j = 0; j < 4; ++j)
      bb[j] = *(const short8*)(const void*)(Bb + (size_t)(wc * 64 + j * 16 + l15) * 32 + lg * 8);
    __builtin_amdgcn_s_setprio(1);
#pragma unroll
    for (int i = 0; i < 4; ++i)
#pragma unroll
      for (int j = 0; j < 4; ++j) acc[i][j] = mfma16(a[i], bb[j], acc[i][j]);
    __builtin_amdgcn_s_setprio(0);
    __syncthreads();
    cur ^= 1;
  }
#pragma unroll
  for (int i = 0; i < 4; ++i)
#pragma unroll
    for (int j = 0; j < 4; ++j)
#pragma unroll
      for (int r = 0; r < 4; ++r) {
        const int row = m0 + wr * 64 + i * 16 + lg * 4 + r;
        if (row < cnt) {
          const int t = tokmap[e * S + row];
          const float wgt = wmap[e * S + row];
          atomicAdd(&out[(size_t)t * 1024 + n0 + wc * 64 + j * 16 + l15], wgt * acc[i][j][r]);
        }
      }
}

// ================================================= launch
extern "C" void kernel_launch(void* const* d_in, const int* in_sizes, int n_in,
                              void* d_out, int out_size, void* d_ws, size_t ws_size,
                              hipStream_t stream) {
  const int*   positions = (const int*)d_in[0];
  const float* hidden    = (const float*)d_in[1];
  const float* ln1_w  = (const float*)d_in[3];
  const float* ln2_w  = (const float*)d_in[4];
  const float* wqkv   = (const float*)d_in[5];
  const float* wo     = (const float*)d_in[6];
  const float* gate_w = (const float*)d_in[7];
  const float* wg     = (const float*)d_in[8];
  const float* wu     = (const float*)d_in[9];
  const float* wd     = (const float*)d_in[10];
  float* out = (float*)d_out;

  char* ws = (char*)d_ws;
  const size_t MB = 1ull << 20;
  u16* wqkvT2 = (u16*)(ws);                 // 12MB (dead after gemm_qkv)
  u16* woT2   = (u16*)(ws + 12 * MB);       // 4MB
  u16* wgT    = (u16*)(ws + 16 * MB);       // 16MB
  u16* wuT    = (u16*)(ws + 32 * MB);       // 16MB
  u16* wdT    = (u16*)(ws + 48 * MB);       // 16MB
  float2* ropetab = (float2*)(ws + 64 * MB);          // 512KB
  float2* ml      = (float2*)(ws + 64 * MB + 524288); // 512KB
  char* mapb = ws + 65 * MB;
  int*   counts   = (int*)mapb;
  int*   tok_map  = (int*)(mapb + 8192);
  float* w_map    = (float*)(mapb + 8192 + 65536);
  float* rstab    = (float*)(mapb + 8192 + 131072);
  u16* xn2    = (u16*)(ws + 66 * MB);       // 8MB  (ph1)
  u16* OA2    = (u16*)(ws + 66 * MB);       // 8MB  (ph4-5)
  u16* yb     = (u16*)(ws + 66 * MB);       // 4MB  (ph6+)
  float* QKVf32 = (float*)(ws + 74 * MB);   // 24MB (ph1-2)
  float* Opart  = (float*)(ws + 74 * MB);   // 16MB (ph3-4)
  float* p01    = (float*)(ws + 74 * MB);   // 32MB (ph5-6)
  u16* Hb     = (u16*)(ws + 74 * MB);       // 32MB (ph7)
  u16* QKVh   = (u16*)(ws + 98 * MB);       // 12MB (ph2-3)
  u16* QKVl   = (u16*)(ws + 110 * MB);      // 12MB (ph2-3)

  // prep: weights + rope tab + rmsnorm1 + zero QKVf32 + zero counts
  prep_kernel<<<11008, 256, 0, stream>>>(wqkv, wo, wg, wu, wd, positions, hidden, ln1_w,
                                         wqkvT2, woT2, wgT, wuT, wdT, ropetab,
                                         xn2, QKVf32, counts);
  gemm_qkv<<<768, 256, 0, stream>>>(xn2, wqkvT2, QKVf32);
  qkv_combine<<<S, 256, 0, stream>>>(QKVf32, ropetab, QKVh, QKVl);
  attn_mfma<<<1024, 256, 0, stream>>>(QKVh, QKVl, Opart, ml);
  attn_combine<<<S, 256, 0, stream>>>(Opart, ml, OA2);
  gemm_wo<<<512, 256, 0, stream>>>(OA2, woT2, p01);
  rmsnorm_res2<<<S, 256, 0, stream>>>(hidden, p01, ln2_w, out, yb, rstab);
  gate_scatter<<<S, 256, 0, stream>>>(out, ln2_w, rstab, gate_w, counts, tok_map, w_map);
  moe_gu<<<2048, 256, 0, stream>>>(yb, wgT, wuT, Hb, counts, tok_map);
  moe_down<<<2048, 256, 0, stream>>>(Hb, wdT, out, counts, tok_map, w_map);
}

// Round 7
// 359.417 us; speedup vs baseline: 4.0685x; 1.1008x over previous
//
#include <hip/hip_runtime.h>
#include <math.h>

constexpr int S  = 2048;
constexpr int D  = 1024;
constexpr int NH = 16;
constexpr int NE = 8;
constexpr float EPS   = 1e-6f;
constexpr float THETA = 10000.0f;
constexpr float SCL2  = 0.125f * 1.4426950408889634f;  // attn scale * log2(e)
constexpr float LOG2E = 1.4426950408889634f;

typedef unsigned short u16;
typedef unsigned int   u32;
typedef unsigned long long u64;
typedef __attribute__((ext_vector_type(8))) short short8;
typedef __attribute__((ext_vector_type(4))) float f32x4;

__device__ __forceinline__ u16 f2bf(float x) {
  union { float f; u32 u; } v; v.f = x;
  u32 r = (v.u + 0x7FFFu + ((v.u >> 16) & 1u)) >> 16;
  return (u16)r;
}
__device__ __forceinline__ float bf2f(u16 h) {
  union { u32 u; float f; } v; v.u = ((u32)h) << 16;
  return v.f;
}
__device__ __forceinline__ f32x4 mfma16(short8 a, short8 b, f32x4 c) {
  return __builtin_amdgcn_mfma_f32_16x16x32_bf16(a, b, c, 0, 0, 0);
}
__device__ __forceinline__ void gl_lds16(const void* g, void* l) {
  __builtin_amdgcn_global_load_lds((const __attribute__((address_space(1))) u32*)g,
                                   (__attribute__((address_space(3))) u32*)l, 16, 0, 0);
}
__device__ __forceinline__ u64 pack4bf(float a, float b, float c, float d) {
  return (u64)f2bf(a) | ((u64)f2bf(b) << 16) | ((u64)f2bf(c) << 32) | ((u64)f2bf(d) << 48);
}

// ================================================= unified prep kernel
// [0,7168): weight transposes; [7168,7424): rope tab (+counts zero);
// [7424,9472): rmsnorm_split rows; [9472,11008): zero QKVf32 (24MB)
__global__ __launch_bounds__(256) void prep_kernel(const float* __restrict__ wqkv,
    const float* __restrict__ wo, const float* __restrict__ wg, const float* __restrict__ wu,
    const float* __restrict__ wd, const int* __restrict__ positions,
    const float* __restrict__ hidden, const float* __restrict__ ln1_w,
    u16* __restrict__ wqkvT2, u16* __restrict__ woT2, u16* __restrict__ wgT,
    u16* __restrict__ wuT, u16* __restrict__ wdT, float2* __restrict__ ropetab,
    u16* __restrict__ xn2, float* __restrict__ QKVf32, int* __restrict__ counts) {
  const int b = blockIdx.x;
  const int tid = threadIdx.x;
  if (b >= 9472) {  // zero QKVf32
    const int z = b - 9472;
    float4* f4 = (float4*)QKVf32;
    const float4 zz = make_float4(0.f, 0.f, 0.f, 0.f);
#pragma unroll
    for (int i = 0; i < 4; ++i) f4[(size_t)z * 1024 + i * 256 + tid] = zz;
    return;
  }
  if (b >= 7424) {  // rmsnorm_split
    const int t = b - 7424;
    const float* xr = hidden + (size_t)t * D;
    float v[4]; float ss = 0.f;
#pragma unroll
    for (int i = 0; i < 4; ++i) { v[i] = xr[tid + i * 256]; ss += v[i] * v[i]; }
#pragma unroll
    for (int m = 32; m >= 1; m >>= 1) ss += __shfl_xor(ss, m, 64);
    __shared__ float red[4];
    if ((tid & 63) == 0) red[tid >> 6] = ss;
    __syncthreads();
    const float rs = rsqrtf((red[0] + red[1] + red[2] + red[3]) * (1.f / (float)D) + EPS);
#pragma unroll
    for (int i = 0; i < 4; ++i) {
      const int d = tid + i * 256;
      const float y = v[i] * rs * ln1_w[d];
      const u16 h = f2bf(y);
      xn2[(size_t)t * 2048 + d] = h;
      xn2[(size_t)t * 2048 + 1024 + d] = f2bf(y - bf2f(h));
    }
    return;
  }
  if (b >= 7168) {  // rope table
    if (b == 7168 && tid < 8) counts[tid] = 0;
    const int idx = (b - 7168) * 256 + tid;
    const int t = idx >> 5, p = idx & 31;
    const float inv = powf(THETA, -(float)p * (1.f / 32.f));
    const float fr = (float)positions[t] * inv;
    float sn, cs; sincosf(fr, &sn, &cs);
    ropetab[idx] = make_float2(cs, sn);
    return;
  }
  __shared__ float t_[64][65];
  const float* W; u16* out; int N, n0, k0; bool split;
  if (b < 768) {
    W = wqkv; out = wqkvT2; N = 3072; split = true;
    n0 = (b % 48) * 64; k0 = (b / 48) * 64;
  } else if (b < 1024) {
    W = wo; out = woT2; N = 1024; split = true;
    const int r = b - 768; n0 = (r & 15) * 64; k0 = (r >> 4) * 64;
  } else {
    int r;
    if (b < 3072)      { r = b - 1024; const int e = r >> 8; W = wg + (size_t)e * 1048576; out = wgT + (size_t)e * 1048576; }
    else if (b < 5120) { r = b - 3072; const int e = r >> 8; W = wu + (size_t)e * 1048576; out = wuT + (size_t)e * 1048576; }
    else               { r = b - 5120; const int e = r >> 8; W = wd + (size_t)e * 1048576; out = wdT + (size_t)e * 1048576; }
    N = 1024; split = false;
    r &= 255; n0 = (r & 15) * 64; k0 = (r >> 4) * 64;
  }
  const int rr = tid >> 4, c4 = (tid & 15) * 4;
#pragma unroll
  for (int i = 0; i < 4; ++i) {
    const float4 v = *(const float4*)(W + (size_t)(k0 + rr + i * 16) * N + n0 + c4);
    t_[rr + i * 16][c4 + 0] = v.x; t_[rr + i * 16][c4 + 1] = v.y;
    t_[rr + i * 16][c4 + 2] = v.z; t_[rr + i * 16][c4 + 3] = v.w;
  }
  __syncthreads();
  if (split) {
#pragma unroll
    for (int i = 0; i < 4; ++i) {
      const int n = n0 + rr + i * 16;
      u16* oh = out + (size_t)n * 2048 + k0 + c4;
      const float v0 = t_[c4 + 0][rr + i * 16], v1 = t_[c4 + 1][rr + i * 16];
      const float v2 = t_[c4 + 2][rr + i * 16], v3 = t_[c4 + 3][rr + i * 16];
      *(u64*)(void*)oh = pack4bf(v0, v1, v2, v3);
      *(u64*)(void*)(oh + 1024) = pack4bf(v0 - bf2f(f2bf(v0)), v1 - bf2f(f2bf(v1)),
                                          v2 - bf2f(f2bf(v2)), v3 - bf2f(f2bf(v3)));
    }
  } else {
#pragma unroll
    for (int i = 0; i < 4; ++i) {
      const int n = n0 + rr + i * 16;
      u16* o = out + (size_t)n * 1024 + k0 + c4;
      *(u64*)(void*)o = pack4bf(t_[c4 + 0][rr + i * 16], t_[c4 + 1][rr + i * 16],
                                t_[c4 + 2][rr + i * 16], t_[c4 + 3][rr + i * 16]);
    }
  }
}

// ================================================= QKV GEMM: 128x128, split-bf16, dbuf, XCD-swz,
// split-K x2, f32 atomic epilogue. grid 768
__global__ __launch_bounds__(256) void gemm_qkv(const u16* __restrict__ A2,
    const u16* __restrict__ Bt2, float* __restrict__ Cf) {
  __shared__ u16 As[2][128 * 32];
  __shared__ u16 Bs[2][128 * 32];
  const int b = blockIdx.x;
  const int xcd = b & 7, ii = b >> 3;
  const int m0 = (ii & 15) * 128;
  const int np = (ii >> 4) % 3, ks = (ii >> 4) / 3;
  const int n0 = (xcd * 3 + np) * 128;
  const int kk0 = ks * 48, kk1 = kk0 + 48;
  const int tid = threadIdx.x, wv = tid >> 6, lane = tid & 63;
  const int l15 = lane & 15, lg = lane >> 4;
  const int wr = wv >> 1, wc = wv & 1;
  const int sr = lane >> 2, sk = (lane & 3) * 16;
  const u16* aptr[2]; const u16* bptr[2];
#pragma unroll
  for (int i = 0; i < 2; ++i) {
    aptr[i] = A2 + (size_t)(m0 + (wv * 2 + i) * 16 + sr) * 2048;
    bptr[i] = Bt2 + (size_t)(n0 + (wv * 2 + i) * 16 + sr) * 2048;
  }
  auto STAGE = [&](int buf, int kk) {
    const int t = kk * 32;
    int ka, kb;
    if (t < 1024)      { ka = t;        kb = t; }
    else if (t < 2048) { ka = t;        kb = t - 1024; }
    else               { ka = t - 2048; kb = t - 1024; }
#pragma unroll
    for (int i = 0; i < 2; ++i) {
      gl_lds16((const char*)(aptr[i] + ka) + sk, (char*)As + buf * 8192 + (wv * 2 + i) * 1024);
      gl_lds16((const char*)(bptr[i] + kb) + sk, (char*)Bs + buf * 8192 + (wv * 2 + i) * 1024);
    }
  };
  f32x4 acc[4][4] = {};
  STAGE(0, kk0);
  __syncthreads();
  int cur = 0;
  for (int kk = kk0; kk < kk1; ++kk) {
    if (kk + 1 < kk1) STAGE(cur ^ 1, kk + 1);
    const u16* Ab = (const u16*)As + cur * 4096;
    const u16* Bb = (const u16*)Bs + cur * 4096;
    short8 a[4], bb[4];
#pragma unroll
    for (int i = 0; i < 4; ++i)
      a[i] = *(const short8*)(const void*)(Ab + (size_t)(wr * 64 + i * 16 + l15) * 32 + lg * 8);
#pragma unroll
    for (int j = 0; j < 4; ++j)
      bb[j] = *(const short8*)(const void*)(Bb + (size_t)(wc * 64 + j * 16 + l15) * 32 + lg * 8);
    __builtin_amdgcn_s_setprio(1);
#pragma unroll
    for (int i = 0; i < 4; ++i)
#pragma unroll
      for (int j = 0; j < 4; ++j) acc[i][j] = mfma16(a[i], bb[j], acc[i][j]);
    __builtin_amdgcn_s_setprio(0);
    __syncthreads();
    cur ^= 1;
  }
#pragma unroll
  for (int i = 0; i < 4; ++i)
#pragma unroll
    for (int j = 0; j < 4; ++j)
#pragma unroll
      for (int r = 0; r < 4; ++r) {
        const int row = m0 + wr * 64 + i * 16 + lg * 4 + r;
        const int col = n0 + wc * 64 + j * 16 + l15;
        atomicAdd(&Cf[(size_t)row * 3072 + col], acc[i][j][r]);
      }
}

// ================================================= QKV combine: rope + hi/lo split-store
__global__ __launch_bounds__(256) void qkv_combine(const float* __restrict__ Cf,
    const float2* __restrict__ tab, u16* __restrict__ Ch, u16* __restrict__ Cl) {
  const int t = blockIdx.x, tid = threadIdx.x;
  const float* row = Cf + (size_t)t * 3072;
  const size_t ob = (size_t)t * 3072;
#pragma unroll
  for (int i = 0; i < 4; ++i) {  // q,k pairs
    const int pi = tid + i * 256;
    const int h = pi >> 5, p = pi & 31;
    const int col = h * 64 + p;
    const float x1 = row[col], x2 = row[col + 32];
    const float2 cs = tab[t * 32 + p];
    const float y1 = x1 * cs.x - x2 * cs.y;
    const float y2 = x1 * cs.y + x2 * cs.x;
    const u16 h1 = f2bf(y1);
    Ch[ob + col] = h1; Cl[ob + col] = f2bf(y1 - bf2f(h1));
    const u16 h2 = f2bf(y2);
    Ch[ob + col + 32] = h2; Cl[ob + col + 32] = f2bf(y2 - bf2f(h2));
  }
#pragma unroll
  for (int i = 0; i < 4; ++i) {  // v
    const int col = 2048 + tid + i * 256;
    const float y = row[col];
    const u16 h = f2bf(y);
    Ch[ob + col] = h; Cl[ob + col] = f2bf(y - bf2f(h));
  }
}

// ================================================= Wo GEMM: 128x128, split-bf16, dbuf, XCD-swz, Kx4
__global__ __launch_bounds__(256) void gemm_wo(const u16* __restrict__ A2,
    const u16* __restrict__ Bt2, float* __restrict__ Pout) {
  constexpr int N = 1024;
  __shared__ u16 As[2][128 * 32];
  __shared__ u16 Bs[2][128 * 32];
  const int b = blockIdx.x;
  const int xcd = b & 7, ii = b >> 3;
  const int n0 = xcd * 128;
  const int m0 = (ii & 15) * 128;
  const int ks = ii >> 4;
  const int kk0 = ks * 24, kk1 = kk0 + 24;
  const int tid = threadIdx.x, wv = tid >> 6, lane = tid & 63;
  const int l15 = lane & 15, lg = lane >> 4;
  const int wr = wv >> 1, wc = wv & 1;
  const int sr = lane >> 2, sk = (lane & 3) * 16;
  const u16* aptr[2]; const u16* bptr[2];
#pragma unroll
  for (int i = 0; i < 2; ++i) {
    aptr[i] = A2 + (size_t)(m0 + (wv * 2 + i) * 16 + sr) * 2048;
    bptr[i] = Bt2 + (size_t)(n0 + (wv * 2 + i) * 16 + sr) * 2048;
  }
  auto STAGE = [&](int buf, int kk) {
    const int t = kk * 32;
    int ka, kb;
    if (t < 1024)      { ka = t;        kb = t; }
    else if (t < 2048) { ka = t;        kb = t - 1024; }
    else               { ka = t - 2048; kb = t - 1024; }
#pragma unroll
    for (int i = 0; i < 2; ++i) {
      gl_lds16((const char*)(aptr[i] + ka) + sk, (char*)As + buf * 8192 + (wv * 2 + i) * 1024);
      gl_lds16((const char*)(bptr[i] + kb) + sk, (char*)Bs + buf * 8192 + (wv * 2 + i) * 1024);
    }
  };
  f32x4 acc[4][4] = {};
  STAGE(0, kk0);
  __syncthreads();
  int cur = 0;
  for (int kk = kk0; kk < kk1; ++kk) {
    if (kk + 1 < kk1) STAGE(cur ^ 1, kk + 1);
    const u16* Ab = (const u16*)As + cur * 4096;
    const u16* Bb = (const u16*)Bs + cur * 4096;
    short8 a[4], bb[4];
#pragma unroll
    for (int i = 0; i < 4; ++i)
      a[i] = *(const short8*)(const void*)(Ab + (size_t)(wr * 64 + i * 16 + l15) * 32 + lg * 8);
#pragma unroll
    for (int j = 0; j < 4; ++j)
      bb[j] = *(const short8*)(const void*)(Bb + (size_t)(wc * 64 + j * 16 + l15) * 32 + lg * 8);
    __builtin_amdgcn_s_setprio(1);
#pragma unroll
    for (int i = 0; i < 4; ++i)
#pragma unroll
      for (int j = 0; j < 4; ++j) acc[i][j] = mfma16(a[i], bb[j], acc[i][j]);
    __builtin_amdgcn_s_setprio(0);
    __syncthreads();
    cur ^= 1;
  }
  float* P = Pout + (size_t)ks * S * N;
#pragma unroll
  for (int i = 0; i < 4; ++i)
#pragma unroll
    for (int j = 0; j < 4; ++j)
#pragma unroll
      for (int r = 0; r < 4; ++r) {
        const int row = m0 + wr * 64 + i * 16 + lg * 4 + r;
        const int col = n0 + wc * 64 + j * 16 + l15;
        P[(size_t)row * N + col] = acc[i][j][r];
      }
}

// ================================================= MFMA flash attention: split-K x4, single-K-buf,
// 2-barrier schedule, 52.2KB LDS -> 3 blocks/CU.
// grid 2048: head=(b&7)+8*((b>>3)&1); qb=31-((b>>4)&31); sp=(b>>9)&3
__global__ __launch_bounds__(256) void attn_mfma(const u16* __restrict__ Qh,
    const u16* __restrict__ Ql, float* __restrict__ Opart, float2* __restrict__ ml) {
  const int b = blockIdx.x;
  const int head = (b & 7) + 8 * ((b >> 3) & 1);
  const int qb = 31 - ((b >> 4) & 31);
  const int sp = (b >> 9) & 3;
  const int q0 = qb * 64;
  const int ktiles = qb + 1;
  const int kbase = ktiles >> 2, krem = ktiles & 3;
  const int t0 = sp * kbase + (sp < krem ? sp : krem);
  const int t1 = t0 + kbase + (sp < krem ? 1 : 0);
  const int tid = threadIdx.x, w = tid >> 6, lane = tid & 63;
  const int l15 = lane & 15, lg = lane >> 4;
  __shared__ u16 Kh[64 * 64];                  // XOR-swizzled rows, single-buffered
  __shared__ u16 Kl[64 * 64];
  __shared__ __align__(16) u16 Vth[64 * 72];
  __shared__ __align__(16) u16 Vtl[64 * 72];
  __shared__ u32 Pp[4][16 * 68];

  short8 qh[2], qlo[2];
  {
    const size_t qbase = (size_t)(q0 + w * 16 + l15) * 3072 + head * 64;
    qh[0]  = *(const short8*)(const void*)(Qh + qbase + lg * 8);
    qh[1]  = *(const short8*)(const void*)(Qh + qbase + 32 + lg * 8);
    qlo[0] = *(const short8*)(const void*)(Ql + qbase + lg * 8);
    qlo[1] = *(const short8*)(const void*)(Ql + qbase + 32 + lg * 8);
  }
  f32x4 oacc[4] = {};
  float m_run[4], l_run[4];
#pragma unroll
  for (int r = 0; r < 4; ++r) { m_run[r] = -__builtin_inff(); l_run[r] = 0.f; }
  const int qrow0 = q0 + w * 16 + lg * 4;

  const int vhl = tid >> 7, rem = tid & 127;
  const int vkq = rem & 15, vdg = rem >> 4;
  const u16* vbase = (vhl ? Ql : Qh) + 2048 + head * 64 + vdg * 8;
  u16* vdst = vhl ? Vtl : Vth;
  short8 vr[4];

  auto STAGEK = [&](int kt) {
#pragma unroll
    for (int i = 0; i < 2; ++i) {
      const int inst = w * 2 + i;
      const int key = inst * 8 + (lane >> 3);
      const int db = ((lane & 7) * 16) ^ ((key & 7) << 4);
      gl_lds16((const char*)(Qh + (size_t)(kt * 64 + key) * 3072 + 1024 + head * 64) + db,
               (char*)Kh + inst * 1024);
      gl_lds16((const char*)(Ql + (size_t)(kt * 64 + key) * 3072 + 1024 + head * 64) + db,
               (char*)Kl + inst * 1024);
    }
  };
  auto VLOAD = [&](int kt) {
    const u16* vs = vbase + (size_t)(kt * 64 + vkq * 4) * 3072;
    vr[0] = *(const short8*)(const void*)vs;
    vr[1] = *(const short8*)(const void*)(vs + 3072);
    vr[2] = *(const short8*)(const void*)(vs + 6144);
    vr[3] = *(const short8*)(const void*)(vs + 9216);
  };
  auto VWRITE = [&]() {
#pragma unroll
    for (int jj = 0; jj < 8; ++jj) {
      const u64 pk = (u64)(u16)vr[0][jj] | ((u64)(u16)vr[1][jj] << 16) |
                     ((u64)(u16)vr[2][jj] << 32) | ((u64)(u16)vr[3][jj] << 48);
      *(u64*)(void*)(vdst + (vdg * 8 + jj) * 72 + vkq * 4) = pk;
    }
  };

  if (t0 < t1) {
    STAGEK(t0);
    VLOAD(t0);
    VWRITE();
    __syncthreads();
  }
  for (int t = t0; t < t1; ++t) {
    const int k0 = t * 64;
    const bool more = (t + 1 < t1);
    // ---- QK^T: 3-term split (reads Kh/Kl)
    f32x4 sacc[4];
    __builtin_amdgcn_s_setprio(1);
#pragma unroll
    for (int nt = 0; nt < 4; ++nt) {
      const int key = nt * 16 + l15;
      const char* kbh = (const char*)Kh + key * 128;
      const char* kbl = (const char*)Kl + key * 128;
      const int sw = (key & 7) << 4;
      const short8 kh0 = *(const short8*)(const void*)(kbh + ((lg * 16) ^ sw));
      const short8 kh1 = *(const short8*)(const void*)(kbh + ((64 + lg * 16) ^ sw));
      const short8 kl0 = *(const short8*)(const void*)(kbl + ((lg * 16) ^ sw));
      const short8 kl1 = *(const short8*)(const void*)(kbl + ((64 + lg * 16) ^ sw));
      f32x4 s = {};
      s = mfma16(qh[0], kh0, s); s = mfma16(qh[1], kh1, s);
      s = mfma16(qlo[0], kh0, s); s = mfma16(qlo[1], kh1, s);
      s = mfma16(qh[0], kl0, s); s = mfma16(qh[1], kl1, s);
      sacc[nt] = s;
    }
    __builtin_amdgcn_s_setprio(0);
    __syncthreads();                  // B1: all K reads done
    if (more) { STAGEK(t + 1); VLOAD(t + 1); }  // safe to overwrite K now
    // ---- scale; mask only on diagonal tile
#pragma unroll
    for (int nt = 0; nt < 4; ++nt)
#pragma unroll
      for (int r = 0; r < 4; ++r) sacc[nt][r] *= SCL2;
    if (t == qb) {
#pragma unroll
      for (int nt = 0; nt < 4; ++nt) {
        const int key = k0 + nt * 16 + l15;
#pragma unroll
        for (int r = 0; r < 4; ++r)
          if (key > qrow0 + r) sacc[nt][r] = -__builtin_inff();
      }
    }
    // ---- online softmax with defer-max
    float mx4[4];
#pragma unroll
    for (int r = 0; r < 4; ++r) {
      float mx = fmaxf(fmaxf(sacc[0][r], sacc[1][r]), fmaxf(sacc[2][r], sacc[3][r]));
#pragma unroll
      for (int msk = 8; msk >= 1; msk >>= 1) mx = fmaxf(mx, __shfl_xor(mx, msk, 64));
      mx4[r] = mx;
    }
    const bool grow = (mx4[0] > m_run[0] + 8.f) || (mx4[1] > m_run[1] + 8.f) ||
                      (mx4[2] > m_run[2] + 8.f) || (mx4[3] > m_run[3] + 8.f);
    if (__any(grow)) {
#pragma unroll
      for (int r = 0; r < 4; ++r) {
        const float m_new = fmaxf(m_run[r], mx4[r]);
        const float fac = __builtin_amdgcn_exp2f(m_run[r] - m_new);
        m_run[r] = m_new;
        l_run[r] *= fac;
#pragma unroll
        for (int nd = 0; nd < 4; ++nd) oacc[nd][r] *= fac;
      }
    }
#pragma unroll
    for (int nt = 0; nt < 4; ++nt)
#pragma unroll
      for (int r = 0; r < 4; ++r)
        sacc[nt][r] = __builtin_amdgcn_exp2f(sacc[nt][r] - m_run[r]);
#pragma unroll
    for (int r = 0; r < 4; ++r) {
      float ls = sacc[0][r] + sacc[1][r] + sacc[2][r] + sacc[3][r];
#pragma unroll
      for (int msk = 8; msk >= 1; msk >>= 1) ls += __shfl_xor(ls, msk, 64);
      l_run[r] += ls;
    }
    // ---- packed split P (trunc-exact) -> per-wave LDS
#pragma unroll
    for (int nt = 0; nt < 4; ++nt)
#pragma unroll
      for (int r = 0; r < 4; ++r) {
        const float p = sacc[nt][r];
        const u32 xu = __float_as_uint(p);
        const u32 hi = xu & 0xFFFF0000u;
        const float pl = p - __uint_as_float(hi);
        const u32 lw = __float_as_uint(pl) >> 16;
        Pp[w][(lg * 4 + r) * 68 + nt * 16 + l15] = (xu >> 16) | (lw << 16);
      }
    // ---- PV: O += PhVh + PlVh + PhVl (reads V(t))
    __builtin_amdgcn_s_setprio(1);
#pragma unroll
    for (int kk2 = 0; kk2 < 2; ++kk2) {
      const u32* prow = &Pp[w][l15 * 68 + kk2 * 32 + lg * 8];
      const uint4 pq0 = *(const uint4*)prow;
      const uint4 pq1 = *(const uint4*)(prow + 4);
      union U8 { u32 wd[4]; short8 v; } ph_, pl_;
      ph_.wd[0] = (pq0.x & 0xFFFFu) | (pq0.y << 16);
      ph_.wd[1] = (pq0.z & 0xFFFFu) | (pq0.w << 16);
      ph_.wd[2] = (pq1.x & 0xFFFFu) | (pq1.y << 16);
      ph_.wd[3] = (pq1.z & 0xFFFFu) | (pq1.w << 16);
      pl_.wd[0] = (pq0.x >> 16) | (pq0.y & 0xFFFF0000u);
      pl_.wd[1] = (pq0.z >> 16) | (pq0.w & 0xFFFF0000u);
      pl_.wd[2] = (pq1.x >> 16) | (pq1.y & 0xFFFF0000u);
      pl_.wd[3] = (pq1.z >> 16) | (pq1.w & 0xFFFF0000u);
#pragma unroll
      for (int nd = 0; nd < 4; ++nd) {
        const short8 vbh = *(const short8*)(const void*)((const char*)Vth + (nd * 16 + l15) * 144 + kk2 * 64 + lg * 16);
        const short8 vbl = *(const short8*)(const void*)((const char*)Vtl + (nd * 16 + l15) * 144 + kk2 * 64 + lg * 16);
        oacc[nd] = mfma16(ph_.v, vbh, oacc[nd]);
        oacc[nd] = mfma16(pl_.v, vbh, oacc[nd]);
        oacc[nd] = mfma16(ph_.v, vbl, oacc[nd]);
      }
    }
    __builtin_amdgcn_s_setprio(0);
    __syncthreads();                  // B2: V reads done; drains K(t+1)/V(t+1) loads
    if (more) VWRITE();               // V(t+1) visible to next PV via next B1
  }
  float* Op = Opart + (size_t)sp * S * 1024;
#pragma unroll
  for (int nd = 0; nd < 4; ++nd)
#pragma unroll
    for (int r = 0; r < 4; ++r)
      Op[(size_t)(qrow0 + r) * 1024 + head * 64 + nd * 16 + l15] = oacc[nd][r];
  if (l15 == 0) {
#pragma unroll
    for (int r = 0; r < 4; ++r)
      ml[((size_t)sp * S + qrow0 + r) * NH + head] = make_float2(m_run[r], l_run[r]);
  }
}

// ================================================= combine 4 split-K attention partials
__global__ __launch_bounds__(256) void attn_combine(const float* __restrict__ Op,
    const float2* __restrict__ ml, u16* __restrict__ OA2) {
  const int t = blockIdx.x, tid = threadIdx.x;
  const int h = tid >> 4, dq = (tid & 15) * 4;
  float2 a[4];
  float M = -__builtin_inff();
#pragma unroll
  for (int c = 0; c < 4; ++c) {
    a[c] = ml[((size_t)c * S + t) * NH + h];
    if (a[c].y > 0.f) M = fmaxf(M, a[c].x);
  }
  float e[4], denom = 0.f;
#pragma unroll
  for (int c = 0; c < 4; ++c) {
    e[c] = (a[c].y > 0.f) ? exp2f(a[c].x - M) : 0.f;
    denom += e[c] * a[c].y;
  }
  const float inv = 1.f / denom;
  float ov[4] = {0.f, 0.f, 0.f, 0.f};
#pragma unroll
  for (int c = 0; c < 4; ++c) {
    const float4 v = *(const float4*)(Op + ((size_t)c * S + t) * 1024 + h * 64 + dq);
    ov[0] += e[c] * v.x; ov[1] += e[c] * v.y; ov[2] += e[c] * v.z; ov[3] += e[c] * v.w;
  }
#pragma unroll
  for (int c2 = 0; c2 < 4; ++c2) {
    const float o = ov[c2] * inv;
    const size_t idx = (size_t)t * 2048 + h * 64 + dq + c2;
    const u16 hb = f2bf(o);
    OA2[idx] = hb;
    OA2[idx + 1024] = f2bf(o - bf2f(hb));
  }
}

// ================================================= res2 (4 partials) + rmsnorm2 + gate + scatter fused
__global__ __launch_bounds__(256) void rmsnorm_res2_gate(const float* __restrict__ hidden,
    const float* __restrict__ p01, const float* __restrict__ w2, const float* __restrict__ GW,
    float* __restrict__ out, u16* __restrict__ yb,
    int* __restrict__ counts, int* __restrict__ tok_map, float* __restrict__ w_map) {
  const int t = blockIdx.x;
  float v[4]; float ss = 0.f;
#pragma unroll
  for (int i = 0; i < 4; ++i) {
    const size_t idx = (size_t)t * D + threadIdx.x + i * 256;
    const float r = hidden[idx] + p01[idx] + p01[idx + (size_t)S * D] +
                    p01[idx + 2 * (size_t)S * D] + p01[idx + 3 * (size_t)S * D];
    v[i] = r; ss += r * r;
  }
#pragma unroll
  for (int m = 32; m >= 1; m >>= 1) ss += __shfl_xor(ss, m, 64);
  __shared__ float red[4];
  if ((threadIdx.x & 63) == 0) red[threadIdx.x >> 6] = ss;
  __syncthreads();
  const float rs = rsqrtf((red[0] + red[1] + red[2] + red[3]) * (1.f / (float)D) + EPS);
  float lg[8] = {};
#pragma unroll
  for (int i = 0; i < 4; ++i) {
    const int d = threadIdx.x + i * 256;
    const size_t idx = (size_t)t * D + d;
    const float y = v[i] * rs * w2[d];
    out[idx] = v[i];
    yb[idx] = f2bf(y);
    const float4 g0 = *(const float4*)(GW + d * 8);
    const float4 g1 = *(const float4*)(GW + d * 8 + 4);
    lg[0] += y * g0.x; lg[1] += y * g0.y; lg[2] += y * g0.z; lg[3] += y * g0.w;
    lg[4] += y * g1.x; lg[5] += y * g1.y; lg[6] += y * g1.z; lg[7] += y * g1.w;
  }
#pragma unroll
  for (int e = 0; e < 8; ++e)
#pragma unroll
    for (int m = 32; m >= 1; m >>= 1) lg[e] += __shfl_xor(lg[e], m, 64);
  __shared__ float wred[4][8];
  if ((threadIdx.x & 63) == 0)
#pragma unroll
    for (int e = 0; e < 8; ++e) wred[threadIdx.x >> 6][e] = lg[e];
  __syncthreads();
  if (threadIdx.x == 0) {
    float L[8];
#pragma unroll
    for (int e = 0; e < 8; ++e) L[e] = wred[0][e] + wred[1][e] + wred[2][e] + wred[3][e];
    int i0 = 0; float v0 = L[0];
    for (int i = 1; i < 8; ++i) if (L[i] > v0) { v0 = L[i]; i0 = i; }
    int i1 = -1; float v1 = -__builtin_inff();
    for (int i = 0; i < 8; ++i) if (i != i0 && L[i] > v1) { v1 = L[i]; i1 = i; }
    const float e1 = expf(v1 - v0);
    const float inv = 1.f / (1.f + e1);
    const int p0 = atomicAdd(&counts[i0], 1);
    tok_map[i0 * S + p0] = t; w_map[i0 * S + p0] = inv;
    const int p1 = atomicAdd(&counts[i1], 1);
    tok_map[i1 * S + p1] = t; w_map[i1 * S + p1] = e1 * inv;
  }
}

// ================================================= MoE gate/up GEMM: 128x64 tile, dual-B, dbuf
__global__ __launch_bounds__(256) void moe_gu(const u16* __restrict__ Yb,
    const u16* __restrict__ Wgb, const u16* __restrict__ Wub, u16* __restrict__ Hb,
    const int* __restrict__ counts, const int* __restrict__ tokmap) {
  const int b = blockIdx.x;
  const int e = b & 7, ii = b >> 3;
  const int n0 = (ii & 15) * 64;
  const int m0 = (ii >> 4) * 128;
  const int cnt = counts[e];
  if (m0 >= cnt) return;
  __shared__ u16 SH[2][16 * 512];
  const int tid = threadIdx.x, wv = tid >> 6, lane = tid & 63;
  const int l15 = lane & 15, lg = lane >> 4;
  const int wr = wv >> 1, wc = wv & 1;
  const int sr = lane >> 2, sk = (lane & 3) * 16;
  const u16* B1 = Wgb + (size_t)e * 1048576;
  const u16* B2 = Wub + (size_t)e * 1048576;
  const u16* cp[4];
#pragma unroll
  for (int i = 0; i < 4; ++i) {
    const int c = wv * 4 + i;
    if (c < 8) {
      const int arow = m0 + c * 16 + sr;
      const int tok = tokmap[e * S + arow] & 2047;
      cp[i] = Yb + (size_t)tok * 1024;
    } else if (c < 12) {
      cp[i] = B1 + (size_t)(n0 + (c - 8) * 16 + sr) * 1024;
    } else {
      cp[i] = B2 + (size_t)(n0 + (c - 12) * 16 + sr) * 1024;
    }
  }
  auto STAGE = [&](int buf, int k) {
#pragma unroll
    for (int i = 0; i < 4; ++i) {
      const int c = wv * 4 + i;
      gl_lds16((const char*)(cp[i] + k) + sk, (char*)SH + buf * 16384 + c * 1024);
    }
  };
  f32x4 acc1[4][2] = {};
  f32x4 acc2[4][2] = {};
  STAGE(0, 0);
  __syncthreads();
  int cur = 0;
  for (int kk = 0; kk < 32; ++kk) {
    if (kk < 31) STAGE(cur ^ 1, (kk + 1) * 32);
    const u16* Sb = (const u16*)SH + cur * 8192;
    short8 a[4], b1f[2], b2f[2];
#pragma unroll
    for (int i = 0; i < 4; ++i)
      a[i] = *(const short8*)(const void*)(Sb + (size_t)(wr * 64 + i * 16 + l15) * 32 + lg * 8);
#pragma unroll
    for (int j = 0; j < 2; ++j) {
      b1f[j] = *(const short8*)(const void*)(Sb + 4096 + (size_t)(wc * 32 + j * 16 + l15) * 32 + lg * 8);
      b2f[j] = *(const short8*)(const void*)(Sb + 6144 + (size_t)(wc * 32 + j * 16 + l15) * 32 + lg * 8);
    }
    __builtin_amdgcn_s_setprio(1);
#pragma unroll
    for (int i = 0; i < 4; ++i)
#pragma unroll
      for (int j = 0; j < 2; ++j) {
        acc1[i][j] = mfma16(a[i], b1f[j], acc1[i][j]);
        acc2[i][j] = mfma16(a[i], b2f[j], acc2[i][j]);
      }
    __builtin_amdgcn_s_setprio(0);
    __syncthreads();
    cur ^= 1;
  }
#pragma unroll
  for (int i = 0; i < 4; ++i)
#pragma unroll
    for (int j = 0; j < 2; ++j)
#pragma unroll
      for (int r = 0; r < 4; ++r) {
        const int row = m0 + wr * 64 + i * 16 + lg * 4 + r;
        if (row < cnt) {
          const float g = acc1[i][j][r];
          const float u = acc2[i][j][r];
          const float sig = __builtin_amdgcn_rcpf(1.f + __builtin_amdgcn_exp2f(-g * LOG2E));
          Hb[((size_t)e * 2048 + row) * 1024 + n0 + wc * 32 + j * 16 + l15] = f2bf(u * g * sig);
        }
      }
}

// ================================================= MoE down GEMM: split-K x2, atomic f32 into out
__global__ __launch_bounds__(256) void moe_down(const u16* __restrict__ Hb,
    const u16* __restrict__ Wdb, float* __restrict__ out,
    const int* __restrict__ counts, const int* __restrict__ tokmap,
    const float* __restrict__ wmap) {
  const int b = blockIdx.x;
  const int e = b & 7, ii = b >> 3;
  const int m0 = (ii & 15) * 128;
  const int n0 = ((ii >> 4) & 7) * 128;
  const int ks = ii >> 7;
  const int cnt = counts[e];
  if (m0 >= cnt) return;
  __shared__ u16 As[2][128 * 32];
  __shared__ u16 Bs[2][128 * 32];
  const int tid = threadIdx.x, wv = tid >> 6, lane = tid & 63;
  const int l15 = lane & 15, lg = lane >> 4;
  const int wr = wv >> 1, wc = wv & 1;
  const int sr = lane >> 2, sk = (lane & 3) * 16;
  const u16* B = Wdb + (size_t)e * 1048576;
  const u16* aptr[2]; const u16* bptr[2];
#pragma unroll
  for (int i = 0; i < 2; ++i) {
    aptr[i] = Hb + ((size_t)e * 2048 + m0 + (wv * 2 + i) * 16 + sr) * 1024;
    bptr[i] = B + (size_t)(n0 + (wv * 2 + i) * 16 + sr) * 1024;
  }
  auto STAGE = [&](int buf, int k) {
#pragma unroll
    for (int i = 0; i < 2; ++i) {
      gl_lds16((const char*)(aptr[i] + k) + sk, (char*)As + buf * 8192 + (wv * 2 + i) * 1024);
      gl_lds16((const char*)(bptr[i] + k) + sk, (char*)Bs + buf * 8192 + (wv * 2 + i) * 1024);
    }
  };
  f32x4 acc[4][4] = {};
  const int kb0 = ks * 16, kb1 = kb0 + 16;
  STAGE(0, kb0 * 32);
  __syncthreads();
  int cur = 0;
  for (int kk = kb0; kk < kb1; ++kk) {
    if (kk + 1 < kb1) STAGE(cur ^ 1, (kk + 1) * 32);
    const u16* Ab = (const u16*)As + cur * 4096;
    const u16* Bb = (const u16*)Bs + cur * 4096;
    short8 a[4], bb[4];
#pragma unroll
    for (int i = 0; i < 4; ++i)
      a[i] = *(const short8*)(const void*)(Ab + (size_t)(wr * 64 + i * 16 + l15) * 32 + lg * 8);
#pragma unroll
    for (int j = 0; j < 4; ++j)
      bb[j] = *(const short8*)(const void*)(Bb + (size_t)(wc * 64 + j * 16 + l15) * 32 + lg * 8);
    __builtin_amdgcn_s_setprio(1);
#pragma unroll
    for (int i = 0; i < 4; ++i)
#pragma unroll
      for (int j = 0; j < 4; ++j) acc[i][j] = mfma16(a[i], bb[j], acc[i][j]);
    __builtin_amdgcn_s_setprio(0);
    __syncthreads();
    cur ^= 1;
  }
#pragma unroll
  for (int i = 0; i < 4; ++i)
#pragma unroll
    for (int j = 0; j < 4; ++j)
#pragma unroll
      for (int r = 0; r < 4; ++r) {
        const int row = m0 + wr * 64 + i * 16 + lg * 4 + r;
        if (row < cnt) {
          const int t = tokmap[e * S + row];
          const float wgt = wmap[e * S + row];
          atomicAdd(&out[(size_t)t * 1024 + n0 + wc * 64 + j * 16 + l15], wgt * acc[i][j][r]);
        }
      }
}

// ================================================= launch
extern "C" void kernel_launch(void* const* d_in, const int* in_sizes, int n_in,
                              void* d_out, int out_size, void* d_ws, size_t ws_size,
                              hipStream_t stream) {
  const int*   positions = (const int*)d_in[0];
  const float* hidden    = (const float*)d_in[1];
  const float* ln1_w  = (const float*)d_in[3];
  const float* ln2_w  = (const float*)d_in[4];
  const float* wqkv   = (const float*)d_in[5];
  const float* wo     = (const float*)d_in[6];
  const float* gate_w = (const float*)d_in[7];
  const float* wg     = (const float*)d_in[8];
  const float* wu     = (const float*)d_in[9];
  const float* wd     = (const float*)d_in[10];
  float* out = (float*)d_out;

  char* ws = (char*)d_ws;
  const size_t MB = 1ull << 20;
  u16* wqkvT2 = (u16*)(ws);                 // 12MB (dead after gemm_qkv)
  u16* OA2    = (u16*)(ws);                 // 8MB  (ph4-5, over wqkvT2)
  u16* woT2   = (u16*)(ws + 12 * MB);       // 4MB
  u16* wgT    = (u16*)(ws + 16 * MB);       // 16MB
  u16* wuT    = (u16*)(ws + 32 * MB);       // 16MB
  u16* wdT    = (u16*)(ws + 48 * MB);       // 16MB
  float2* ropetab = (float2*)(ws + 64 * MB);            // 512KB
  float2* ml      = (float2*)(ws + 64 * MB + 524288);   // 1MB (4 splits)
  char* mapb = ws + 65 * MB + 524288 + 1048576;         // ~66.5MB... keep inside 66MB? see below
  // maps: place at 64MB+1.5MB..66MB region
  mapb = ws + 64 * MB + 1572864;
  int*   counts   = (int*)mapb;
  int*   tok_map  = (int*)(mapb + 8192);
  float* w_map    = (float*)(mapb + 8192 + 65536);
  u16* xn2    = (u16*)(ws + 66 * MB);       // 8MB  (ph1-2)
  float* QKVf32 = (float*)(ws + 74 * MB);   // 24MB (ph1-2)
  float* Opart  = (float*)(ws + 66 * MB);   // 32MB (ph3-4, over xn2+QKVf32)
  float* p01    = (float*)(ws + 66 * MB);   // 32MB (ph5-6)
  u16* Hb     = (u16*)(ws + 66 * MB);       // 32MB (ph7)
  u16* QKVh   = (u16*)(ws + 98 * MB);       // 12MB (ph2-3)
  u16* QKVl   = (u16*)(ws + 110 * MB);      // 12MB (ph2-3)
  u16* yb     = (u16*)(ws + 98 * MB);       // 4MB  (ph6+, over QKVh)

  prep_kernel<<<11008, 256, 0, stream>>>(wqkv, wo, wg, wu, wd, positions, hidden, ln1_w,
                                         wqkvT2, woT2, wgT, wuT, wdT, ropetab,
                                         xn2, QKVf32, counts);
  gemm_qkv<<<768, 256, 0, stream>>>(xn2, wqkvT2, QKVf32);
  qkv_combine<<<S, 256, 0, stream>>>(QKVf32, ropetab, QKVh, QKVl);
  attn_mfma<<<2048, 256, 0, stream>>>(QKVh, QKVl, Opart, ml);
  attn_combine<<<S, 256, 0, stream>>>(Opart, ml, OA2);
  gemm_wo<<<512, 256, 0, stream>>>(OA2, woT2, p01);
  rmsnorm_res2_gate<<<S, 256, 0, stream>>>(hidden, p01, ln2_w, gate_w, out, yb,
                                           counts, tok_map, w_map);
  moe_gu<<<2048, 256, 0, stream>>>(yb, wgT, wuT, Hb, counts, tok_map);
  moe_down<<<2048, 256, 0, stream>>>(Hb, wdT, out, counts, tok_map, w_map);
}

// Round 8
// 315.667 us; speedup vs baseline: 4.6323x; 1.1386x over previous
//
#include <hip/hip_runtime.h>
#include <math.h>

constexpr int S  = 2048;
constexpr int D  = 1024;
constexpr int NH = 16;
constexpr int NE = 8;
constexpr float EPS   = 1e-6f;
constexpr float THETA = 10000.0f;
constexpr float SCL2  = 0.125f * 1.4426950408889634f;  // attn scale * log2(e)
constexpr float LOG2E = 1.4426950408889634f;

typedef unsigned short u16;
typedef unsigned int   u32;
typedef unsigned long long u64;
typedef __attribute__((ext_vector_type(8))) short short8;
typedef __attribute__((ext_vector_type(4))) float f32x4;

__device__ __forceinline__ u16 f2bf(float x) {
  union { float f; u32 u; } v; v.f = x;
  u32 r = (v.u + 0x7FFFu + ((v.u >> 16) & 1u)) >> 16;
  return (u16)r;
}
__device__ __forceinline__ float bf2f(u16 h) {
  union { u32 u; float f; } v; v.u = ((u32)h) << 16;
  return v.f;
}
__device__ __forceinline__ f32x4 mfma16(short8 a, short8 b, f32x4 c) {
  return __builtin_amdgcn_mfma_f32_16x16x32_bf16(a, b, c, 0, 0, 0);
}
__device__ __forceinline__ void gl_lds16(const void* g, void* l) {
  __builtin_amdgcn_global_load_lds((const __attribute__((address_space(1))) u32*)g,
                                   (__attribute__((address_space(3))) u32*)l, 16, 0, 0);
}
__device__ __forceinline__ u64 pack4bf(float a, float b, float c, float d) {
  return (u64)f2bf(a) | ((u64)f2bf(b) << 16) | ((u64)f2bf(c) << 32) | ((u64)f2bf(d) << 48);
}

// ================================================= unified prep kernel
// [0,7168): weight transposes; [7168,7424): rope tab (+counts zero);
// [7424,9472): rmsnorm_split rows
__global__ __launch_bounds__(256) void prep_kernel(const float* __restrict__ wqkv,
    const float* __restrict__ wo, const float* __restrict__ wg, const float* __restrict__ wu,
    const float* __restrict__ wd, const int* __restrict__ positions,
    const float* __restrict__ hidden, const float* __restrict__ ln1_w,
    u16* __restrict__ wqkvT2, u16* __restrict__ woT2, u16* __restrict__ wgT,
    u16* __restrict__ wuT, u16* __restrict__ wdT, float2* __restrict__ ropetab,
    u16* __restrict__ xn2, int* __restrict__ counts) {
  const int b = blockIdx.x;
  const int tid = threadIdx.x;
  if (b >= 7424) {  // rmsnorm_split
    const int t = b - 7424;
    const float* xr = hidden + (size_t)t * D;
    float v[4]; float ss = 0.f;
#pragma unroll
    for (int i = 0; i < 4; ++i) { v[i] = xr[tid + i * 256]; ss += v[i] * v[i]; }
#pragma unroll
    for (int m = 32; m >= 1; m >>= 1) ss += __shfl_xor(ss, m, 64);
    __shared__ float red[4];
    if ((tid & 63) == 0) red[tid >> 6] = ss;
    __syncthreads();
    const float rs = rsqrtf((red[0] + red[1] + red[2] + red[3]) * (1.f / (float)D) + EPS);
#pragma unroll
    for (int i = 0; i < 4; ++i) {
      const int d = tid + i * 256;
      const float y = v[i] * rs * ln1_w[d];
      const u16 h = f2bf(y);
      xn2[(size_t)t * 2048 + d] = h;
      xn2[(size_t)t * 2048 + 1024 + d] = f2bf(y - bf2f(h));
    }
    return;
  }
  if (b >= 7168) {  // rope table
    if (b == 7168 && tid < 8) counts[tid] = 0;
    const int idx = (b - 7168) * 256 + tid;
    const int t = idx >> 5, p = idx & 31;
    const float inv = powf(THETA, -(float)p * (1.f / 32.f));
    const float fr = (float)positions[t] * inv;
    float sn, cs; sincosf(fr, &sn, &cs);
    ropetab[idx] = make_float2(cs, sn);
    return;
  }
  __shared__ float t_[64][65];
  const float* W; u16* out; int N, n0, k0; bool split;
  if (b < 768) {
    W = wqkv; out = wqkvT2; N = 3072; split = true;
    n0 = (b % 48) * 64; k0 = (b / 48) * 64;
  } else if (b < 1024) {
    W = wo; out = woT2; N = 1024; split = true;
    const int r = b - 768; n0 = (r & 15) * 64; k0 = (r >> 4) * 64;
  } else {
    int r;
    if (b < 3072)      { r = b - 1024; const int e = r >> 8; W = wg + (size_t)e * 1048576; out = wgT + (size_t)e * 1048576; }
    else if (b < 5120) { r = b - 3072; const int e = r >> 8; W = wu + (size_t)e * 1048576; out = wuT + (size_t)e * 1048576; }
    else               { r = b - 5120; const int e = r >> 8; W = wd + (size_t)e * 1048576; out = wdT + (size_t)e * 1048576; }
    N = 1024; split = false;
    r &= 255; n0 = (r & 15) * 64; k0 = (r >> 4) * 64;
  }
  const int rr = tid >> 4, c4 = (tid & 15) * 4;
#pragma unroll
  for (int i = 0; i < 4; ++i) {
    const float4 v = *(const float4*)(W + (size_t)(k0 + rr + i * 16) * N + n0 + c4);
    t_[rr + i * 16][c4 + 0] = v.x; t_[rr + i * 16][c4 + 1] = v.y;
    t_[rr + i * 16][c4 + 2] = v.z; t_[rr + i * 16][c4 + 3] = v.w;
  }
  __syncthreads();
  if (split) {
#pragma unroll
    for (int i = 0; i < 4; ++i) {
      const int n = n0 + rr + i * 16;
      u16* oh = out + (size_t)n * 2048 + k0 + c4;
      const float v0 = t_[c4 + 0][rr + i * 16], v1 = t_[c4 + 1][rr + i * 16];
      const float v2 = t_[c4 + 2][rr + i * 16], v3 = t_[c4 + 3][rr + i * 16];
      *(u64*)(void*)oh = pack4bf(v0, v1, v2, v3);
      *(u64*)(void*)(oh + 1024) = pack4bf(v0 - bf2f(f2bf(v0)), v1 - bf2f(f2bf(v1)),
                                          v2 - bf2f(f2bf(v2)), v3 - bf2f(f2bf(v3)));
    }
  } else {
#pragma unroll
    for (int i = 0; i < 4; ++i) {
      const int n = n0 + rr + i * 16;
      u16* o = out + (size_t)n * 1024 + k0 + c4;
      *(u64*)(void*)o = pack4bf(t_[c4 + 0][rr + i * 16], t_[c4 + 1][rr + i * 16],
                                t_[c4 + 2][rr + i * 16], t_[c4 + 3][rr + i * 16]);
    }
  }
}

// ================================================= QKV GEMM: 128x128, split-bf16, dbuf, XCD-swz,
// split-K x2 -> f32 partial planes (plain stores). grid 768
__global__ __launch_bounds__(256) void gemm_qkv(const u16* __restrict__ A2,
    const u16* __restrict__ Bt2, float* __restrict__ Cpart) {
  __shared__ u16 As[2][128 * 32];
  __shared__ u16 Bs[2][128 * 32];
  const int b = blockIdx.x;
  const int xcd = b & 7, ii = b >> 3;
  const int m0 = (ii & 15) * 128;
  const int np = (ii >> 4) % 3, ks = (ii >> 4) / 3;
  const int n0 = (xcd * 3 + np) * 128;
  const int kk0 = ks * 48, kk1 = kk0 + 48;
  const int tid = threadIdx.x, wv = tid >> 6, lane = tid & 63;
  const int l15 = lane & 15, lg = lane >> 4;
  const int wr = wv >> 1, wc = wv & 1;
  const int sr = lane >> 2, sk = (lane & 3) * 16;
  const u16* aptr[2]; const u16* bptr[2];
#pragma unroll
  for (int i = 0; i < 2; ++i) {
    aptr[i] = A2 + (size_t)(m0 + (wv * 2 + i) * 16 + sr) * 2048;
    bptr[i] = Bt2 + (size_t)(n0 + (wv * 2 + i) * 16 + sr) * 2048;
  }
  auto STAGE = [&](int buf, int kk) {
    const int t = kk * 32;
    int ka, kb;
    if (t < 1024)      { ka = t;        kb = t; }
    else if (t < 2048) { ka = t;        kb = t - 1024; }
    else               { ka = t - 2048; kb = t - 1024; }
#pragma unroll
    for (int i = 0; i < 2; ++i) {
      gl_lds16((const char*)(aptr[i] + ka) + sk, (char*)As + buf * 8192 + (wv * 2 + i) * 1024);
      gl_lds16((const char*)(bptr[i] + kb) + sk, (char*)Bs + buf * 8192 + (wv * 2 + i) * 1024);
    }
  };
  f32x4 acc[4][4] = {};
  STAGE(0, kk0);
  __syncthreads();
  int cur = 0;
  for (int kk = kk0; kk < kk1; ++kk) {
    if (kk + 1 < kk1) STAGE(cur ^ 1, kk + 1);
    const u16* Ab = (const u16*)As + cur * 4096;
    const u16* Bb = (const u16*)Bs + cur * 4096;
    short8 a[4], bb[4];
#pragma unroll
    for (int i = 0; i < 4; ++i)
      a[i] = *(const short8*)(const void*)(Ab + (size_t)(wr * 64 + i * 16 + l15) * 32 + lg * 8);
#pragma unroll
    for (int j = 0; j < 4; ++j)
      bb[j] = *(const short8*)(const void*)(Bb + (size_t)(wc * 64 + j * 16 + l15) * 32 + lg * 8);
    __builtin_amdgcn_s_setprio(1);
#pragma unroll
    for (int i = 0; i < 4; ++i)
#pragma unroll
      for (int j = 0; j < 4; ++j) acc[i][j] = mfma16(a[i], bb[j], acc[i][j]);
    __builtin_amdgcn_s_setprio(0);
    __syncthreads();
    cur ^= 1;
  }
  float* P = Cpart + (size_t)ks * S * 3072;
#pragma unroll
  for (int i = 0; i < 4; ++i)
#pragma unroll
    for (int j = 0; j < 4; ++j)
#pragma unroll
      for (int r = 0; r < 4; ++r) {
        const int row = m0 + wr * 64 + i * 16 + lg * 4 + r;
        const int col = n0 + wc * 64 + j * 16 + l15;
        P[(size_t)row * 3072 + col] = acc[i][j][r];
      }
}

// ================================================= QKV combine: sum 2 planes + rope + hi/lo split
__global__ __launch_bounds__(256) void qkv_combine(const float* __restrict__ Cp,
    const float2* __restrict__ tab, u16* __restrict__ Ch, u16* __restrict__ Cl) {
  const int t = blockIdx.x, tid = threadIdx.x;
  const float* r0 = Cp + (size_t)t * 3072;
  const float* r1 = r0 + (size_t)S * 3072;
  const size_t ob = (size_t)t * 3072;
#pragma unroll
  for (int i = 0; i < 4; ++i) {  // q,k pairs
    const int pi = tid + i * 256;
    const int h = pi >> 5, p = pi & 31;
    const int col = h * 64 + p;
    const float x1 = r0[col] + r1[col];
    const float x2 = r0[col + 32] + r1[col + 32];
    const float2 cs = tab[t * 32 + p];
    const float y1 = x1 * cs.x - x2 * cs.y;
    const float y2 = x1 * cs.y + x2 * cs.x;
    const u16 h1 = f2bf(y1);
    Ch[ob + col] = h1; Cl[ob + col] = f2bf(y1 - bf2f(h1));
    const u16 h2 = f2bf(y2);
    Ch[ob + col + 32] = h2; Cl[ob + col + 32] = f2bf(y2 - bf2f(h2));
  }
#pragma unroll
  for (int i = 0; i < 4; ++i) {  // v
    const int col = 2048 + tid + i * 256;
    const float y = r0[col] + r1[col];
    const u16 h = f2bf(y);
    Ch[ob + col] = h; Cl[ob + col] = f2bf(y - bf2f(h));
  }
}

// ================================================= Wo GEMM: 128x128, split-bf16, dbuf, XCD-swz, Kx4
__global__ __launch_bounds__(256) void gemm_wo(const u16* __restrict__ A2,
    const u16* __restrict__ Bt2, float* __restrict__ Pout) {
  constexpr int N = 1024;
  __shared__ u16 As[2][128 * 32];
  __shared__ u16 Bs[2][128 * 32];
  const int b = blockIdx.x;
  const int xcd = b & 7, ii = b >> 3;
  const int n0 = xcd * 128;
  const int m0 = (ii & 15) * 128;
  const int ks = ii >> 4;
  const int kk0 = ks * 24, kk1 = kk0 + 24;
  const int tid = threadIdx.x, wv = tid >> 6, lane = tid & 63;
  const int l15 = lane & 15, lg = lane >> 4;
  const int wr = wv >> 1, wc = wv & 1;
  const int sr = lane >> 2, sk = (lane & 3) * 16;
  const u16* aptr[2]; const u16* bptr[2];
#pragma unroll
  for (int i = 0; i < 2; ++i) {
    aptr[i] = A2 + (size_t)(m0 + (wv * 2 + i) * 16 + sr) * 2048;
    bptr[i] = Bt2 + (size_t)(n0 + (wv * 2 + i) * 16 + sr) * 2048;
  }
  auto STAGE = [&](int buf, int kk) {
    const int t = kk * 32;
    int ka, kb;
    if (t < 1024)      { ka = t;        kb = t; }
    else if (t < 2048) { ka = t;        kb = t - 1024; }
    else               { ka = t - 2048; kb = t - 1024; }
#pragma unroll
    for (int i = 0; i < 2; ++i) {
      gl_lds16((const char*)(aptr[i] + ka) + sk, (char*)As + buf * 8192 + (wv * 2 + i) * 1024);
      gl_lds16((const char*)(bptr[i] + kb) + sk, (char*)Bs + buf * 8192 + (wv * 2 + i) * 1024);
    }
  };
  f32x4 acc[4][4] = {};
  STAGE(0, kk0);
  __syncthreads();
  int cur = 0;
  for (int kk = kk0; kk < kk1; ++kk) {
    if (kk + 1 < kk1) STAGE(cur ^ 1, kk + 1);
    const u16* Ab = (const u16*)As + cur * 4096;
    const u16* Bb = (const u16*)Bs + cur * 4096;
    short8 a[4], bb[4];
#pragma unroll
    for (int i = 0; i < 4; ++i)
      a[i] = *(const short8*)(const void*)(Ab + (size_t)(wr * 64 + i * 16 + l15) * 32 + lg * 8);
#pragma unroll
    for (int j = 0; j < 4; ++j)
      bb[j] = *(const short8*)(const void*)(Bb + (size_t)(wc * 64 + j * 16 + l15) * 32 + lg * 8);
    __builtin_amdgcn_s_setprio(1);
#pragma unroll
    for (int i = 0; i < 4; ++i)
#pragma unroll
      for (int j = 0; j < 4; ++j) acc[i][j] = mfma16(a[i], bb[j], acc[i][j]);
    __builtin_amdgcn_s_setprio(0);
    __syncthreads();
    cur ^= 1;
  }
  float* P = Pout + (size_t)ks * S * N;
#pragma unroll
  for (int i = 0; i < 4; ++i)
#pragma unroll
    for (int j = 0; j < 4; ++j)
#pragma unroll
      for (int r = 0; r < 4; ++r) {
        const int row = m0 + wr * 64 + i * 16 + lg * 4 + r;
        const int col = n0 + wc * 64 + j * 16 + l15;
        P[(size_t)row * N + col] = acc[i][j][r];
      }
}

// ================================================= MFMA flash attention: split-K x4, single-K-buf
__global__ __launch_bounds__(256) void attn_mfma(const u16* __restrict__ Qh,
    const u16* __restrict__ Ql, float* __restrict__ Opart, float2* __restrict__ ml) {
  const int b = blockIdx.x;
  const int head = (b & 7) + 8 * ((b >> 3) & 1);
  const int qb = 31 - ((b >> 4) & 31);
  const int sp = (b >> 9) & 3;
  const int q0 = qb * 64;
  const int ktiles = qb + 1;
  const int kbase = ktiles >> 2, krem = ktiles & 3;
  const int t0 = sp * kbase + (sp < krem ? sp : krem);
  const int t1 = t0 + kbase + (sp < krem ? 1 : 0);
  const int tid = threadIdx.x, w = tid >> 6, lane = tid & 63;
  const int l15 = lane & 15, lg = lane >> 4;
  __shared__ u16 Kh[64 * 64];
  __shared__ u16 Kl[64 * 64];
  __shared__ __align__(16) u16 Vth[64 * 72];
  __shared__ __align__(16) u16 Vtl[64 * 72];
  __shared__ u32 Pp[4][16 * 68];

  short8 qh[2], qlo[2];
  {
    const size_t qbase = (size_t)(q0 + w * 16 + l15) * 3072 + head * 64;
    qh[0]  = *(const short8*)(const void*)(Qh + qbase + lg * 8);
    qh[1]  = *(const short8*)(const void*)(Qh + qbase + 32 + lg * 8);
    qlo[0] = *(const short8*)(const void*)(Ql + qbase + lg * 8);
    qlo[1] = *(const short8*)(const void*)(Ql + qbase + 32 + lg * 8);
  }
  f32x4 oacc[4] = {};
  float m_run[4], l_run[4];
#pragma unroll
  for (int r = 0; r < 4; ++r) { m_run[r] = -__builtin_inff(); l_run[r] = 0.f; }
  const int qrow0 = q0 + w * 16 + lg * 4;

  const int vhl = tid >> 7, rem = tid & 127;
  const int vkq = rem & 15, vdg = rem >> 4;
  const u16* vbase = (vhl ? Ql : Qh) + 2048 + head * 64 + vdg * 8;
  u16* vdst = vhl ? Vtl : Vth;
  short8 vr[4];

  auto STAGEK = [&](int kt) {
#pragma unroll
    for (int i = 0; i < 2; ++i) {
      const int inst = w * 2 + i;
      const int key = inst * 8 + (lane >> 3);
      const int db = ((lane & 7) * 16) ^ ((key & 7) << 4);
      gl_lds16((const char*)(Qh + (size_t)(kt * 64 + key) * 3072 + 1024 + head * 64) + db,
               (char*)Kh + inst * 1024);
      gl_lds16((const char*)(Ql + (size_t)(kt * 64 + key) * 3072 + 1024 + head * 64) + db,
               (char*)Kl + inst * 1024);
    }
  };
  auto VLOAD = [&](int kt) {
    const u16* vs = vbase + (size_t)(kt * 64 + vkq * 4) * 3072;
    vr[0] = *(const short8*)(const void*)vs;
    vr[1] = *(const short8*)(const void*)(vs + 3072);
    vr[2] = *(const short8*)(const void*)(vs + 6144);
    vr[3] = *(const short8*)(const void*)(vs + 9216);
  };
  auto VWRITE = [&]() {
#pragma unroll
    for (int jj = 0; jj < 8; ++jj) {
      const u64 pk = (u64)(u16)vr[0][jj] | ((u64)(u16)vr[1][jj] << 16) |
                     ((u64)(u16)vr[2][jj] << 32) | ((u64)(u16)vr[3][jj] << 48);
      *(u64*)(void*)(vdst + (vdg * 8 + jj) * 72 + vkq * 4) = pk;
    }
  };

  if (t0 < t1) {
    STAGEK(t0);
    VLOAD(t0);
    VWRITE();
    __syncthreads();
  }
  for (int t = t0; t < t1; ++t) {
    const int k0 = t * 64;
    const bool more = (t + 1 < t1);
    f32x4 sacc[4];
    __builtin_amdgcn_s_setprio(1);
#pragma unroll
    for (int nt = 0; nt < 4; ++nt) {
      const int key = nt * 16 + l15;
      const char* kbh = (const char*)Kh + key * 128;
      const char* kbl = (const char*)Kl + key * 128;
      const int sw = (key & 7) << 4;
      const short8 kh0 = *(const short8*)(const void*)(kbh + ((lg * 16) ^ sw));
      const short8 kh1 = *(const short8*)(const void*)(kbh + ((64 + lg * 16) ^ sw));
      const short8 kl0 = *(const short8*)(const void*)(kbl + ((lg * 16) ^ sw));
      const short8 kl1 = *(const short8*)(const void*)(kbl + ((64 + lg * 16) ^ sw));
      f32x4 s = {};
      s = mfma16(qh[0], kh0, s); s = mfma16(qh[1], kh1, s);
      s = mfma16(qlo[0], kh0, s); s = mfma16(qlo[1], kh1, s);
      s = mfma16(qh[0], kl0, s); s = mfma16(qh[1], kl1, s);
      sacc[nt] = s;
    }
    __builtin_amdgcn_s_setprio(0);
    __syncthreads();                  // B1: all K reads done
    if (more) { STAGEK(t + 1); VLOAD(t + 1); }
#pragma unroll
    for (int nt = 0; nt < 4; ++nt)
#pragma unroll
      for (int r = 0; r < 4; ++r) sacc[nt][r] *= SCL2;
    if (t == qb) {
#pragma unroll
      for (int nt = 0; nt < 4; ++nt) {
        const int key = k0 + nt * 16 + l15;
#pragma unroll
        for (int r = 0; r < 4; ++r)
          if (key > qrow0 + r) sacc[nt][r] = -__builtin_inff();
      }
    }
    float mx4[4];
#pragma unroll
    for (int r = 0; r < 4; ++r) {
      float mx = fmaxf(fmaxf(sacc[0][r], sacc[1][r]), fmaxf(sacc[2][r], sacc[3][r]));
#pragma unroll
      for (int msk = 8; msk >= 1; msk >>= 1) mx = fmaxf(mx, __shfl_xor(mx, msk, 64));
      mx4[r] = mx;
    }
    const bool grow = (mx4[0] > m_run[0] + 8.f) || (mx4[1] > m_run[1] + 8.f) ||
                      (mx4[2] > m_run[2] + 8.f) || (mx4[3] > m_run[3] + 8.f);
    if (__any(grow)) {
#pragma unroll
      for (int r = 0; r < 4; ++r) {
        const float m_new = fmaxf(m_run[r], mx4[r]);
        const float fac = __builtin_amdgcn_exp2f(m_run[r] - m_new);
        m_run[r] = m_new;
        l_run[r] *= fac;
#pragma unroll
        for (int nd = 0; nd < 4; ++nd) oacc[nd][r] *= fac;
      }
    }
#pragma unroll
    for (int nt = 0; nt < 4; ++nt)
#pragma unroll
      for (int r = 0; r < 4; ++r)
        sacc[nt][r] = __builtin_amdgcn_exp2f(sacc[nt][r] - m_run[r]);
#pragma unroll
    for (int r = 0; r < 4; ++r) {
      float ls = sacc[0][r] + sacc[1][r] + sacc[2][r] + sacc[3][r];
#pragma unroll
      for (int msk = 8; msk >= 1; msk >>= 1) ls += __shfl_xor(ls, msk, 64);
      l_run[r] += ls;
    }
#pragma unroll
    for (int nt = 0; nt < 4; ++nt)
#pragma unroll
      for (int r = 0; r < 4; ++r) {
        const float p = sacc[nt][r];
        const u32 xu = __float_as_uint(p);
        const u32 hi = xu & 0xFFFF0000u;
        const float pl = p - __uint_as_float(hi);
        const u32 lw = __float_as_uint(pl) >> 16;
        Pp[w][(lg * 4 + r) * 68 + nt * 16 + l15] = (xu >> 16) | (lw << 16);
      }
    __builtin_amdgcn_s_setprio(1);
#pragma unroll
    for (int kk2 = 0; kk2 < 2; ++kk2) {
      const u32* prow = &Pp[w][l15 * 68 + kk2 * 32 + lg * 8];
      const uint4 pq0 = *(const uint4*)prow;
      const uint4 pq1 = *(const uint4*)(prow + 4);
      union U8 { u32 wd[4]; short8 v; } ph_, pl_;
      ph_.wd[0] = (pq0.x & 0xFFFFu) | (pq0.y << 16);
      ph_.wd[1] = (pq0.z & 0xFFFFu) | (pq0.w << 16);
      ph_.wd[2] = (pq1.x & 0xFFFFu) | (pq1.y << 16);
      ph_.wd[3] = (pq1.z & 0xFFFFu) | (pq1.w << 16);
      pl_.wd[0] = (pq0.x >> 16) | (pq0.y & 0xFFFF0000u);
      pl_.wd[1] = (pq0.z >> 16) | (pq0.w & 0xFFFF0000u);
      pl_.wd[2] = (pq1.x >> 16) | (pq1.y & 0xFFFF0000u);
      pl_.wd[3] = (pq1.z >> 16) | (pq1.w & 0xFFFF0000u);
#pragma unroll
      for (int nd = 0; nd < 4; ++nd) {
        const short8 vbh = *(const short8*)(const void*)((const char*)Vth + (nd * 16 + l15) * 144 + kk2 * 64 + lg * 16);
        const short8 vbl = *(const short8*)(const void*)((const char*)Vtl + (nd * 16 + l15) * 144 + kk2 * 64 + lg * 16);
        oacc[nd] = mfma16(ph_.v, vbh, oacc[nd]);
        oacc[nd] = mfma16(pl_.v, vbh, oacc[nd]);
        oacc[nd] = mfma16(ph_.v, vbl, oacc[nd]);
      }
    }
    __builtin_amdgcn_s_setprio(0);
    __syncthreads();                  // B2
    if (more) VWRITE();
  }
  float* Op = Opart + (size_t)sp * S * 1024;
#pragma unroll
  for (int nd = 0; nd < 4; ++nd)
#pragma unroll
    for (int r = 0; r < 4; ++r)
      Op[(size_t)(qrow0 + r) * 1024 + head * 64 + nd * 16 + l15] = oacc[nd][r];
  if (l15 == 0) {
#pragma unroll
    for (int r = 0; r < 4; ++r)
      ml[((size_t)sp * S + qrow0 + r) * NH + head] = make_float2(m_run[r], l_run[r]);
  }
}

// ================================================= combine 4 split-K attention partials
__global__ __launch_bounds__(256) void attn_combine(const float* __restrict__ Op,
    const float2* __restrict__ ml, u16* __restrict__ OA2) {
  const int t = blockIdx.x, tid = threadIdx.x;
  const int h = tid >> 4, dq = (tid & 15) * 4;
  float2 a[4];
  float M = -__builtin_inff();
#pragma unroll
  for (int c = 0; c < 4; ++c) {
    a[c] = ml[((size_t)c * S + t) * NH + h];
    if (a[c].y > 0.f) M = fmaxf(M, a[c].x);
  }
  float e[4], denom = 0.f;
#pragma unroll
  for (int c = 0; c < 4; ++c) {
    e[c] = (a[c].y > 0.f) ? exp2f(a[c].x - M) : 0.f;
    denom += e[c] * a[c].y;
  }
  const float inv = 1.f / denom;
  float ov[4] = {0.f, 0.f, 0.f, 0.f};
#pragma unroll
  for (int c = 0; c < 4; ++c) {
    const float4 v = *(const float4*)(Op + ((size_t)c * S + t) * 1024 + h * 64 + dq);
    ov[0] += e[c] * v.x; ov[1] += e[c] * v.y; ov[2] += e[c] * v.z; ov[3] += e[c] * v.w;
  }
#pragma unroll
  for (int c2 = 0; c2 < 4; ++c2) {
    const float o = ov[c2] * inv;
    const size_t idx = (size_t)t * 2048 + h * 64 + dq + c2;
    const u16 hb = f2bf(o);
    OA2[idx] = hb;
    OA2[idx + 1024] = f2bf(o - bf2f(hb));
  }
}

// ================================================= res2 (4 partials) + rmsnorm2 + gate + scatter fused
__global__ __launch_bounds__(256) void rmsnorm_res2_gate(const float* __restrict__ hidden,
    const float* __restrict__ p01, const float* __restrict__ w2, const float* __restrict__ GW,
    float* __restrict__ out, u16* __restrict__ yb,
    int* __restrict__ counts, int* __restrict__ tok_map, float* __restrict__ w_map) {
  const int t = blockIdx.x;
  float v[4]; float ss = 0.f;
#pragma unroll
  for (int i = 0; i < 4; ++i) {
    const size_t idx = (size_t)t * D + threadIdx.x + i * 256;
    const float r = hidden[idx] + p01[idx] + p01[idx + (size_t)S * D] +
                    p01[idx + 2 * (size_t)S * D] + p01[idx + 3 * (size_t)S * D];
    v[i] = r; ss += r * r;
  }
#pragma unroll
  for (int m = 32; m >= 1; m >>= 1) ss += __shfl_xor(ss, m, 64);
  __shared__ float red[4];
  if ((threadIdx.x & 63) == 0) red[threadIdx.x >> 6] = ss;
  __syncthreads();
  const float rs = rsqrtf((red[0] + red[1] + red[2] + red[3]) * (1.f / (float)D) + EPS);
  float lg[8] = {};
#pragma unroll
  for (int i = 0; i < 4; ++i) {
    const int d = threadIdx.x + i * 256;
    const size_t idx = (size_t)t * D + d;
    const float y = v[i] * rs * w2[d];
    out[idx] = v[i];
    yb[idx] = f2bf(y);
    const float4 g0 = *(const float4*)(GW + d * 8);
    const float4 g1 = *(const float4*)(GW + d * 8 + 4);
    lg[0] += y * g0.x; lg[1] += y * g0.y; lg[2] += y * g0.z; lg[3] += y * g0.w;
    lg[4] += y * g1.x; lg[5] += y * g1.y; lg[6] += y * g1.z; lg[7] += y * g1.w;
  }
#pragma unroll
  for (int e = 0; e < 8; ++e)
#pragma unroll
    for (int m = 32; m >= 1; m >>= 1) lg[e] += __shfl_xor(lg[e], m, 64);
  __shared__ float wred[4][8];
  if ((threadIdx.x & 63) == 0)
#pragma unroll
    for (int e = 0; e < 8; ++e) wred[threadIdx.x >> 6][e] = lg[e];
  __syncthreads();
  if (threadIdx.x == 0) {
    float L[8];
#pragma unroll
    for (int e = 0; e < 8; ++e) L[e] = wred[0][e] + wred[1][e] + wred[2][e] + wred[3][e];
    int i0 = 0; float v0 = L[0];
    for (int i = 1; i < 8; ++i) if (L[i] > v0) { v0 = L[i]; i0 = i; }
    int i1 = -1; float v1 = -__builtin_inff();
    for (int i = 0; i < 8; ++i) if (i != i0 && L[i] > v1) { v1 = L[i]; i1 = i; }
    const float e1 = expf(v1 - v0);
    const float inv = 1.f / (1.f + e1);
    const int p0 = atomicAdd(&counts[i0], 1);
    tok_map[i0 * S + p0] = t;          // slot 0
    w_map[i0 * S + p0] = inv;
    const int p1 = atomicAdd(&counts[i1], 1);
    tok_map[i1 * S + p1] = t | 65536;  // slot 1 in bit 16
    w_map[i1 * S + p1] = e1 * inv;
  }
}

// ================================================= MoE gate/up GEMM: 128x64 tile, dual-B, dbuf
__global__ __launch_bounds__(256) void moe_gu(const u16* __restrict__ Yb,
    const u16* __restrict__ Wgb, const u16* __restrict__ Wub, u16* __restrict__ Hb,
    const int* __restrict__ counts, const int* __restrict__ tokmap) {
  const int b = blockIdx.x;
  const int e = b & 7, ii = b >> 3;
  const int n0 = (ii & 15) * 64;
  const int m0 = (ii >> 4) * 128;
  const int cnt = counts[e];
  if (m0 >= cnt) return;
  __shared__ u16 SH[2][16 * 512];
  const int tid = threadIdx.x, wv = tid >> 6, lane = tid & 63;
  const int l15 = lane & 15, lg = lane >> 4;
  const int wr = wv >> 1, wc = wv & 1;
  const int sr = lane >> 2, sk = (lane & 3) * 16;
  const u16* B1 = Wgb + (size_t)e * 1048576;
  const u16* B2 = Wub + (size_t)e * 1048576;
  const u16* cp[4];
#pragma unroll
  for (int i = 0; i < 4; ++i) {
    const int c = wv * 4 + i;
    if (c < 8) {
      const int arow = m0 + c * 16 + sr;
      const int tok = tokmap[e * S + arow] & 2047;
      cp[i] = Yb + (size_t)tok * 1024;
    } else if (c < 12) {
      cp[i] = B1 + (size_t)(n0 + (c - 8) * 16 + sr) * 1024;
    } else {
      cp[i] = B2 + (size_t)(n0 + (c - 12) * 16 + sr) * 1024;
    }
  }
  auto STAGE = [&](int buf, int k) {
#pragma unroll
    for (int i = 0; i < 4; ++i) {
      const int c = wv * 4 + i;
      gl_lds16((const char*)(cp[i] + k) + sk, (char*)SH + buf * 16384 + c * 1024);
    }
  };
  f32x4 acc1[4][2] = {};
  f32x4 acc2[4][2] = {};
  STAGE(0, 0);
  __syncthreads();
  int cur = 0;
  for (int kk = 0; kk < 32; ++kk) {
    if (kk < 31) STAGE(cur ^ 1, (kk + 1) * 32);
    const u16* Sb = (const u16*)SH + cur * 8192;
    short8 a[4], b1f[2], b2f[2];
#pragma unroll
    for (int i = 0; i < 4; ++i)
      a[i] = *(const short8*)(const void*)(Sb + (size_t)(wr * 64 + i * 16 + l15) * 32 + lg * 8);
#pragma unroll
    for (int j = 0; j < 2; ++j) {
      b1f[j] = *(const short8*)(const void*)(Sb + 4096 + (size_t)(wc * 32 + j * 16 + l15) * 32 + lg * 8);
      b2f[j] = *(const short8*)(const void*)(Sb + 6144 + (size_t)(wc * 32 + j * 16 + l15) * 32 + lg * 8);
    }
    __builtin_amdgcn_s_setprio(1);
#pragma unroll
    for (int i = 0; i < 4; ++i)
#pragma unroll
      for (int j = 0; j < 2; ++j) {
        acc1[i][j] = mfma16(a[i], b1f[j], acc1[i][j]);
        acc2[i][j] = mfma16(a[i], b2f[j], acc2[i][j]);
      }
    __builtin_amdgcn_s_setprio(0);
    __syncthreads();
    cur ^= 1;
  }
#pragma unroll
  for (int i = 0; i < 4; ++i)
#pragma unroll
    for (int j = 0; j < 2; ++j)
#pragma unroll
      for (int r = 0; r < 4; ++r) {
        const int row = m0 + wr * 64 + i * 16 + lg * 4 + r;
        if (row < cnt) {
          const float g = acc1[i][j][r];
          const float u = acc2[i][j][r];
          const float sig = __builtin_amdgcn_rcpf(1.f + __builtin_amdgcn_exp2f(-g * LOG2E));
          Hb[((size_t)e * 2048 + row) * 1024 + n0 + wc * 32 + j * 16 + l15] = f2bf(u * g * sig);
        }
      }
}

// ================================================= MoE down GEMM: split-K x2 -> 4 bf16 slot planes
__global__ __launch_bounds__(256) void moe_down(const u16* __restrict__ Hb,
    const u16* __restrict__ Wdb, u16* __restrict__ slotp,
    const int* __restrict__ counts, const int* __restrict__ tokmap,
    const float* __restrict__ wmap) {
  const int b = blockIdx.x;
  const int e = b & 7, ii = b >> 3;
  const int m0 = (ii & 15) * 128;
  const int n0 = ((ii >> 4) & 7) * 128;
  const int ks = ii >> 7;
  const int cnt = counts[e];
  if (m0 >= cnt) return;
  __shared__ u16 As[2][128 * 32];
  __shared__ u16 Bs[2][128 * 32];
  const int tid = threadIdx.x, wv = tid >> 6, lane = tid & 63;
  const int l15 = lane & 15, lg = lane >> 4;
  const int wr = wv >> 1, wc = wv & 1;
  const int sr = lane >> 2, sk = (lane & 3) * 16;
  const u16* B = Wdb + (size_t)e * 1048576;
  const u16* aptr[2]; const u16* bptr[2];
#pragma unroll
  for (int i = 0; i < 2; ++i) {
    aptr[i] = Hb + ((size_t)e * 2048 + m0 + (wv * 2 + i) * 16 + sr) * 1024;
    bptr[i] = B + (size_t)(n0 + (wv * 2 + i) * 16 + sr) * 1024;
  }
  auto STAGE = [&](int buf, int k) {
#pragma unroll
    for (int i = 0; i < 2; ++i) {
      gl_lds16((const char*)(aptr[i] + k) + sk, (char*)As + buf * 8192 + (wv * 2 + i) * 1024);
      gl_lds16((const char*)(bptr[i] + k) + sk, (char*)Bs + buf * 8192 + (wv * 2 + i) * 1024);
    }
  };
  f32x4 acc[4][4] = {};
  const int kb0 = ks * 16, kb1 = kb0 + 16;
  STAGE(0, kb0 * 32);
  __syncthreads();
  int cur = 0;
  for (int kk = kb0; kk < kb1; ++kk) {
    if (kk + 1 < kb1) STAGE(cur ^ 1, (kk + 1) * 32);
    const u16* Ab = (const u16*)As + cur * 4096;
    const u16* Bb = (const u16*)Bs + cur * 4096;
    short8 a[4], bb[4];
#pragma unroll
    for (int i = 0; i < 4; ++i)
      a[i] = *(const short8*)(const void*)(Ab + (size_t)(wr * 64 + i * 16 + l15) * 32 + lg * 8);
#pragma unroll
    for (int j = 0; j < 4; ++j)
      bb[j] = *(const short8*)(const void*)(Bb + (size_t)(wc * 64 + j * 16 + l15) * 32 + lg * 8);
    __builtin_amdgcn_s_setprio(1);
#pragma unroll
    for (int i = 0; i < 4; ++i)
#pragma unroll
      for (int j = 0; j < 4; ++j) acc[i][j] = mfma16(a[i], bb[j], acc[i][j]);
    __builtin_amdgcn_s_setprio(0);
    __syncthreads();
    cur ^= 1;
  }
#pragma unroll
  for (int i = 0; i < 4; ++i)
#pragma unroll
    for (int j = 0; j < 4; ++j)
#pragma unroll
      for (int r = 0; r < 4; ++r) {
        const int row = m0 + wr * 64 + i * 16 + lg * 4 + r;
        if (row < cnt) {
          const int raw = tokmap[e * S + row];
          const int t = raw & 2047;
          const int sl = (raw >> 16) & 1;
          const float wgt = wmap[e * S + row];
          slotp[((size_t)(sl * 2 + ks) * S + t) * 1024 + n0 + wc * 64 + j * 16 + l15] =
              f2bf(wgt * acc[i][j][r]);
        }
      }
}

// ================================================= final add: out += sum of 4 slot planes
__global__ __launch_bounds__(256) void final_add(float* __restrict__ out,
    const u16* __restrict__ sp) {
  const size_t i = ((size_t)blockIdx.x * 256 + threadIdx.x) * 4;
  float4 o = *(float4*)(out + i);
#pragma unroll
  for (int c = 0; c < 4; ++c) {
    const u64 a = *(const u64*)(sp + (size_t)c * S * D + i);
    o.x += bf2f((u16)(a));
    o.y += bf2f((u16)(a >> 16));
    o.z += bf2f((u16)(a >> 32));
    o.w += bf2f((u16)(a >> 48));
  }
  *(float4*)(out + i) = o;
}

// ================================================= launch
extern "C" void kernel_launch(void* const* d_in, const int* in_sizes, int n_in,
                              void* d_out, int out_size, void* d_ws, size_t ws_size,
                              hipStream_t stream) {
  const int*   positions = (const int*)d_in[0];
  const float* hidden    = (const float*)d_in[1];
  const float* ln1_w  = (const float*)d_in[3];
  const float* ln2_w  = (const float*)d_in[4];
  const float* wqkv   = (const float*)d_in[5];
  const float* wo     = (const float*)d_in[6];
  const float* gate_w = (const float*)d_in[7];
  const float* wg     = (const float*)d_in[8];
  const float* wu     = (const float*)d_in[9];
  const float* wd     = (const float*)d_in[10];
  float* out = (float*)d_out;

  char* ws = (char*)d_ws;
  const size_t MB = 1ull << 20;
  // ph1-2: wqkvT2 @0-12. ph3+: QKVh @0-12 (combine writes after gemm_qkv done).
  // ph5: OA2 @0-8 (attn_combine writes after attn done).
  u16* wqkvT2 = (u16*)(ws);
  u16* QKVh   = (u16*)(ws);
  u16* OA2    = (u16*)(ws);
  u16* woT2   = (u16*)(ws + 12 * MB);       // 4MB  (prep -> gemm_wo)
  u16* wgT    = (u16*)(ws + 16 * MB);       // 16MB
  u16* wuT    = (u16*)(ws + 32 * MB);       // 16MB
  u16* wdT    = (u16*)(ws + 48 * MB);       // 16MB
  float2* ropetab = (float2*)(ws + 64 * MB);            // 512KB
  float2* ml      = (float2*)(ws + 64 * MB + 524288);   // 1MB
  char* mapb = ws + 64 * MB + 1572864;
  int*   counts   = (int*)mapb;
  int*   tok_map  = (int*)(mapb + 8192);
  float* w_map    = (float*)(mapb + 8192 + 65536);
  u16* xn2    = (u16*)(ws + 66 * MB);       // 8MB  (ph1-2)
  u16* QKVl   = (u16*)(ws + 66 * MB);       // 12MB (ph3-4, xn2 dead)
  u16* yb     = (u16*)(ws + 66 * MB);       // 4MB  (ph6+, QKVl dead)
  float* Cpart  = (float*)(ws + 78 * MB);   // 48MB (ph2-3)
  float* Opart  = (float*)(ws + 78 * MB);   // 32MB (ph4, Cpart dead)
  float* p01    = (float*)(ws + 78 * MB);   // 32MB (ph5-6)
  u16* Hb     = (u16*)(ws + 78 * MB);       // 32MB (ph7)
  u16* slotp  = (u16*)(ws + 110 * MB);      // 16MB (ph7-8)

  prep_kernel<<<9472, 256, 0, stream>>>(wqkv, wo, wg, wu, wd, positions, hidden, ln1_w,
                                        wqkvT2, woT2, wgT, wuT, wdT, ropetab, xn2, counts);
  gemm_qkv<<<768, 256, 0, stream>>>(xn2, wqkvT2, Cpart);
  qkv_combine<<<S, 256, 0, stream>>>(Cpart, ropetab, QKVh, QKVl);
  attn_mfma<<<2048, 256, 0, stream>>>(QKVh, QKVl, Opart, ml);
  attn_combine<<<S, 256, 0, stream>>>(Opart, ml, OA2);
  gemm_wo<<<512, 256, 0, stream>>>(OA2, woT2, p01);
  rmsnorm_res2_gate<<<S, 256, 0, stream>>>(hidden, p01, ln2_w, gate_w, out, yb,
                                           counts, tok_map, w_map);
  moe_gu<<<2048, 256, 0, stream>>>(yb, wgT, wuT, Hb, counts, tok_map);
  moe_down<<<2048, 256, 0, stream>>>(Hb, wdT, slotp, counts, tok_map, w_map);
  final_add<<<2048, 256, 0, stream>>>(out, slotp);
}